// Round 1
// 746.442 us; speedup vs baseline: 1.3153x; 1.3153x over previous
//
#include <hip/hip_runtime.h>
#include <stdint.h>

// ---------------------------------------------------------------------------
// LSTM pointer-generator decoder step, B=128 TK=400 NK=50 H=E=256 V=50000.
// Round 7: kill the latency-bound k_pre (306 us, VALUBusy 2.9%, occ 6%,
// 0.5 waves/SIMD). Split into k_x / k_gates / k_cellsd with 512/512/256
// blocks (2 waves/SIMD), LDS-staged activations, K-split partial buffers
// (no atomics, no init kernel). LSTM chain stays f32 so absmax holds.
// k_scores epilogue now sums two sd/sf partials + bias.
// k_tc/k_scores(MFMA)/k_doc/k_node/k_logits/k_vsoft unchanged from R6.
// ---------------------------------------------------------------------------

typedef unsigned short u16;
typedef unsigned int   u32;

#define Bv  128
#define TKv 400
#define NKv 50
#define Hv  256
#define Vv  50000
#define VPAD 50176   // 50000 padded to multiple of 128

typedef __attribute__((ext_vector_type(8))) short bf16x8;
typedef __attribute__((ext_vector_type(4))) float f32x4;

// ---- module-global workspace (no d_ws dependency) -------------------------
__device__ float g_x[32768];      // x = cat @ Wx + bx
__device__ float g_xp[4 * 32768]; // x K-partials
__device__ float g_gates[131072]; // LSTM gates [B,4H]
__device__ float g_h[32768];      // h_new
__device__ float g_c[32768];      // c_new
__device__ float g_sdp[2 * 32768];// s_hat@Wsd partials (no bias)
__device__ float g_sfp[2 * 32768];// s_hat@Wsf partials (no bias)
__device__ float g_e[51200];      // doc scores
__device__ float g_en[6400];      // node scores
__device__ float g_a[51200];      // doc attention a
__device__ float g_cd[32768];     // c_d
__device__ float g_cg[32768];     // c_g
__device__ float g_cg2[32768];    // c_g2
__device__ float g_pg[128];       // p_gen
__device__ float g_o1[32768];     // out1
__device__ float g_logits[6400000];        // f32 logits (25.6 MB)
__device__ u16   g_Wdt[256 * 256];         // Whd^T bf16 [n][k]
__device__ u16   g_Wnt[256 * 256];         // Wn^T  bf16 [n][k]
__device__ u16   g_W2t[(size_t)VPAD * 256];// W2^T  bf16 [v][k] (25.7 MB)

__device__ __forceinline__ float sigm(float x) { return 1.f / (1.f + expf(-x)); }

__device__ __forceinline__ u16 f2bf(float f) {
    u32 u = __float_as_uint(f);
    return (u16)((u + 0x7fffu + ((u >> 16) & 1u)) >> 16);  // RNE
}

__device__ __forceinline__ bf16x8 cvt8(const float* __restrict__ p) {
    const float4 a = *(const float4*)p;
    const float4 b = *(const float4*)(p + 4);
    bf16x8 r;
    r[0] = (short)f2bf(a.x); r[1] = (short)f2bf(a.y);
    r[2] = (short)f2bf(a.z); r[3] = (short)f2bf(a.w);
    r[4] = (short)f2bf(b.x); r[5] = (short)f2bf(b.y);
    r[6] = (short)f2bf(b.z); r[7] = (short)f2bf(b.w);
    return r;
}

// tanh via exp; clamp so exp never overflows (tanh saturated anyway)
__device__ __forceinline__ float fast_tanh(float x) {
    x = fminf(fmaxf(x, -15.f), 15.f);
    float e = __expf(2.f * x);
    return (e - 1.f) / (e + 1.f);
}

// ---------------------------------------------------------------------------
// K0: transpose-cast  src[K][N] f32  ->  dst[n][k] bf16.
// grid = (Npad/32, K/32), block 256 (32x8). Reads n>=N give 0 (pad rows).
// ---------------------------------------------------------------------------
__global__ __launch_bounds__(256) void k_tc(
    const float* __restrict__ src, u16* __restrict__ dst, int K, int N)
{
    __shared__ float tile[32][33];
    const int n0 = blockIdx.x * 32, k0 = blockIdx.y * 32;
    const int tx = threadIdx.x & 31, ty = threadIdx.x >> 5;
    #pragma unroll
    for (int i = 0; i < 32; i += 8) {
        int k = k0 + ty + i, n = n0 + tx;
        tile[ty + i][tx] = (n < N) ? src[(size_t)k * N + n] : 0.f;
    }
    __syncthreads();
    #pragma unroll
    for (int i = 0; i < 32; i += 8) {
        int n = n0 + ty + i, k = k0 + tx;
        dst[(size_t)n * K + k] = f2bf(tile[tx][ty + i]);
    }
}

// ---------------------------------------------------------------------------
// K1a: x K-partials. grid (B, 4): block (b, ks) stages cat-chunk ks in LDS,
// computes partial x over its 256-row slice of Wx. 512 blocks = 2 waves/SIMD.
// ---------------------------------------------------------------------------
__global__ __launch_bounds__(256) void k_x(
    const int* __restrict__ y,
    const float* __restrict__ ctd, const float* __restrict__ ctg,
    const float* __restrict__ ctg2, const float* __restrict__ emb,
    const float* __restrict__ Wx)
{
    const int b = blockIdx.x, ks = blockIdx.y, j = threadIdx.x;
    __shared__ float cs[256];
    float v;
    if      (ks == 0) v = ctd [b * 256 + j];
    else if (ks == 1) v = ctg [b * 256 + j];
    else if (ks == 2) v = ctg2[b * 256 + j];
    else              v = emb[(size_t)y[b] * 256 + j];
    cs[j] = v;
    __syncthreads();

    float acc = 0.f;
    const float* w = Wx + (size_t)(ks * 256) * 256 + j;
    #pragma unroll 8
    for (int k = 0; k < 256; k++) acc += cs[k] * w[(size_t)k * 256];
    g_xp[ks * 32768 + b * 256 + j] = acc;
}

// ---------------------------------------------------------------------------
// K1b: gates = x@Wi + h@Wh + bi + bh. grid (B, 4 col-chunks), fully
// output-parallel (no atomics). Sums the 4 x-partials + bx while staging
// (col-chunk 0 also publishes g_x for k_node).
// ---------------------------------------------------------------------------
__global__ __launch_bounds__(256) void k_gates(
    const float* __restrict__ h_prev,
    const float* __restrict__ Wi, const float* __restrict__ Wh,
    const float* __restrict__ bi, const float* __restrict__ bh,
    const float* __restrict__ bx)
{
    const int b = blockIdx.x, cc = blockIdx.y, j = threadIdx.x;
    __shared__ float xs[256], hs[256];

    float xv = bx[j] + g_xp[b * 256 + j] + g_xp[32768 + b * 256 + j]
             + g_xp[65536 + b * 256 + j] + g_xp[98304 + b * 256 + j];
    xs[j] = xv;
    if (cc == 0) g_x[b * 256 + j] = xv;
    hs[j] = h_prev[b * 256 + j];
    __syncthreads();

    const int col = cc * 256 + j;
    float acc = bi[col] + bh[col];
    const float* wi = Wi + col;
    const float* wh = Wh + col;
    #pragma unroll 8
    for (int k = 0; k < 256; k++)
        acc += xs[k] * wi[(size_t)k * 1024] + hs[k] * wh[(size_t)k * 1024];
    g_gates[b * 1024 + col] = acc;
}

// ---------------------------------------------------------------------------
// K1c: LSTM elementwise + sd/sf K-partials. grid (B, 2): both K-halves
// redundantly compute the cheap cell update; ks==0 publishes h/c. Each block
// stages its half of s_hat=[h|c] and emits sd/sf partials (bias deferred to
// the k_scores epilogue).
// ---------------------------------------------------------------------------
__global__ __launch_bounds__(256) void k_cellsd(
    const float* __restrict__ c_prev,
    const float* __restrict__ Wsd, const float* __restrict__ Wsf,
    float* __restrict__ out_h, float* __restrict__ out_c)
{
    const int b = blockIdx.x, ks = blockIdx.y, j = threadIdx.x;
    __shared__ float sh[256];

    const float* gb = g_gates + b * 1024;
    float gi_ = gb[j], gf_ = gb[256 + j], gg_ = gb[512 + j], go_ = gb[768 + j];
    float cp = c_prev[b * 256 + j];
    float cn = sigm(gf_) * cp + sigm(gi_) * tanhf(gg_);
    float hn = sigm(go_) * tanhf(cn);
    if (ks == 0) {
        g_h[b * 256 + j] = hn;  g_c[b * 256 + j] = cn;
        out_h[b * 256 + j] = hn; out_c[b * 256 + j] = cn;
    }
    sh[j] = (ks == 0) ? hn : cn;   // s_hat rows [0,256) = h, [256,512) = c
    __syncthreads();

    float asd = 0.f, asf = 0.f;
    const float* wd = Wsd + (size_t)(ks * 256) * 256 + j;
    const float* wf = Wsf + (size_t)(ks * 256) * 256 + j;
    #pragma unroll 8
    for (int k = 0; k < 256; k++) {
        float sv = sh[k];
        asd += sv * wd[(size_t)k * 256];
        asf += sv * wf[(size_t)k * 256];
    }
    g_sdp[ks * 32768 + b * 256 + j] = asd;
    g_sfp[ks * 32768 + b * 256 + j] = asf;
}

// ---------------------------------------------------------------------------
// K2/K4 (MFMA): e[b,t] = vv . tanh( src[b,t,:]@W + add0+add1+abias + cov*wcw )
// Wt is the bf16 transposed weight [n][k]. grid (ceil(R/64), B), block 256.
// Wave w handles rows t0+w*16..+15 (one 16-row M-tile x 16 N-tiles, K=256).
// ---------------------------------------------------------------------------
__global__ __launch_bounds__(256) void k_scores(
    const float* __restrict__ src, int R,
    const u16* __restrict__ Wt,
    const float* __restrict__ addv0,  // s_hat@W partial (K lower half)
    const float* __restrict__ addv1,  // s_hat@W partial (K upper half)
    const float* __restrict__ abias,  // attention bias vector (bd / bf)
    const float* __restrict__ cov,    // nullptr for node attention
    const float* __restrict__ wcw,    // nullptr for node attention
    const float* __restrict__ vv,
    float* __restrict__ eout)
{
    const int b = blockIdx.y, t0 = blockIdx.x * 64;
    const int tid = threadIdx.x;
    const int lane = tid & 63, wave = tid >> 6;
    const int nlow = lane & 15, quad = lane >> 4;
    const int trow = t0 + wave * 16 + nlow;
    const bool tval = trow < R;
    const float* arow = src + ((size_t)b * R + trow) * 256 + quad * 8;
    const u16* brow = Wt + nlow * 256 + quad * 8;

    const f32x4 zf = {0.f, 0.f, 0.f, 0.f};
    f32x4 acc[16];
    #pragma unroll
    for (int i = 0; i < 16; i++) acc[i] = zf;

    for (int k0 = 0; k0 < 256; k0 += 32) {
        bf16x8 af = {0, 0, 0, 0, 0, 0, 0, 0};
        if (tval) af = cvt8(arow + k0);
        #pragma unroll
        for (int nt = 0; nt < 16; nt++) {
            bf16x8 bf = *(const bf16x8*)(brow + nt * 4096 + k0);
            acc[nt] = __builtin_amdgcn_mfma_f32_16x16x32_bf16(af, bf, acc[nt], 0, 0, 0);
        }
    }

    // epilogue: C row = quad*4+r, col = nt*16+nlow
    float covt[4];
    #pragma unroll
    for (int r = 0; r < 4; r++) {
        int t = t0 + wave * 16 + quad * 4 + r;
        covt[r] = (cov && t < R) ? cov[b * R + t] : 0.f;
    }
    float s4[4] = {0.f, 0.f, 0.f, 0.f};
    #pragma unroll
    for (int nt = 0; nt < 16; nt++) {
        int col = nt * 16 + nlow;
        float vvc = vv[col];
        float adc = addv0[b * 256 + col] + addv1[b * 256 + col] + abias[col];
        float wcc = wcw ? wcw[col] : 0.f;
        #pragma unroll
        for (int r = 0; r < 4; r++)
            s4[r] += vvc * fast_tanh(acc[nt][r] + adc + covt[r] * wcc);
    }
    #pragma unroll
    for (int r = 0; r < 4; r++) {
        float s = s4[r];
        s += __shfl_xor(s, 1, 64);
        s += __shfl_xor(s, 2, 64);
        s += __shfl_xor(s, 4, 64);
        s += __shfl_xor(s, 8, 64);
        int t = t0 + wave * 16 + quad * 4 + r;
        if (nlow == 0 && t < R) eout[b * R + t] = s;
    }
}

// ---------------------------------------------------------------------------
// K3: doc softmax (+mask renorm), a, coverage_next, c_d, flow_next.
// ---------------------------------------------------------------------------
__global__ __launch_bounds__(256) void k_doc(
    const float* __restrict__ enc,
    const float* __restrict__ mask,
    const float* __restrict__ cov,
    const float* __restrict__ n2t,
    float* __restrict__ out_a, float* __restrict__ out_cov,
    float* __restrict__ out_cd, float* __restrict__ out_flow)
{
    const int b = blockIdx.x, tid = threadIdx.x;
    __shared__ float as_[TKv];
    __shared__ float red[256];
    __shared__ float fl[NKv];

    float m = -1e30f;
    for (int t = tid; t < TKv; t += 256) m = fmaxf(m, g_e[b * TKv + t]);
    red[tid] = m; __syncthreads();
    for (int s = 128; s > 0; s >>= 1) { if (tid < s) red[tid] = fmaxf(red[tid], red[tid + s]); __syncthreads(); }
    m = red[0]; __syncthreads();

    float ls = 0.f;
    for (int t = tid; t < TKv; t += 256) {
        float p = expf(g_e[b * TKv + t] - m) * mask[b * TKv + t];
        as_[t] = p; ls += p;
    }
    red[tid] = ls; __syncthreads();
    for (int s = 128; s > 0; s >>= 1) { if (tid < s) red[tid] += red[tid + s]; __syncthreads(); }
    float inv = 1.f / red[0]; __syncthreads();

    for (int t = tid; t < TKv; t += 256) {
        float a = as_[t] * inv;
        as_[t] = a;
        g_a[b * TKv + t] = a;
        out_a[b * TKv + t] = a;
        out_cov[b * TKv + t] = cov[b * TKv + t] + a;
    }
    __syncthreads();

    float cd = 0.f;
    const float* eb = enc + (size_t)b * TKv * 256 + tid;
    #pragma unroll 4
    for (int t = 0; t < TKv; t++) cd += as_[t] * eb[(size_t)t * 256];
    g_cd[b * 256 + tid] = cd;
    out_cd[b * 256 + tid] = cd;

    if (tid < NKv) {
        const float* nb = n2t + ((size_t)b * NKv + tid) * TKv;
        float mx = 0.f;
        for (int t = 0; t < TKv; t++) mx = fmaxf(mx, as_[t] * nb[t]);
        fl[tid] = mx;
    }
    __syncthreads();
    float fv = (tid < NKv) ? fl[tid] : 0.f;
    red[tid] = fv; __syncthreads();
    for (int s = 128; s > 0; s >>= 1) { if (tid < s) red[tid] += red[tid + s]; __syncthreads(); }
    float fs = red[0];
    if (tid < NKv) out_flow[b * NKv + tid] = fl[tid] / fs;
}

// ---------------------------------------------------------------------------
// K5: node softmax chain (an, c_g, an2, c_g2, a_n2t), p_gen, out1.
// ---------------------------------------------------------------------------
__global__ __launch_bounds__(256) void k_node(
    const float* __restrict__ encn,
    const float* __restrict__ maskn,
    const float* __restrict__ flow,
    const float* __restrict__ graph,
    const float* __restrict__ n2t,
    const float* __restrict__ Wpg, const float* __restrict__ bpg,
    const float* __restrict__ W1, const float* __restrict__ b1,
    float* __restrict__ out_cg, float* __restrict__ out_cg2,
    float* __restrict__ out_ant, float* __restrict__ out_pgen)
{
    const int b = blockIdx.x, tid = threadIdx.x;
    __shared__ float ans[NKv], an2s[NKv], red[256], cat[1024];

    float v = (tid < NKv) ? g_en[b * NKv + tid] : -1e30f;
    red[tid] = v; __syncthreads();
    for (int s = 128; s > 0; s >>= 1) { if (tid < s) red[tid] = fmaxf(red[tid], red[tid + s]); __syncthreads(); }
    float m = red[0]; __syncthreads();

    float p = (tid < NKv) ? expf(v - m) * maskn[b * NKv + tid] : 0.f;
    red[tid] = p; __syncthreads();
    for (int s = 128; s > 0; s >>= 1) { if (tid < s) red[tid] += red[tid + s]; __syncthreads(); }
    float S = red[0]; __syncthreads();
    p = (tid < NKv) ? (p / S) * flow[b * NKv + tid] : 0.f;
    red[tid] = p; __syncthreads();
    for (int s = 128; s > 0; s >>= 1) { if (tid < s) red[tid] += red[tid + s]; __syncthreads(); }
    float S2 = red[0]; __syncthreads();
    if (tid < NKv) ans[tid] = p / S2;
    __syncthreads();

    float cg = 0.f;
    const float* enb = encn + (size_t)b * NKv * 256 + tid;
    #pragma unroll
    for (int n = 0; n < NKv; n++) cg += ans[n] * enb[n * 256];
    g_cg[b * 256 + tid] = cg;
    out_cg[b * 256 + tid] = cg;

    float q = 0.f;
    if (tid < NKv) {
        const float* gb = graph + (size_t)b * NKv * NKv + tid;
        #pragma unroll
        for (int n = 0; n < NKv; n++) q += ans[n] * gb[n * NKv];
        q *= maskn[b * NKv + tid];
    }
    red[tid] = q; __syncthreads();
    for (int s = 128; s > 0; s >>= 1) { if (tid < s) red[tid] += red[tid + s]; __syncthreads(); }
    float S3 = red[0]; __syncthreads();
    if (tid < NKv) an2s[tid] = q / S3;
    __syncthreads();

    float cg2 = 0.f;
    #pragma unroll
    for (int n = 0; n < NKv; n++) cg2 += an2s[n] * enb[n * 256];
    g_cg2[b * 256 + tid] = cg2;
    out_cg2[b * 256 + tid] = cg2;

    float at0 = 0.f, at1 = 0.f;
    {
        const float* nb = n2t + (size_t)b * NKv * TKv;
        #pragma unroll
        for (int n = 0; n < NKv; n++) {
            float an = ans[n];
            at0 += an * nb[n * TKv + tid];
            if (tid + 256 < TKv) at1 += an * nb[n * TKv + tid + 256];
        }
    }
    float loc = at0 + ((tid + 256 < TKv) ? at1 : 0.f);
    red[tid] = loc; __syncthreads();
    for (int s = 128; s > 0; s >>= 1) { if (tid < s) red[tid] += red[tid + s]; __syncthreads(); }
    float S4 = red[0]; __syncthreads();
    out_ant[b * TKv + tid] = at0 / S4;
    if (tid + 256 < TKv) out_ant[b * TKv + tid + 256] = at1 / S4;

    float hvv = g_h[b * 256 + tid], cvv = g_c[b * 256 + tid];
    float xvv = g_x[b * 256 + tid], cdv = g_cd[b * 256 + tid];
    float part = cdv * Wpg[tid]        + cg  * Wpg[256 + tid]
               + cg2 * Wpg[512 + tid]  + hvv * Wpg[768 + tid]
               + cvv * Wpg[1024 + tid] + xvv * Wpg[1280 + tid];
    red[tid] = part; __syncthreads();
    for (int s = 128; s > 0; s >>= 1) { if (tid < s) red[tid] += red[tid + s]; __syncthreads(); }
    float pg = sigm(red[0] + bpg[0]);
    __syncthreads();
    if (tid == 0) { g_pg[b] = pg; out_pgen[b] = pg; }

    cat[tid] = hvv; cat[256 + tid] = cdv; cat[512 + tid] = cg; cat[768 + tid] = cg2;
    __syncthreads();
    float o = b1[tid];
    const float* w1c = W1 + tid;
    #pragma unroll 4
    for (int k = 0; k < 1024; k++) o += cat[k] * w1c[k * 256];
    g_o1[b * 256 + tid] = o;
}

// ---------------------------------------------------------------------------
// K7 (MFMA): logits = out1[128,256] @ W2[256,50000] + b2 -> g_logits (f32).
// W2t bf16 [VPAD][256]. grid (392): each block does all 128 rows x 128 cols.
// Per wave: 2 M-tiles (32 rows) x 8 N-tiles; acc = 64 VGPRs.
// ---------------------------------------------------------------------------
__global__ __launch_bounds__(256) void k_logits(const float* __restrict__ b2)
{
    const int v0 = blockIdx.x * 128;
    const int tid = threadIdx.x;
    const int lane = tid & 63, wave = tid >> 6;
    const int nlow = lane & 15, quad = lane >> 4;

    const float* a0p = g_o1 + (wave * 32 + nlow) * 256 + quad * 8;
    const float* a1p = a0p + 16 * 256;
    const u16* bbase = g_W2t + (size_t)(v0 + nlow) * 256 + quad * 8;

    const f32x4 zf = {0.f, 0.f, 0.f, 0.f};
    f32x4 acc0[8], acc1[8];
    #pragma unroll
    for (int i = 0; i < 8; i++) { acc0[i] = zf; acc1[i] = zf; }

    for (int k0 = 0; k0 < 256; k0 += 32) {
        bf16x8 a0 = cvt8(a0p + k0);
        bf16x8 a1 = cvt8(a1p + k0);
        #pragma unroll
        for (int nt = 0; nt < 8; nt++) {
            bf16x8 bf = *(const bf16x8*)(bbase + (size_t)nt * 4096 + k0);
            acc0[nt] = __builtin_amdgcn_mfma_f32_16x16x32_bf16(a0, bf, acc0[nt], 0, 0, 0);
            acc1[nt] = __builtin_amdgcn_mfma_f32_16x16x32_bf16(a1, bf, acc1[nt], 0, 0, 0);
        }
    }

    #pragma unroll
    for (int nt = 0; nt < 8; nt++) {
        int v = v0 + nt * 16 + nlow;
        if (v < Vv) {
            float bb = b2[v];
            #pragma unroll
            for (int r = 0; r < 4; r++) {
                int row0 = wave * 32 + quad * 4 + r;
                g_logits[(size_t)row0 * Vv + v]        = acc0[nt][r] + bb;
                g_logits[(size_t)(row0 + 16) * Vv + v] = acc1[nt][r] + bb;
            }
        }
    }
}

// ---------------------------------------------------------------------------
// K8: fused per-row softmax over V (f32 g_logits -> f32 out, scaled by
// p_gen) + row-local pointer scatter (1-pg)*a[b,t] at voc_d[b,t].
// ---------------------------------------------------------------------------
__global__ __launch_bounds__(256) void k_vsoft(
    float* __restrict__ outF, const int* __restrict__ vocd)
{
    const int b = blockIdx.x, tid = threadIdx.x;
    __shared__ float rm[256], rs[256];
    const float* Lb = g_logits + (size_t)b * Vv;
    float* Ob = outF + (size_t)b * Vv;

    float m = -1e30f, s = 0.f;
    for (int v = tid; v < Vv; v += 256) {
        float x = Lb[v];
        if (x > m) { s = s * expf(m - x) + 1.f; m = x; }
        else       { s += expf(x - m); }
    }
    rm[tid] = m; rs[tid] = s; __syncthreads();
    for (int off = 128; off > 0; off >>= 1) {
        if (tid < off) {
            float m1 = rm[tid], m2 = rm[tid + off], s1 = rs[tid], s2 = rs[tid + off];
            float M = fmaxf(m1, m2);
            rs[tid] = s1 * expf(m1 - M) + s2 * expf(m2 - M);
            rm[tid] = M;
        }
        __syncthreads();
    }
    const float M = rm[0];
    const float pg = g_pg[b];
    const float inv = pg / rs[0];
    for (int v = tid; v < Vv; v += 256) Ob[v] = expf(Lb[v] - M) * inv;

    __threadfence();
    __syncthreads();

    const float omp = 1.f - pg;
    for (int t = tid; t < TKv; t += 256)
        atomicAdd(Ob + vocd[b * TKv + t], omp * g_a[b * TKv + t]);
}

// ---------------------------------------------------------------------------

extern "C" void kernel_launch(void* const* d_in, const int* in_sizes, int n_in,
                              void* d_out, int out_size, void* d_ws, size_t ws_size,
                              hipStream_t stream)
{
    (void)in_sizes; (void)n_in; (void)out_size; (void)d_ws; (void)ws_size;

    const int*   y      = (const int*)d_in[0];
    const float* h_prev = (const float*)d_in[1];
    const float* c_prev = (const float*)d_in[2];
    const float* enc    = (const float*)d_in[3];
    const float* encn   = (const float*)d_in[4];
    const float* mask   = (const float*)d_in[5];
    const float* maskn  = (const float*)d_in[6];
    const float* ctd    = (const float*)d_in[7];
    const float* ctg    = (const float*)d_in[8];
    const float* ctg2   = (const float*)d_in[9];
    const float* cov    = (const float*)d_in[10];
    const float* flow   = (const float*)d_in[11];
    const float* n2t    = (const float*)d_in[12];
    const float* graph  = (const float*)d_in[13];
    const int*   vocd   = (const int*)d_in[14];
    // d_in[15] = step (unused)
    const float* emb    = (const float*)d_in[16];
    const float* Wx     = (const float*)d_in[17];
    const float* bx     = (const float*)d_in[18];
    const float* Wi     = (const float*)d_in[19];
    const float* Wh     = (const float*)d_in[20];
    const float* bi     = (const float*)d_in[21];
    const float* bh     = (const float*)d_in[22];
    const float* Whd    = (const float*)d_in[23];
    const float* Wsd    = (const float*)d_in[24];
    const float* wcdw   = (const float*)d_in[25];
    const float* vd     = (const float*)d_in[26];
    const float* bd     = (const float*)d_in[27];
    const float* Wn     = (const float*)d_in[28];
    const float* Wsf    = (const float*)d_in[29];
    const float* vf     = (const float*)d_in[30];
    const float* bfv    = (const float*)d_in[31];
    const float* Wpg    = (const float*)d_in[32];
    const float* bpg    = (const float*)d_in[33];
    const float* W1     = (const float*)d_in[34];
    const float* b1     = (const float*)d_in[35];
    const float* W2     = (const float*)d_in[36];
    const float* b2     = (const float*)d_in[37];

    float* o = (float*)d_out;                 // FLOAT32 output
    float* o_final = o;                       // 6,400,000
    float* o_h     = o + 6400000;
    float* o_c     = o + 6432768;
    float* o_cd    = o + 6465536;
    float* o_cg    = o + 6498304;
    float* o_cg2   = o + 6531072;
    float* o_a     = o + 6563840;
    float* o_ant   = o + 6615040;
    float* o_pg    = o + 6666240;
    float* o_cov   = o + 6666368;
    float* o_fl    = o + 6717568;

    float* g_e_p;   hipGetSymbolAddress((void**)&g_e_p,   HIP_SYMBOL(g_e));
    float* g_en_p;  hipGetSymbolAddress((void**)&g_en_p,  HIP_SYMBOL(g_en));
    float* g_sdp_p; hipGetSymbolAddress((void**)&g_sdp_p, HIP_SYMBOL(g_sdp));
    float* g_sfp_p; hipGetSymbolAddress((void**)&g_sfp_p, HIP_SYMBOL(g_sfp));
    u16*   g_Wdt_p; hipGetSymbolAddress((void**)&g_Wdt_p, HIP_SYMBOL(g_Wdt));
    u16*   g_Wnt_p; hipGetSymbolAddress((void**)&g_Wnt_p, HIP_SYMBOL(g_Wnt));
    u16*   g_W2t_p; hipGetSymbolAddress((void**)&g_W2t_p, HIP_SYMBOL(g_W2t));

    // transpose-cast weights to bf16 [n][k]
    k_tc<<<dim3(8, 8), dim3(256), 0, stream>>>(Whd, g_Wdt_p, 256, 256);
    k_tc<<<dim3(8, 8), dim3(256), 0, stream>>>(Wn,  g_Wnt_p, 256, 256);
    k_tc<<<dim3(VPAD / 32, 8), dim3(256), 0, stream>>>(W2, g_W2t_p, 256, Vv);

    // LSTM front-end, latency-optimized: 512/512/256 blocks
    k_x<<<dim3(Bv, 4), dim3(256), 0, stream>>>(y, ctd, ctg, ctg2, emb, Wx);

    k_gates<<<dim3(Bv, 4), dim3(256), 0, stream>>>(h_prev, Wi, Wh, bi, bh, bx);

    k_cellsd<<<dim3(Bv, 2), dim3(256), 0, stream>>>(c_prev, Wsd, Wsf, o_h, o_c);

    k_scores<<<dim3(7, Bv), dim3(256), 0, stream>>>(
        enc, TKv, g_Wdt_p, g_sdp_p, g_sdp_p + 32768, bd, cov, wcdw, vd, g_e_p);

    k_scores<<<dim3(1, Bv), dim3(256), 0, stream>>>(
        encn, NKv, g_Wnt_p, g_sfp_p, g_sfp_p + 32768, bfv,
        nullptr, nullptr, vf, g_en_p);

    k_doc<<<dim3(Bv), dim3(256), 0, stream>>>(
        enc, mask, cov, n2t, o_a, o_cov, o_cd, o_fl);

    k_node<<<dim3(Bv), dim3(256), 0, stream>>>(
        encn, maskn, flow, graph, n2t, Wpg, bpg, W1, b1,
        o_cg, o_cg2, o_ant, o_pg);

    k_logits<<<dim3(VPAD / 128), dim3(256), 0, stream>>>(b2);

    k_vsoft<<<dim3(Bv), dim3(256), 0, stream>>>(o_final, vocd);
}

// Round 2
// 629.361 us; speedup vs baseline: 1.5600x; 1.1860x over previous
//
#include <hip/hip_runtime.h>
#include <stdint.h>

// ---------------------------------------------------------------------------
// LSTM pointer-generator decoder step, B=128 TK=400 NK=50 H=E=256 V=50000.
// Round 8: kill the latency-bound k_node (131 us, VALUBusy 1.3%, occ 5.8%)
// and the structurally-identical parts of k_doc. Same playbook as R7's
// k_pre split: out1 GEMM -> k_o1 (B,4 col-chunks x 4 K-quarter threads),
// c_d -> k_cd (B,2 t-split partials), flow -> k_flow (50 nodes x 4 thr),
// k_doc reduced to softmax/a/coverage, k_node1 keeps the short 50-length
// chains (fully unrolled, cg+cg2 share one enb pass) + p_gen.
// k_tc/k_x/k_gates/k_cellsd/k_scores/k_logits/k_vsoft unchanged.
// ---------------------------------------------------------------------------

typedef unsigned short u16;
typedef unsigned int   u32;

#define Bv  128
#define TKv 400
#define NKv 50
#define Hv  256
#define Vv  50000
#define VPAD 50176   // 50000 padded to multiple of 128

typedef __attribute__((ext_vector_type(8))) short bf16x8;
typedef __attribute__((ext_vector_type(4))) float f32x4;

// ---- module-global workspace (no d_ws dependency) -------------------------
__device__ float g_x[32768];      // x = cat @ Wx + bx
__device__ float g_xp[4 * 32768]; // x K-partials
__device__ float g_gates[131072]; // LSTM gates [B,4H]
__device__ float g_h[32768];      // h_new
__device__ float g_c[32768];      // c_new
__device__ float g_sdp[2 * 32768];// s_hat@Wsd partials (no bias)
__device__ float g_sfp[2 * 32768];// s_hat@Wsf partials (no bias)
__device__ float g_e[51200];      // doc scores
__device__ float g_en[6400];      // node scores
__device__ float g_a[51200];      // doc attention a
__device__ float g_cd[32768];     // c_d
__device__ float g_cdp[2 * 32768];// c_d t-split partials
__device__ float g_cg[32768];     // c_g
__device__ float g_cg2[32768];    // c_g2
__device__ float g_pg[128];       // p_gen
__device__ float g_o1[32768];     // out1
__device__ float g_logits[6400000];        // f32 logits (25.6 MB)
__device__ u16   g_Wdt[256 * 256];         // Whd^T bf16 [n][k]
__device__ u16   g_Wnt[256 * 256];         // Wn^T  bf16 [n][k]
__device__ u16   g_W2t[(size_t)VPAD * 256];// W2^T  bf16 [v][k] (25.7 MB)

__device__ __forceinline__ float sigm(float x) { return 1.f / (1.f + expf(-x)); }

__device__ __forceinline__ u16 f2bf(float f) {
    u32 u = __float_as_uint(f);
    return (u16)((u + 0x7fffu + ((u >> 16) & 1u)) >> 16);  // RNE
}

__device__ __forceinline__ bf16x8 cvt8(const float* __restrict__ p) {
    const float4 a = *(const float4*)p;
    const float4 b = *(const float4*)(p + 4);
    bf16x8 r;
    r[0] = (short)f2bf(a.x); r[1] = (short)f2bf(a.y);
    r[2] = (short)f2bf(a.z); r[3] = (short)f2bf(a.w);
    r[4] = (short)f2bf(b.x); r[5] = (short)f2bf(b.y);
    r[6] = (short)f2bf(b.z); r[7] = (short)f2bf(b.w);
    return r;
}

// tanh via exp; clamp so exp never overflows (tanh saturated anyway)
__device__ __forceinline__ float fast_tanh(float x) {
    x = fminf(fmaxf(x, -15.f), 15.f);
    float e = __expf(2.f * x);
    return (e - 1.f) / (e + 1.f);
}

// ---------------------------------------------------------------------------
// K0: transpose-cast  src[K][N] f32  ->  dst[n][k] bf16.
// grid = (Npad/32, K/32), block 256 (32x8). Reads n>=N give 0 (pad rows).
// ---------------------------------------------------------------------------
__global__ __launch_bounds__(256) void k_tc(
    const float* __restrict__ src, u16* __restrict__ dst, int K, int N)
{
    __shared__ float tile[32][33];
    const int n0 = blockIdx.x * 32, k0 = blockIdx.y * 32;
    const int tx = threadIdx.x & 31, ty = threadIdx.x >> 5;
    #pragma unroll
    for (int i = 0; i < 32; i += 8) {
        int k = k0 + ty + i, n = n0 + tx;
        tile[ty + i][tx] = (n < N) ? src[(size_t)k * N + n] : 0.f;
    }
    __syncthreads();
    #pragma unroll
    for (int i = 0; i < 32; i += 8) {
        int n = n0 + ty + i, k = k0 + tx;
        dst[(size_t)n * K + k] = f2bf(tile[tx][ty + i]);
    }
}

// ---------------------------------------------------------------------------
// K1a: x K-partials. grid (B, 4): block (b, ks) stages cat-chunk ks in LDS,
// computes partial x over its 256-row slice of Wx. 512 blocks = 2 waves/SIMD.
// ---------------------------------------------------------------------------
__global__ __launch_bounds__(256) void k_x(
    const int* __restrict__ y,
    const float* __restrict__ ctd, const float* __restrict__ ctg,
    const float* __restrict__ ctg2, const float* __restrict__ emb,
    const float* __restrict__ Wx)
{
    const int b = blockIdx.x, ks = blockIdx.y, j = threadIdx.x;
    __shared__ float cs[256];
    float v;
    if      (ks == 0) v = ctd [b * 256 + j];
    else if (ks == 1) v = ctg [b * 256 + j];
    else if (ks == 2) v = ctg2[b * 256 + j];
    else              v = emb[(size_t)y[b] * 256 + j];
    cs[j] = v;
    __syncthreads();

    float acc = 0.f;
    const float* w = Wx + (size_t)(ks * 256) * 256 + j;
    #pragma unroll 8
    for (int k = 0; k < 256; k++) acc += cs[k] * w[(size_t)k * 256];
    g_xp[ks * 32768 + b * 256 + j] = acc;
}

// ---------------------------------------------------------------------------
// K1b: gates = x@Wi + h@Wh + bi + bh. grid (B, 4 col-chunks), fully
// output-parallel (no atomics). Sums the 4 x-partials + bx while staging
// (col-chunk 0 also publishes g_x for k_node1's p_gen).
// ---------------------------------------------------------------------------
__global__ __launch_bounds__(256) void k_gates(
    const float* __restrict__ h_prev,
    const float* __restrict__ Wi, const float* __restrict__ Wh,
    const float* __restrict__ bi, const float* __restrict__ bh,
    const float* __restrict__ bx)
{
    const int b = blockIdx.x, cc = blockIdx.y, j = threadIdx.x;
    __shared__ float xs[256], hs[256];

    float xv = bx[j] + g_xp[b * 256 + j] + g_xp[32768 + b * 256 + j]
             + g_xp[65536 + b * 256 + j] + g_xp[98304 + b * 256 + j];
    xs[j] = xv;
    if (cc == 0) g_x[b * 256 + j] = xv;
    hs[j] = h_prev[b * 256 + j];
    __syncthreads();

    const int col = cc * 256 + j;
    float acc = bi[col] + bh[col];
    const float* wi = Wi + col;
    const float* wh = Wh + col;
    #pragma unroll 8
    for (int k = 0; k < 256; k++)
        acc += xs[k] * wi[(size_t)k * 1024] + hs[k] * wh[(size_t)k * 1024];
    g_gates[b * 1024 + col] = acc;
}

// ---------------------------------------------------------------------------
// K1c: LSTM elementwise + sd/sf K-partials. grid (B, 2): both K-halves
// redundantly compute the cheap cell update; ks==0 publishes h/c. Each block
// stages its half of s_hat=[h|c] and emits sd/sf partials (bias deferred to
// the k_scores epilogue).
// ---------------------------------------------------------------------------
__global__ __launch_bounds__(256) void k_cellsd(
    const float* __restrict__ c_prev,
    const float* __restrict__ Wsd, const float* __restrict__ Wsf,
    float* __restrict__ out_h, float* __restrict__ out_c)
{
    const int b = blockIdx.x, ks = blockIdx.y, j = threadIdx.x;
    __shared__ float sh[256];

    const float* gb = g_gates + b * 1024;
    float gi_ = gb[j], gf_ = gb[256 + j], gg_ = gb[512 + j], go_ = gb[768 + j];
    float cp = c_prev[b * 256 + j];
    float cn = sigm(gf_) * cp + sigm(gi_) * tanhf(gg_);
    float hn = sigm(go_) * tanhf(cn);
    if (ks == 0) {
        g_h[b * 256 + j] = hn;  g_c[b * 256 + j] = cn;
        out_h[b * 256 + j] = hn; out_c[b * 256 + j] = cn;
    }
    sh[j] = (ks == 0) ? hn : cn;   // s_hat rows [0,256) = h, [256,512) = c
    __syncthreads();

    float asd = 0.f, asf = 0.f;
    const float* wd = Wsd + (size_t)(ks * 256) * 256 + j;
    const float* wf = Wsf + (size_t)(ks * 256) * 256 + j;
    #pragma unroll 8
    for (int k = 0; k < 256; k++) {
        float sv = sh[k];
        asd += sv * wd[(size_t)k * 256];
        asf += sv * wf[(size_t)k * 256];
    }
    g_sdp[ks * 32768 + b * 256 + j] = asd;
    g_sfp[ks * 32768 + b * 256 + j] = asf;
}

// ---------------------------------------------------------------------------
// K2/K4 (MFMA): e[b,t] = vv . tanh( src[b,t,:]@W + add0+add1+abias + cov*wcw )
// Wt is the bf16 transposed weight [n][k]. grid (ceil(R/64), B), block 256.
// Wave w handles rows t0+w*16..+15 (one 16-row M-tile x 16 N-tiles, K=256).
// ---------------------------------------------------------------------------
__global__ __launch_bounds__(256) void k_scores(
    const float* __restrict__ src, int R,
    const u16* __restrict__ Wt,
    const float* __restrict__ addv0,  // s_hat@W partial (K lower half)
    const float* __restrict__ addv1,  // s_hat@W partial (K upper half)
    const float* __restrict__ abias,  // attention bias vector (bd / bf)
    const float* __restrict__ cov,    // nullptr for node attention
    const float* __restrict__ wcw,    // nullptr for node attention
    const float* __restrict__ vv,
    float* __restrict__ eout)
{
    const int b = blockIdx.y, t0 = blockIdx.x * 64;
    const int tid = threadIdx.x;
    const int lane = tid & 63, wave = tid >> 6;
    const int nlow = lane & 15, quad = lane >> 4;
    const int trow = t0 + wave * 16 + nlow;
    const bool tval = trow < R;
    const float* arow = src + ((size_t)b * R + trow) * 256 + quad * 8;
    const u16* brow = Wt + nlow * 256 + quad * 8;

    const f32x4 zf = {0.f, 0.f, 0.f, 0.f};
    f32x4 acc[16];
    #pragma unroll
    for (int i = 0; i < 16; i++) acc[i] = zf;

    for (int k0 = 0; k0 < 256; k0 += 32) {
        bf16x8 af = {0, 0, 0, 0, 0, 0, 0, 0};
        if (tval) af = cvt8(arow + k0);
        #pragma unroll
        for (int nt = 0; nt < 16; nt++) {
            bf16x8 bf = *(const bf16x8*)(brow + nt * 4096 + k0);
            acc[nt] = __builtin_amdgcn_mfma_f32_16x16x32_bf16(af, bf, acc[nt], 0, 0, 0);
        }
    }

    // epilogue: C row = quad*4+r, col = nt*16+nlow
    float covt[4];
    #pragma unroll
    for (int r = 0; r < 4; r++) {
        int t = t0 + wave * 16 + quad * 4 + r;
        covt[r] = (cov && t < R) ? cov[b * R + t] : 0.f;
    }
    float s4[4] = {0.f, 0.f, 0.f, 0.f};
    #pragma unroll
    for (int nt = 0; nt < 16; nt++) {
        int col = nt * 16 + nlow;
        float vvc = vv[col];
        float adc = addv0[b * 256 + col] + addv1[b * 256 + col] + abias[col];
        float wcc = wcw ? wcw[col] : 0.f;
        #pragma unroll
        for (int r = 0; r < 4; r++)
            s4[r] += vvc * fast_tanh(acc[nt][r] + adc + covt[r] * wcc);
    }
    #pragma unroll
    for (int r = 0; r < 4; r++) {
        float s = s4[r];
        s += __shfl_xor(s, 1, 64);
        s += __shfl_xor(s, 2, 64);
        s += __shfl_xor(s, 4, 64);
        s += __shfl_xor(s, 8, 64);
        int t = t0 + wave * 16 + quad * 4 + r;
        if (nlow == 0 && t < R) eout[b * R + t] = s;
    }
}

// ---------------------------------------------------------------------------
// K3: doc softmax (+mask renorm) only: a, coverage_next. Fully t-parallel.
// ---------------------------------------------------------------------------
__global__ __launch_bounds__(256) void k_doc(
    const float* __restrict__ mask,
    const float* __restrict__ cov,
    float* __restrict__ out_a, float* __restrict__ out_cov)
{
    const int b = blockIdx.x, tid = threadIdx.x;
    __shared__ float red[256];

    float e0 = g_e[b * TKv + tid];
    float e1 = (tid + 256 < TKv) ? g_e[b * TKv + tid + 256] : -1e30f;

    float m = fmaxf(e0, e1);
    red[tid] = m; __syncthreads();
    for (int s = 128; s > 0; s >>= 1) { if (tid < s) red[tid] = fmaxf(red[tid], red[tid + s]); __syncthreads(); }
    m = red[0]; __syncthreads();

    float p0 = expf(e0 - m) * mask[b * TKv + tid];
    float p1 = (tid + 256 < TKv) ? expf(e1 - m) * mask[b * TKv + tid + 256] : 0.f;
    red[tid] = p0 + p1; __syncthreads();
    for (int s = 128; s > 0; s >>= 1) { if (tid < s) red[tid] += red[tid + s]; __syncthreads(); }
    float inv = 1.f / red[0];

    float a0 = p0 * inv;
    g_a[b * TKv + tid] = a0;
    out_a[b * TKv + tid] = a0;
    out_cov[b * TKv + tid] = cov[b * TKv + tid] + a0;
    if (tid + 256 < TKv) {
        float a1 = p1 * inv;
        g_a[b * TKv + tid + 256] = a1;
        out_a[b * TKv + tid + 256] = a1;
        out_cov[b * TKv + tid + 256] = cov[b * TKv + tid + 256] + a1;
    }
}

// ---------------------------------------------------------------------------
// K3b: c_d t-split partials. grid (B, 2): block (b,ks) stages its 200-elem
// a-chunk in LDS, each thread does 200 serial MACs over enc (unroll 8).
// ---------------------------------------------------------------------------
__global__ __launch_bounds__(256) void k_cd(const float* __restrict__ enc)
{
    const int b = blockIdx.x, ks = blockIdx.y, tid = threadIdx.x;
    __shared__ float as_[200];
    if (tid < 200) as_[tid] = g_a[b * TKv + ks * 200 + tid];
    __syncthreads();

    const float* eb = enc + ((size_t)b * TKv + ks * 200) * 256 + tid;
    float acc = 0.f;
    #pragma unroll 8
    for (int t = 0; t < 200; t++) acc += as_[t] * eb[(size_t)t * 256];
    g_cdp[ks * 32768 + b * 256 + tid] = acc;
}

// ---------------------------------------------------------------------------
// K3c: flow_next. grid (B): 50 nodes x 4 threads (t-quarters of 100),
// shuffle-max across the 4, block-sum over 50, normalized write.
// ---------------------------------------------------------------------------
__global__ __launch_bounds__(256) void k_flow(
    const float* __restrict__ n2t, float* __restrict__ out_flow)
{
    const int b = blockIdx.x, tid = threadIdx.x;
    __shared__ float as_[TKv];
    __shared__ float fl[NKv];
    __shared__ float red[256];

    for (int t = tid; t < TKv; t += 256) as_[t] = g_a[b * TKv + t];
    __syncthreads();

    const int nn = tid >> 2, sub = tid & 3;
    float mx = 0.f;
    if (nn < NKv) {
        const float* nb = n2t + ((size_t)b * NKv + nn) * TKv + sub * 100;
        const float* ab = as_ + sub * 100;
        #pragma unroll 4
        for (int t = 0; t < 100; t++) mx = fmaxf(mx, ab[t] * nb[t]);
    }
    mx = fmaxf(mx, __shfl_xor(mx, 1, 64));
    mx = fmaxf(mx, __shfl_xor(mx, 2, 64));
    if (sub == 0 && nn < NKv) fl[nn] = mx;
    __syncthreads();

    float fv = (tid < NKv) ? fl[tid] : 0.f;
    red[tid] = fv; __syncthreads();
    for (int s = 128; s > 0; s >>= 1) { if (tid < s) red[tid] += red[tid + s]; __syncthreads(); }
    float fs = red[0];
    if (tid < NKv) out_flow[b * NKv + tid] = fl[tid] / fs;
}

// ---------------------------------------------------------------------------
// K5: node softmax chain (an, c_g, an2, c_g2, a_n2t), cd-partial sum, p_gen.
// All 50-length loops fully unrolled so loads pipeline; cg+cg2 share one
// enb pass. out1 moved to k_o1.
// ---------------------------------------------------------------------------
__global__ __launch_bounds__(256) void k_node1(
    const float* __restrict__ encn,
    const float* __restrict__ maskn,
    const float* __restrict__ flow,
    const float* __restrict__ graph,
    const float* __restrict__ n2t,
    const float* __restrict__ Wpg, const float* __restrict__ bpg,
    float* __restrict__ out_cd, float* __restrict__ out_cg,
    float* __restrict__ out_cg2, float* __restrict__ out_ant,
    float* __restrict__ out_pgen)
{
    const int b = blockIdx.x, tid = threadIdx.x;
    __shared__ float ans[NKv], an2s[NKv], red[256];

    // c_d = sum of t-split partials
    const float cd = g_cdp[b * 256 + tid] + g_cdp[32768 + b * 256 + tid];
    g_cd[b * 256 + tid] = cd;
    out_cd[b * 256 + tid] = cd;

    // node softmax -> flow-weighted renorm
    float v = (tid < NKv) ? g_en[b * NKv + tid] : -1e30f;
    red[tid] = v; __syncthreads();
    for (int s = 128; s > 0; s >>= 1) { if (tid < s) red[tid] = fmaxf(red[tid], red[tid + s]); __syncthreads(); }
    float m = red[0]; __syncthreads();

    float p = (tid < NKv) ? expf(v - m) * maskn[b * NKv + tid] : 0.f;
    red[tid] = p; __syncthreads();
    for (int s = 128; s > 0; s >>= 1) { if (tid < s) red[tid] += red[tid + s]; __syncthreads(); }
    float S = red[0]; __syncthreads();
    p = (tid < NKv) ? (p / S) * flow[b * NKv + tid] : 0.f;
    red[tid] = p; __syncthreads();
    for (int s = 128; s > 0; s >>= 1) { if (tid < s) red[tid] += red[tid + s]; __syncthreads(); }
    float S2 = red[0]; __syncthreads();
    if (tid < NKv) ans[tid] = p / S2;
    __syncthreads();

    // an2 = (ans @ graph) * mask, renormalized
    float q = 0.f;
    if (tid < NKv) {
        const float* gb = graph + (size_t)b * NKv * NKv + tid;
        #pragma unroll
        for (int n = 0; n < NKv; n++) q += ans[n] * gb[n * NKv];
        q *= maskn[b * NKv + tid];
    }
    red[tid] = q; __syncthreads();
    for (int s = 128; s > 0; s >>= 1) { if (tid < s) red[tid] += red[tid + s]; __syncthreads(); }
    float S3 = red[0]; __syncthreads();
    if (tid < NKv) an2s[tid] = q / S3;
    __syncthreads();

    // c_g and c_g2 in one pass over encn
    float cg = 0.f, cg2 = 0.f;
    {
        const float* enb = encn + (size_t)b * NKv * 256 + tid;
        #pragma unroll
        for (int n = 0; n < NKv; n++) {
            float e = enb[n * 256];
            cg  += ans[n]  * e;
            cg2 += an2s[n] * e;
        }
    }
    g_cg[b * 256 + tid] = cg;   out_cg[b * 256 + tid] = cg;
    g_cg2[b * 256 + tid] = cg2; out_cg2[b * 256 + tid] = cg2;

    // a_n2t with normalization
    float at0 = 0.f, at1 = 0.f;
    {
        const float* nb = n2t + (size_t)b * NKv * TKv;
        #pragma unroll
        for (int n = 0; n < NKv; n++) {
            float an = ans[n];
            at0 += an * nb[n * TKv + tid];
            if (tid + 256 < TKv) at1 += an * nb[n * TKv + tid + 256];
        }
    }
    float loc = at0 + ((tid + 256 < TKv) ? at1 : 0.f);
    red[tid] = loc; __syncthreads();
    for (int s = 128; s > 0; s >>= 1) { if (tid < s) red[tid] += red[tid + s]; __syncthreads(); }
    float S4 = red[0]; __syncthreads();
    out_ant[b * TKv + tid] = at0 / S4;
    if (tid + 256 < TKv) out_ant[b * TKv + tid + 256] = at1 / S4;

    // p_gen
    float hvv = g_h[b * 256 + tid], cvv = g_c[b * 256 + tid];
    float xvv = g_x[b * 256 + tid];
    float part = cd  * Wpg[tid]        + cg  * Wpg[256 + tid]
               + cg2 * Wpg[512 + tid]  + hvv * Wpg[768 + tid]
               + cvv * Wpg[1024 + tid] + xvv * Wpg[1280 + tid];
    red[tid] = part; __syncthreads();
    for (int s = 128; s > 0; s >>= 1) { if (tid < s) red[tid] += red[tid + s]; __syncthreads(); }
    if (tid == 0) {
        float pg = sigm(red[0] + bpg[0]);
        g_pg[b] = pg; out_pgen[b] = pg;
    }
}

// ---------------------------------------------------------------------------
// K6: out1 = [h|cd|cg|cg2] @ W1 + b1. grid (B, 4 col-chunks of 64).
// Thread (kq, lane): kq = tid>>6 K-quarter, lane picks output col; 256
// serial MACs each (unroll 8), LDS cross-kq reduce.
// ---------------------------------------------------------------------------
__global__ __launch_bounds__(256) void k_o1(
    const float* __restrict__ W1, const float* __restrict__ b1)
{
    const int b = blockIdx.x, cc = blockIdx.y, tid = threadIdx.x;
    __shared__ float cat[1024];
    __shared__ float red[256];

    cat[tid]       = g_h  [b * 256 + tid];
    cat[256 + tid] = g_cd [b * 256 + tid];
    cat[512 + tid] = g_cg [b * 256 + tid];
    cat[768 + tid] = g_cg2[b * 256 + tid];
    __syncthreads();

    const int lane = tid & 63, kq = tid >> 6;
    const int col = cc * 64 + lane;
    const float* w  = W1 + (size_t)(kq * 256) * 256 + col;
    const float* cs = cat + kq * 256;
    float acc = 0.f;
    #pragma unroll 8
    for (int k = 0; k < 256; k++) acc += cs[k] * w[(size_t)k * 256];
    red[tid] = acc; __syncthreads();

    if (tid < 64) {
        float o = b1[cc * 64 + tid]
                + red[tid] + red[64 + tid] + red[128 + tid] + red[192 + tid];
        g_o1[b * 256 + cc * 64 + tid] = o;
    }
}

// ---------------------------------------------------------------------------
// K7 (MFMA): logits = out1[128,256] @ W2[256,50000] + b2 -> g_logits (f32).
// W2t bf16 [VPAD][256]. grid (392): each block does all 128 rows x 128 cols.
// Per wave: 2 M-tiles (32 rows) x 8 N-tiles; acc = 64 VGPRs.
// ---------------------------------------------------------------------------
__global__ __launch_bounds__(256) void k_logits(const float* __restrict__ b2)
{
    const int v0 = blockIdx.x * 128;
    const int tid = threadIdx.x;
    const int lane = tid & 63, wave = tid >> 6;
    const int nlow = lane & 15, quad = lane >> 4;

    const float* a0p = g_o1 + (wave * 32 + nlow) * 256 + quad * 8;
    const float* a1p = a0p + 16 * 256;
    const u16* bbase = g_W2t + (size_t)(v0 + nlow) * 256 + quad * 8;

    const f32x4 zf = {0.f, 0.f, 0.f, 0.f};
    f32x4 acc0[8], acc1[8];
    #pragma unroll
    for (int i = 0; i < 8; i++) { acc0[i] = zf; acc1[i] = zf; }

    for (int k0 = 0; k0 < 256; k0 += 32) {
        bf16x8 a0 = cvt8(a0p + k0);
        bf16x8 a1 = cvt8(a1p + k0);
        #pragma unroll
        for (int nt = 0; nt < 8; nt++) {
            bf16x8 bf = *(const bf16x8*)(bbase + (size_t)nt * 4096 + k0);
            acc0[nt] = __builtin_amdgcn_mfma_f32_16x16x32_bf16(a0, bf, acc0[nt], 0, 0, 0);
            acc1[nt] = __builtin_amdgcn_mfma_f32_16x16x32_bf16(a1, bf, acc1[nt], 0, 0, 0);
        }
    }

    #pragma unroll
    for (int nt = 0; nt < 8; nt++) {
        int v = v0 + nt * 16 + nlow;
        if (v < Vv) {
            float bb = b2[v];
            #pragma unroll
            for (int r = 0; r < 4; r++) {
                int row0 = wave * 32 + quad * 4 + r;
                g_logits[(size_t)row0 * Vv + v]        = acc0[nt][r] + bb;
                g_logits[(size_t)(row0 + 16) * Vv + v] = acc1[nt][r] + bb;
            }
        }
    }
}

// ---------------------------------------------------------------------------
// K8: fused per-row softmax over V (f32 g_logits -> f32 out, scaled by
// p_gen) + row-local pointer scatter (1-pg)*a[b,t] at voc_d[b,t].
// ---------------------------------------------------------------------------
__global__ __launch_bounds__(256) void k_vsoft(
    float* __restrict__ outF, const int* __restrict__ vocd)
{
    const int b = blockIdx.x, tid = threadIdx.x;
    __shared__ float rm[256], rs[256];
    const float* Lb = g_logits + (size_t)b * Vv;
    float* Ob = outF + (size_t)b * Vv;

    float m = -1e30f, s = 0.f;
    for (int v = tid; v < Vv; v += 256) {
        float x = Lb[v];
        if (x > m) { s = s * expf(m - x) + 1.f; m = x; }
        else       { s += expf(x - m); }
    }
    rm[tid] = m; rs[tid] = s; __syncthreads();
    for (int off = 128; off > 0; off >>= 1) {
        if (tid < off) {
            float m1 = rm[tid], m2 = rm[tid + off], s1 = rs[tid], s2 = rs[tid + off];
            float M = fmaxf(m1, m2);
            rs[tid] = s1 * expf(m1 - M) + s2 * expf(m2 - M);
            rm[tid] = M;
        }
        __syncthreads();
    }
    const float M = rm[0];
    const float pg = g_pg[b];
    const float inv = pg / rs[0];
    for (int v = tid; v < Vv; v += 256) Ob[v] = expf(Lb[v] - M) * inv;

    __threadfence();
    __syncthreads();

    const float omp = 1.f - pg;
    for (int t = tid; t < TKv; t += 256)
        atomicAdd(Ob + vocd[b * TKv + t], omp * g_a[b * TKv + t]);
}

// ---------------------------------------------------------------------------

extern "C" void kernel_launch(void* const* d_in, const int* in_sizes, int n_in,
                              void* d_out, int out_size, void* d_ws, size_t ws_size,
                              hipStream_t stream)
{
    (void)in_sizes; (void)n_in; (void)out_size; (void)d_ws; (void)ws_size;

    const int*   y      = (const int*)d_in[0];
    const float* h_prev = (const float*)d_in[1];
    const float* c_prev = (const float*)d_in[2];
    const float* enc    = (const float*)d_in[3];
    const float* encn   = (const float*)d_in[4];
    const float* mask   = (const float*)d_in[5];
    const float* maskn  = (const float*)d_in[6];
    const float* ctd    = (const float*)d_in[7];
    const float* ctg    = (const float*)d_in[8];
    const float* ctg2   = (const float*)d_in[9];
    const float* cov    = (const float*)d_in[10];
    const float* flow   = (const float*)d_in[11];
    const float* n2t    = (const float*)d_in[12];
    const float* graph  = (const float*)d_in[13];
    const int*   vocd   = (const int*)d_in[14];
    // d_in[15] = step (unused)
    const float* emb    = (const float*)d_in[16];
    const float* Wx     = (const float*)d_in[17];
    const float* bx     = (const float*)d_in[18];
    const float* Wi     = (const float*)d_in[19];
    const float* Wh     = (const float*)d_in[20];
    const float* bi     = (const float*)d_in[21];
    const float* bh     = (const float*)d_in[22];
    const float* Whd    = (const float*)d_in[23];
    const float* Wsd    = (const float*)d_in[24];
    const float* wcdw   = (const float*)d_in[25];
    const float* vd     = (const float*)d_in[26];
    const float* bd     = (const float*)d_in[27];
    const float* Wn     = (const float*)d_in[28];
    const float* Wsf    = (const float*)d_in[29];
    const float* vf     = (const float*)d_in[30];
    const float* bfv    = (const float*)d_in[31];
    const float* Wpg    = (const float*)d_in[32];
    const float* bpg    = (const float*)d_in[33];
    const float* W1     = (const float*)d_in[34];
    const float* b1     = (const float*)d_in[35];
    const float* W2     = (const float*)d_in[36];
    const float* b2     = (const float*)d_in[37];

    float* o = (float*)d_out;                 // FLOAT32 output
    float* o_final = o;                       // 6,400,000
    float* o_h     = o + 6400000;
    float* o_c     = o + 6432768;
    float* o_cd    = o + 6465536;
    float* o_cg    = o + 6498304;
    float* o_cg2   = o + 6531072;
    float* o_a     = o + 6563840;
    float* o_ant   = o + 6615040;
    float* o_pg    = o + 6666240;
    float* o_cov   = o + 6666368;
    float* o_fl    = o + 6717568;

    float* g_e_p;   hipGetSymbolAddress((void**)&g_e_p,   HIP_SYMBOL(g_e));
    float* g_en_p;  hipGetSymbolAddress((void**)&g_en_p,  HIP_SYMBOL(g_en));
    float* g_sdp_p; hipGetSymbolAddress((void**)&g_sdp_p, HIP_SYMBOL(g_sdp));
    float* g_sfp_p; hipGetSymbolAddress((void**)&g_sfp_p, HIP_SYMBOL(g_sfp));
    u16*   g_Wdt_p; hipGetSymbolAddress((void**)&g_Wdt_p, HIP_SYMBOL(g_Wdt));
    u16*   g_Wnt_p; hipGetSymbolAddress((void**)&g_Wnt_p, HIP_SYMBOL(g_Wnt));
    u16*   g_W2t_p; hipGetSymbolAddress((void**)&g_W2t_p, HIP_SYMBOL(g_W2t));

    // transpose-cast weights to bf16 [n][k]
    k_tc<<<dim3(8, 8), dim3(256), 0, stream>>>(Whd, g_Wdt_p, 256, 256);
    k_tc<<<dim3(8, 8), dim3(256), 0, stream>>>(Wn,  g_Wnt_p, 256, 256);
    k_tc<<<dim3(VPAD / 32, 8), dim3(256), 0, stream>>>(W2, g_W2t_p, 256, Vv);

    // LSTM front-end, latency-optimized: 512/512/256 blocks
    k_x<<<dim3(Bv, 4), dim3(256), 0, stream>>>(y, ctd, ctg, ctg2, emb, Wx);

    k_gates<<<dim3(Bv, 4), dim3(256), 0, stream>>>(h_prev, Wi, Wh, bi, bh, bx);

    k_cellsd<<<dim3(Bv, 2), dim3(256), 0, stream>>>(c_prev, Wsd, Wsf, o_h, o_c);

    k_scores<<<dim3(7, Bv), dim3(256), 0, stream>>>(
        enc, TKv, g_Wdt_p, g_sdp_p, g_sdp_p + 32768, bd, cov, wcdw, vd, g_e_p);

    k_scores<<<dim3(1, Bv), dim3(256), 0, stream>>>(
        encn, NKv, g_Wnt_p, g_sfp_p, g_sfp_p + 32768, bfv,
        nullptr, nullptr, vf, g_en_p);

    // doc attention back-end, latency-optimized
    k_doc<<<dim3(Bv), dim3(256), 0, stream>>>(mask, cov, o_a, o_cov);

    k_cd<<<dim3(Bv, 2), dim3(256), 0, stream>>>(enc);

    k_flow<<<dim3(Bv), dim3(256), 0, stream>>>(n2t, o_fl);

    k_node1<<<dim3(Bv), dim3(256), 0, stream>>>(
        encn, maskn, flow, graph, n2t, Wpg, bpg,
        o_cd, o_cg, o_cg2, o_ant, o_pg);

    k_o1<<<dim3(Bv, 4), dim3(256), 0, stream>>>(W1, b1);

    k_logits<<<dim3(VPAD / 128), dim3(256), 0, stream>>>(b2);

    k_vsoft<<<dim3(Bv), dim3(256), 0, stream>>>(o_final, vocd);
}

// Round 3
// 543.527 us; speedup vs baseline: 1.8064x; 1.1579x over previous
//
#include <hip/hip_runtime.h>
#include <stdint.h>

// ---------------------------------------------------------------------------
// LSTM pointer-generator decoder step, B=128 TK=400 NK=50 H=E=256 V=50000.
// Round 9: kill the latency-bound k_vsoft (120 us, HBM 5.2%, occ 5.2%,
// 0.5 waves/SIMD). Split into k_vpart (B x 16 chunk-partials, float4,
// online max/sum) + k_vwrite (merge 16 pairs, float4 writes) + k_scatter
// (row-local pointer adds). 2048 blocks = 8 waves/SIMD on the V passes.
// Chunk = 3136 = VPAD/16 keeps all chunks float4-aligned, last chunk is
// exactly 740 float4s (50000-15*3136=2960). Everything else unchanged.
// ---------------------------------------------------------------------------

typedef unsigned short u16;
typedef unsigned int   u32;

#define Bv  128
#define TKv 400
#define NKv 50
#define Hv  256
#define Vv  50000
#define VPAD 50176   // 50000 padded to multiple of 128
#define NSv 16
#define CHUNKv 3136  // VPAD / NSv

typedef __attribute__((ext_vector_type(8))) short bf16x8;
typedef __attribute__((ext_vector_type(4))) float f32x4;

// ---- module-global workspace (no d_ws dependency) -------------------------
__device__ float g_x[32768];      // x = cat @ Wx + bx
__device__ float g_xp[4 * 32768]; // x K-partials
__device__ float g_gates[131072]; // LSTM gates [B,4H]
__device__ float g_h[32768];      // h_new
__device__ float g_c[32768];      // c_new
__device__ float g_sdp[2 * 32768];// s_hat@Wsd partials (no bias)
__device__ float g_sfp[2 * 32768];// s_hat@Wsf partials (no bias)
__device__ float g_e[51200];      // doc scores
__device__ float g_en[6400];      // node scores
__device__ float g_a[51200];      // doc attention a
__device__ float g_cd[32768];     // c_d
__device__ float g_cdp[2 * 32768];// c_d t-split partials
__device__ float g_cg[32768];     // c_g
__device__ float g_cg2[32768];    // c_g2
__device__ float g_pg[128];       // p_gen
__device__ float g_o1[32768];     // out1
__device__ float g_vred[Bv * NSv * 2];     // per-chunk (max, sum) pairs
__device__ float g_logits[6400000];        // f32 logits (25.6 MB)
__device__ u16   g_Wdt[256 * 256];         // Whd^T bf16 [n][k]
__device__ u16   g_Wnt[256 * 256];         // Wn^T  bf16 [n][k]
__device__ u16   g_W2t[(size_t)VPAD * 256];// W2^T  bf16 [v][k] (25.7 MB)

__device__ __forceinline__ float sigm(float x) { return 1.f / (1.f + expf(-x)); }

__device__ __forceinline__ u16 f2bf(float f) {
    u32 u = __float_as_uint(f);
    return (u16)((u + 0x7fffu + ((u >> 16) & 1u)) >> 16);  // RNE
}

__device__ __forceinline__ bf16x8 cvt8(const float* __restrict__ p) {
    const float4 a = *(const float4*)p;
    const float4 b = *(const float4*)(p + 4);
    bf16x8 r;
    r[0] = (short)f2bf(a.x); r[1] = (short)f2bf(a.y);
    r[2] = (short)f2bf(a.z); r[3] = (short)f2bf(a.w);
    r[4] = (short)f2bf(b.x); r[5] = (short)f2bf(b.y);
    r[6] = (short)f2bf(b.z); r[7] = (short)f2bf(b.w);
    return r;
}

// tanh via exp; clamp so exp never overflows (tanh saturated anyway)
__device__ __forceinline__ float fast_tanh(float x) {
    x = fminf(fmaxf(x, -15.f), 15.f);
    float e = __expf(2.f * x);
    return (e - 1.f) / (e + 1.f);
}

// online (max,sum) merge: (m1,s1) <- (m1,s1) U (m2,s2)
__device__ __forceinline__ void ms_merge(float& m1, float& s1, float m2, float s2) {
    float M = fmaxf(m1, m2);
    s1 = s1 * expf(m1 - M) + s2 * expf(m2 - M);
    m1 = M;
}

// ---------------------------------------------------------------------------
// K0: transpose-cast  src[K][N] f32  ->  dst[n][k] bf16.
// grid = (Npad/32, K/32), block 256 (32x8). Reads n>=N give 0 (pad rows).
// ---------------------------------------------------------------------------
__global__ __launch_bounds__(256) void k_tc(
    const float* __restrict__ src, u16* __restrict__ dst, int K, int N)
{
    __shared__ float tile[32][33];
    const int n0 = blockIdx.x * 32, k0 = blockIdx.y * 32;
    const int tx = threadIdx.x & 31, ty = threadIdx.x >> 5;
    #pragma unroll
    for (int i = 0; i < 32; i += 8) {
        int k = k0 + ty + i, n = n0 + tx;
        tile[ty + i][tx] = (n < N) ? src[(size_t)k * N + n] : 0.f;
    }
    __syncthreads();
    #pragma unroll
    for (int i = 0; i < 32; i += 8) {
        int n = n0 + ty + i, k = k0 + tx;
        dst[(size_t)n * K + k] = f2bf(tile[tx][ty + i]);
    }
}

// ---------------------------------------------------------------------------
// K1a: x K-partials. grid (B, 4): block (b, ks) stages cat-chunk ks in LDS,
// computes partial x over its 256-row slice of Wx. 512 blocks = 2 waves/SIMD.
// ---------------------------------------------------------------------------
__global__ __launch_bounds__(256) void k_x(
    const int* __restrict__ y,
    const float* __restrict__ ctd, const float* __restrict__ ctg,
    const float* __restrict__ ctg2, const float* __restrict__ emb,
    const float* __restrict__ Wx)
{
    const int b = blockIdx.x, ks = blockIdx.y, j = threadIdx.x;
    __shared__ float cs[256];
    float v;
    if      (ks == 0) v = ctd [b * 256 + j];
    else if (ks == 1) v = ctg [b * 256 + j];
    else if (ks == 2) v = ctg2[b * 256 + j];
    else              v = emb[(size_t)y[b] * 256 + j];
    cs[j] = v;
    __syncthreads();

    float acc = 0.f;
    const float* w = Wx + (size_t)(ks * 256) * 256 + j;
    #pragma unroll 8
    for (int k = 0; k < 256; k++) acc += cs[k] * w[(size_t)k * 256];
    g_xp[ks * 32768 + b * 256 + j] = acc;
}

// ---------------------------------------------------------------------------
// K1b: gates = x@Wi + h@Wh + bi + bh. grid (B, 4 col-chunks), fully
// output-parallel (no atomics). Sums the 4 x-partials + bx while staging
// (col-chunk 0 also publishes g_x for k_node1's p_gen).
// ---------------------------------------------------------------------------
__global__ __launch_bounds__(256) void k_gates(
    const float* __restrict__ h_prev,
    const float* __restrict__ Wi, const float* __restrict__ Wh,
    const float* __restrict__ bi, const float* __restrict__ bh,
    const float* __restrict__ bx)
{
    const int b = blockIdx.x, cc = blockIdx.y, j = threadIdx.x;
    __shared__ float xs[256], hs[256];

    float xv = bx[j] + g_xp[b * 256 + j] + g_xp[32768 + b * 256 + j]
             + g_xp[65536 + b * 256 + j] + g_xp[98304 + b * 256 + j];
    xs[j] = xv;
    if (cc == 0) g_x[b * 256 + j] = xv;
    hs[j] = h_prev[b * 256 + j];
    __syncthreads();

    const int col = cc * 256 + j;
    float acc = bi[col] + bh[col];
    const float* wi = Wi + col;
    const float* wh = Wh + col;
    #pragma unroll 8
    for (int k = 0; k < 256; k++)
        acc += xs[k] * wi[(size_t)k * 1024] + hs[k] * wh[(size_t)k * 1024];
    g_gates[b * 1024 + col] = acc;
}

// ---------------------------------------------------------------------------
// K1c: LSTM elementwise + sd/sf K-partials. grid (B, 2): both K-halves
// redundantly compute the cheap cell update; ks==0 publishes h/c. Each block
// stages its half of s_hat=[h|c] and emits sd/sf partials (bias deferred to
// the k_scores epilogue).
// ---------------------------------------------------------------------------
__global__ __launch_bounds__(256) void k_cellsd(
    const float* __restrict__ c_prev,
    const float* __restrict__ Wsd, const float* __restrict__ Wsf,
    float* __restrict__ out_h, float* __restrict__ out_c)
{
    const int b = blockIdx.x, ks = blockIdx.y, j = threadIdx.x;
    __shared__ float sh[256];

    const float* gb = g_gates + b * 1024;
    float gi_ = gb[j], gf_ = gb[256 + j], gg_ = gb[512 + j], go_ = gb[768 + j];
    float cp = c_prev[b * 256 + j];
    float cn = sigm(gf_) * cp + sigm(gi_) * tanhf(gg_);
    float hn = sigm(go_) * tanhf(cn);
    if (ks == 0) {
        g_h[b * 256 + j] = hn;  g_c[b * 256 + j] = cn;
        out_h[b * 256 + j] = hn; out_c[b * 256 + j] = cn;
    }
    sh[j] = (ks == 0) ? hn : cn;   // s_hat rows [0,256) = h, [256,512) = c
    __syncthreads();

    float asd = 0.f, asf = 0.f;
    const float* wd = Wsd + (size_t)(ks * 256) * 256 + j;
    const float* wf = Wsf + (size_t)(ks * 256) * 256 + j;
    #pragma unroll 8
    for (int k = 0; k < 256; k++) {
        float sv = sh[k];
        asd += sv * wd[(size_t)k * 256];
        asf += sv * wf[(size_t)k * 256];
    }
    g_sdp[ks * 32768 + b * 256 + j] = asd;
    g_sfp[ks * 32768 + b * 256 + j] = asf;
}

// ---------------------------------------------------------------------------
// K2/K4 (MFMA): e[b,t] = vv . tanh( src[b,t,:]@W + add0+add1+abias + cov*wcw )
// Wt is the bf16 transposed weight [n][k]. grid (ceil(R/64), B), block 256.
// Wave w handles rows t0+w*16..+15 (one 16-row M-tile x 16 N-tiles, K=256).
// ---------------------------------------------------------------------------
__global__ __launch_bounds__(256) void k_scores(
    const float* __restrict__ src, int R,
    const u16* __restrict__ Wt,
    const float* __restrict__ addv0,  // s_hat@W partial (K lower half)
    const float* __restrict__ addv1,  // s_hat@W partial (K upper half)
    const float* __restrict__ abias,  // attention bias vector (bd / bf)
    const float* __restrict__ cov,    // nullptr for node attention
    const float* __restrict__ wcw,    // nullptr for node attention
    const float* __restrict__ vv,
    float* __restrict__ eout)
{
    const int b = blockIdx.y, t0 = blockIdx.x * 64;
    const int tid = threadIdx.x;
    const int lane = tid & 63, wave = tid >> 6;
    const int nlow = lane & 15, quad = lane >> 4;
    const int trow = t0 + wave * 16 + nlow;
    const bool tval = trow < R;
    const float* arow = src + ((size_t)b * R + trow) * 256 + quad * 8;
    const u16* brow = Wt + nlow * 256 + quad * 8;

    const f32x4 zf = {0.f, 0.f, 0.f, 0.f};
    f32x4 acc[16];
    #pragma unroll
    for (int i = 0; i < 16; i++) acc[i] = zf;

    for (int k0 = 0; k0 < 256; k0 += 32) {
        bf16x8 af = {0, 0, 0, 0, 0, 0, 0, 0};
        if (tval) af = cvt8(arow + k0);
        #pragma unroll
        for (int nt = 0; nt < 16; nt++) {
            bf16x8 bf = *(const bf16x8*)(brow + nt * 4096 + k0);
            acc[nt] = __builtin_amdgcn_mfma_f32_16x16x32_bf16(af, bf, acc[nt], 0, 0, 0);
        }
    }

    // epilogue: C row = quad*4+r, col = nt*16+nlow
    float covt[4];
    #pragma unroll
    for (int r = 0; r < 4; r++) {
        int t = t0 + wave * 16 + quad * 4 + r;
        covt[r] = (cov && t < R) ? cov[b * R + t] : 0.f;
    }
    float s4[4] = {0.f, 0.f, 0.f, 0.f};
    #pragma unroll
    for (int nt = 0; nt < 16; nt++) {
        int col = nt * 16 + nlow;
        float vvc = vv[col];
        float adc = addv0[b * 256 + col] + addv1[b * 256 + col] + abias[col];
        float wcc = wcw ? wcw[col] : 0.f;
        #pragma unroll
        for (int r = 0; r < 4; r++)
            s4[r] += vvc * fast_tanh(acc[nt][r] + adc + covt[r] * wcc);
    }
    #pragma unroll
    for (int r = 0; r < 4; r++) {
        float s = s4[r];
        s += __shfl_xor(s, 1, 64);
        s += __shfl_xor(s, 2, 64);
        s += __shfl_xor(s, 4, 64);
        s += __shfl_xor(s, 8, 64);
        int t = t0 + wave * 16 + quad * 4 + r;
        if (nlow == 0 && t < R) eout[b * R + t] = s;
    }
}

// ---------------------------------------------------------------------------
// K3: doc softmax (+mask renorm) only: a, coverage_next. Fully t-parallel.
// ---------------------------------------------------------------------------
__global__ __launch_bounds__(256) void k_doc(
    const float* __restrict__ mask,
    const float* __restrict__ cov,
    float* __restrict__ out_a, float* __restrict__ out_cov)
{
    const int b = blockIdx.x, tid = threadIdx.x;
    __shared__ float red[256];

    float e0 = g_e[b * TKv + tid];
    float e1 = (tid + 256 < TKv) ? g_e[b * TKv + tid + 256] : -1e30f;

    float m = fmaxf(e0, e1);
    red[tid] = m; __syncthreads();
    for (int s = 128; s > 0; s >>= 1) { if (tid < s) red[tid] = fmaxf(red[tid], red[tid + s]); __syncthreads(); }
    m = red[0]; __syncthreads();

    float p0 = expf(e0 - m) * mask[b * TKv + tid];
    float p1 = (tid + 256 < TKv) ? expf(e1 - m) * mask[b * TKv + tid + 256] : 0.f;
    red[tid] = p0 + p1; __syncthreads();
    for (int s = 128; s > 0; s >>= 1) { if (tid < s) red[tid] += red[tid + s]; __syncthreads(); }
    float inv = 1.f / red[0];

    float a0 = p0 * inv;
    g_a[b * TKv + tid] = a0;
    out_a[b * TKv + tid] = a0;
    out_cov[b * TKv + tid] = cov[b * TKv + tid] + a0;
    if (tid + 256 < TKv) {
        float a1 = p1 * inv;
        g_a[b * TKv + tid + 256] = a1;
        out_a[b * TKv + tid + 256] = a1;
        out_cov[b * TKv + tid + 256] = cov[b * TKv + tid + 256] + a1;
    }
}

// ---------------------------------------------------------------------------
// K3b: c_d t-split partials. grid (B, 2): block (b,ks) stages its 200-elem
// a-chunk in LDS, each thread does 200 serial MACs over enc (unroll 8).
// ---------------------------------------------------------------------------
__global__ __launch_bounds__(256) void k_cd(const float* __restrict__ enc)
{
    const int b = blockIdx.x, ks = blockIdx.y, tid = threadIdx.x;
    __shared__ float as_[200];
    if (tid < 200) as_[tid] = g_a[b * TKv + ks * 200 + tid];
    __syncthreads();

    const float* eb = enc + ((size_t)b * TKv + ks * 200) * 256 + tid;
    float acc = 0.f;
    #pragma unroll 8
    for (int t = 0; t < 200; t++) acc += as_[t] * eb[(size_t)t * 256];
    g_cdp[ks * 32768 + b * 256 + tid] = acc;
}

// ---------------------------------------------------------------------------
// K3c: flow_next. grid (B): 50 nodes x 4 threads (t-quarters of 100),
// shuffle-max across the 4, block-sum over 50, normalized write.
// ---------------------------------------------------------------------------
__global__ __launch_bounds__(256) void k_flow(
    const float* __restrict__ n2t, float* __restrict__ out_flow)
{
    const int b = blockIdx.x, tid = threadIdx.x;
    __shared__ float as_[TKv];
    __shared__ float fl[NKv];
    __shared__ float red[256];

    for (int t = tid; t < TKv; t += 256) as_[t] = g_a[b * TKv + t];
    __syncthreads();

    const int nn = tid >> 2, sub = tid & 3;
    float mx = 0.f;
    if (nn < NKv) {
        const float* nb = n2t + ((size_t)b * NKv + nn) * TKv + sub * 100;
        const float* ab = as_ + sub * 100;
        #pragma unroll 4
        for (int t = 0; t < 100; t++) mx = fmaxf(mx, ab[t] * nb[t]);
    }
    mx = fmaxf(mx, __shfl_xor(mx, 1, 64));
    mx = fmaxf(mx, __shfl_xor(mx, 2, 64));
    if (sub == 0 && nn < NKv) fl[nn] = mx;
    __syncthreads();

    float fv = (tid < NKv) ? fl[tid] : 0.f;
    red[tid] = fv; __syncthreads();
    for (int s = 128; s > 0; s >>= 1) { if (tid < s) red[tid] += red[tid + s]; __syncthreads(); }
    float fs = red[0];
    if (tid < NKv) out_flow[b * NKv + tid] = fl[tid] / fs;
}

// ---------------------------------------------------------------------------
// K5: node softmax chain (an, c_g, an2, c_g2, a_n2t), cd-partial sum, p_gen.
// All 50-length loops fully unrolled so loads pipeline; cg+cg2 share one
// enb pass. out1 moved to k_o1.
// ---------------------------------------------------------------------------
__global__ __launch_bounds__(256) void k_node1(
    const float* __restrict__ encn,
    const float* __restrict__ maskn,
    const float* __restrict__ flow,
    const float* __restrict__ graph,
    const float* __restrict__ n2t,
    const float* __restrict__ Wpg, const float* __restrict__ bpg,
    float* __restrict__ out_cd, float* __restrict__ out_cg,
    float* __restrict__ out_cg2, float* __restrict__ out_ant,
    float* __restrict__ out_pgen)
{
    const int b = blockIdx.x, tid = threadIdx.x;
    __shared__ float ans[NKv], an2s[NKv], red[256];

    // c_d = sum of t-split partials
    const float cd = g_cdp[b * 256 + tid] + g_cdp[32768 + b * 256 + tid];
    g_cd[b * 256 + tid] = cd;
    out_cd[b * 256 + tid] = cd;

    // node softmax -> flow-weighted renorm
    float v = (tid < NKv) ? g_en[b * NKv + tid] : -1e30f;
    red[tid] = v; __syncthreads();
    for (int s = 128; s > 0; s >>= 1) { if (tid < s) red[tid] = fmaxf(red[tid], red[tid + s]); __syncthreads(); }
    float m = red[0]; __syncthreads();

    float p = (tid < NKv) ? expf(v - m) * maskn[b * NKv + tid] : 0.f;
    red[tid] = p; __syncthreads();
    for (int s = 128; s > 0; s >>= 1) { if (tid < s) red[tid] += red[tid + s]; __syncthreads(); }
    float S = red[0]; __syncthreads();
    p = (tid < NKv) ? (p / S) * flow[b * NKv + tid] : 0.f;
    red[tid] = p; __syncthreads();
    for (int s = 128; s > 0; s >>= 1) { if (tid < s) red[tid] += red[tid + s]; __syncthreads(); }
    float S2 = red[0]; __syncthreads();
    if (tid < NKv) ans[tid] = p / S2;
    __syncthreads();

    // an2 = (ans @ graph) * mask, renormalized
    float q = 0.f;
    if (tid < NKv) {
        const float* gb = graph + (size_t)b * NKv * NKv + tid;
        #pragma unroll
        for (int n = 0; n < NKv; n++) q += ans[n] * gb[n * NKv];
        q *= maskn[b * NKv + tid];
    }
    red[tid] = q; __syncthreads();
    for (int s = 128; s > 0; s >>= 1) { if (tid < s) red[tid] += red[tid + s]; __syncthreads(); }
    float S3 = red[0]; __syncthreads();
    if (tid < NKv) an2s[tid] = q / S3;
    __syncthreads();

    // c_g and c_g2 in one pass over encn
    float cg = 0.f, cg2 = 0.f;
    {
        const float* enb = encn + (size_t)b * NKv * 256 + tid;
        #pragma unroll
        for (int n = 0; n < NKv; n++) {
            float e = enb[n * 256];
            cg  += ans[n]  * e;
            cg2 += an2s[n] * e;
        }
    }
    g_cg[b * 256 + tid] = cg;   out_cg[b * 256 + tid] = cg;
    g_cg2[b * 256 + tid] = cg2; out_cg2[b * 256 + tid] = cg2;

    // a_n2t with normalization
    float at0 = 0.f, at1 = 0.f;
    {
        const float* nb = n2t + (size_t)b * NKv * TKv;
        #pragma unroll
        for (int n = 0; n < NKv; n++) {
            float an = ans[n];
            at0 += an * nb[n * TKv + tid];
            if (tid + 256 < TKv) at1 += an * nb[n * TKv + tid + 256];
        }
    }
    float loc = at0 + ((tid + 256 < TKv) ? at1 : 0.f);
    red[tid] = loc; __syncthreads();
    for (int s = 128; s > 0; s >>= 1) { if (tid < s) red[tid] += red[tid + s]; __syncthreads(); }
    float S4 = red[0]; __syncthreads();
    out_ant[b * TKv + tid] = at0 / S4;
    if (tid + 256 < TKv) out_ant[b * TKv + tid + 256] = at1 / S4;

    // p_gen
    float hvv = g_h[b * 256 + tid], cvv = g_c[b * 256 + tid];
    float xvv = g_x[b * 256 + tid];
    float part = cd  * Wpg[tid]        + cg  * Wpg[256 + tid]
               + cg2 * Wpg[512 + tid]  + hvv * Wpg[768 + tid]
               + cvv * Wpg[1024 + tid] + xvv * Wpg[1280 + tid];
    red[tid] = part; __syncthreads();
    for (int s = 128; s > 0; s >>= 1) { if (tid < s) red[tid] += red[tid + s]; __syncthreads(); }
    if (tid == 0) {
        float pg = sigm(red[0] + bpg[0]);
        g_pg[b] = pg; out_pgen[b] = pg;
    }
}

// ---------------------------------------------------------------------------
// K6: out1 = [h|cd|cg|cg2] @ W1 + b1. grid (B, 4 col-chunks of 64).
// Thread (kq, lane): kq = tid>>6 K-quarter, lane picks output col; 256
// serial MACs each (unroll 8), LDS cross-kq reduce.
// ---------------------------------------------------------------------------
__global__ __launch_bounds__(256) void k_o1(
    const float* __restrict__ W1, const float* __restrict__ b1)
{
    const int b = blockIdx.x, cc = blockIdx.y, tid = threadIdx.x;
    __shared__ float cat[1024];
    __shared__ float red[256];

    cat[tid]       = g_h  [b * 256 + tid];
    cat[256 + tid] = g_cd [b * 256 + tid];
    cat[512 + tid] = g_cg [b * 256 + tid];
    cat[768 + tid] = g_cg2[b * 256 + tid];
    __syncthreads();

    const int lane = tid & 63, kq = tid >> 6;
    const int col = cc * 64 + lane;
    const float* w  = W1 + (size_t)(kq * 256) * 256 + col;
    const float* cs = cat + kq * 256;
    float acc = 0.f;
    #pragma unroll 8
    for (int k = 0; k < 256; k++) acc += cs[k] * w[(size_t)k * 256];
    red[tid] = acc; __syncthreads();

    if (tid < 64) {
        float o = b1[cc * 64 + tid]
                + red[tid] + red[64 + tid] + red[128 + tid] + red[192 + tid];
        g_o1[b * 256 + cc * 64 + tid] = o;
    }
}

// ---------------------------------------------------------------------------
// K7 (MFMA): logits = out1[128,256] @ W2[256,50000] + b2 -> g_logits (f32).
// W2t bf16 [VPAD][256]. grid (392): each block does all 128 rows x 128 cols.
// Per wave: 2 M-tiles (32 rows) x 8 N-tiles; acc = 64 VGPRs.
// ---------------------------------------------------------------------------
__global__ __launch_bounds__(256) void k_logits(const float* __restrict__ b2)
{
    const int v0 = blockIdx.x * 128;
    const int tid = threadIdx.x;
    const int lane = tid & 63, wave = tid >> 6;
    const int nlow = lane & 15, quad = lane >> 4;

    const float* a0p = g_o1 + (wave * 32 + nlow) * 256 + quad * 8;
    const float* a1p = a0p + 16 * 256;
    const u16* bbase = g_W2t + (size_t)(v0 + nlow) * 256 + quad * 8;

    const f32x4 zf = {0.f, 0.f, 0.f, 0.f};
    f32x4 acc0[8], acc1[8];
    #pragma unroll
    for (int i = 0; i < 8; i++) { acc0[i] = zf; acc1[i] = zf; }

    for (int k0 = 0; k0 < 256; k0 += 32) {
        bf16x8 a0 = cvt8(a0p + k0);
        bf16x8 a1 = cvt8(a1p + k0);
        #pragma unroll
        for (int nt = 0; nt < 8; nt++) {
            bf16x8 bf = *(const bf16x8*)(bbase + (size_t)nt * 4096 + k0);
            acc0[nt] = __builtin_amdgcn_mfma_f32_16x16x32_bf16(a0, bf, acc0[nt], 0, 0, 0);
            acc1[nt] = __builtin_amdgcn_mfma_f32_16x16x32_bf16(a1, bf, acc1[nt], 0, 0, 0);
        }
    }

    #pragma unroll
    for (int nt = 0; nt < 8; nt++) {
        int v = v0 + nt * 16 + nlow;
        if (v < Vv) {
            float bb = b2[v];
            #pragma unroll
            for (int r = 0; r < 4; r++) {
                int row0 = wave * 32 + quad * 4 + r;
                g_logits[(size_t)row0 * Vv + v]        = acc0[nt][r] + bb;
                g_logits[(size_t)(row0 + 16) * Vv + v] = acc1[nt][r] + bb;
            }
        }
    }
}

// ---------------------------------------------------------------------------
// K8a: per-chunk online (max, sum) partials. grid (B, NS), float4 loads.
// Chunk ks covers [ks*3136, min(+3136, 50000)) — always float4-exact.
// ---------------------------------------------------------------------------
__global__ __launch_bounds__(256) void k_vpart()
{
    const int b = blockIdx.x, ks = blockIdx.y, tid = threadIdx.x;
    __shared__ float rm[256], rs[256];

    const int base = ks * CHUNKv;
    const int end  = min(base + CHUNKv, Vv);
    const int n4   = (end - base) >> 2;
    const float4* L4 = (const float4*)(g_logits + (size_t)b * Vv + base);

    float m = -1e30f, s = 0.f;
    for (int i = tid; i < n4; i += 256) {
        float4 x = L4[i];
        float mx = fmaxf(fmaxf(x.x, x.y), fmaxf(x.z, x.w));
        if (mx > m) { s *= expf(m - mx); m = mx; }
        s += expf(x.x - m) + expf(x.y - m) + expf(x.z - m) + expf(x.w - m);
    }
    rm[tid] = m; rs[tid] = s; __syncthreads();
    for (int off = 128; off > 0; off >>= 1) {
        if (tid < off) {
            float m1 = rm[tid], s1 = rs[tid];
            ms_merge(m1, s1, rm[tid + off], rs[tid + off]);
            rm[tid] = m1; rs[tid] = s1;
        }
        __syncthreads();
    }
    if (tid == 0) {
        g_vred[(b * NSv + ks) * 2]     = rm[0];
        g_vred[(b * NSv + ks) * 2 + 1] = rs[0];
    }
}

// ---------------------------------------------------------------------------
// K8b: merge the NS pairs (broadcast, L2-hot), write exp(x-M)*pg/S for the
// chunk with float4 stores. grid (B, NS).
// ---------------------------------------------------------------------------
__global__ __launch_bounds__(256) void k_vwrite(float* __restrict__ outF)
{
    const int b = blockIdx.x, ks = blockIdx.y, tid = threadIdx.x;

    float M = -1e30f, S = 0.f;
    #pragma unroll
    for (int i = 0; i < NSv; i++) {
        float mi = g_vred[(b * NSv + i) * 2];
        float si = g_vred[(b * NSv + i) * 2 + 1];
        ms_merge(M, S, mi, si);
    }
    const float inv = g_pg[b] / S;

    const int base = ks * CHUNKv;
    const int end  = min(base + CHUNKv, Vv);
    const int n4   = (end - base) >> 2;
    const float4* L4 = (const float4*)(g_logits + (size_t)b * Vv + base);
    float4* O4 = (float4*)(outF + (size_t)b * Vv + base);

    for (int i = tid; i < n4; i += 256) {
        float4 x = L4[i];
        float4 r;
        r.x = expf(x.x - M) * inv;
        r.y = expf(x.y - M) * inv;
        r.z = expf(x.z - M) * inv;
        r.w = expf(x.w - M) * inv;
        O4[i] = r;
    }
}

// ---------------------------------------------------------------------------
// K8c: row-local pointer scatter (1-pg)*a[b,t] at voc_d[b,t]. Runs after
// k_vwrite (stream order guarantees the base probs are in place).
// ---------------------------------------------------------------------------
__global__ __launch_bounds__(256) void k_scatter(
    float* __restrict__ outF, const int* __restrict__ vocd)
{
    const int b = blockIdx.x, tid = threadIdx.x;
    float* Ob = outF + (size_t)b * Vv;
    const float omp = 1.f - g_pg[b];
    for (int t = tid; t < TKv; t += 256)
        atomicAdd(Ob + vocd[b * TKv + t], omp * g_a[b * TKv + t]);
}

// ---------------------------------------------------------------------------

extern "C" void kernel_launch(void* const* d_in, const int* in_sizes, int n_in,
                              void* d_out, int out_size, void* d_ws, size_t ws_size,
                              hipStream_t stream)
{
    (void)in_sizes; (void)n_in; (void)out_size; (void)d_ws; (void)ws_size;

    const int*   y      = (const int*)d_in[0];
    const float* h_prev = (const float*)d_in[1];
    const float* c_prev = (const float*)d_in[2];
    const float* enc    = (const float*)d_in[3];
    const float* encn   = (const float*)d_in[4];
    const float* mask   = (const float*)d_in[5];
    const float* maskn  = (const float*)d_in[6];
    const float* ctd    = (const float*)d_in[7];
    const float* ctg    = (const float*)d_in[8];
    const float* ctg2   = (const float*)d_in[9];
    const float* cov    = (const float*)d_in[10];
    const float* flow   = (const float*)d_in[11];
    const float* n2t    = (const float*)d_in[12];
    const float* graph  = (const float*)d_in[13];
    const int*   vocd   = (const int*)d_in[14];
    // d_in[15] = step (unused)
    const float* emb    = (const float*)d_in[16];
    const float* Wx     = (const float*)d_in[17];
    const float* bx     = (const float*)d_in[18];
    const float* Wi     = (const float*)d_in[19];
    const float* Wh     = (const float*)d_in[20];
    const float* bi     = (const float*)d_in[21];
    const float* bh     = (const float*)d_in[22];
    const float* Whd    = (const float*)d_in[23];
    const float* Wsd    = (const float*)d_in[24];
    const float* wcdw   = (const float*)d_in[25];
    const float* vd     = (const float*)d_in[26];
    const float* bd     = (const float*)d_in[27];
    const float* Wn     = (const float*)d_in[28];
    const float* Wsf    = (const float*)d_in[29];
    const float* vf     = (const float*)d_in[30];
    const float* bfv    = (const float*)d_in[31];
    const float* Wpg    = (const float*)d_in[32];
    const float* bpg    = (const float*)d_in[33];
    const float* W1     = (const float*)d_in[34];
    const float* b1     = (const float*)d_in[35];
    const float* W2     = (const float*)d_in[36];
    const float* b2     = (const float*)d_in[37];

    float* o = (float*)d_out;                 // FLOAT32 output
    float* o_final = o;                       // 6,400,000
    float* o_h     = o + 6400000;
    float* o_c     = o + 6432768;
    float* o_cd    = o + 6465536;
    float* o_cg    = o + 6498304;
    float* o_cg2   = o + 6531072;
    float* o_a     = o + 6563840;
    float* o_ant   = o + 6615040;
    float* o_pg    = o + 6666240;
    float* o_cov   = o + 6666368;
    float* o_fl    = o + 6717568;

    float* g_e_p;   hipGetSymbolAddress((void**)&g_e_p,   HIP_SYMBOL(g_e));
    float* g_en_p;  hipGetSymbolAddress((void**)&g_en_p,  HIP_SYMBOL(g_en));
    float* g_sdp_p; hipGetSymbolAddress((void**)&g_sdp_p, HIP_SYMBOL(g_sdp));
    float* g_sfp_p; hipGetSymbolAddress((void**)&g_sfp_p, HIP_SYMBOL(g_sfp));
    u16*   g_Wdt_p; hipGetSymbolAddress((void**)&g_Wdt_p, HIP_SYMBOL(g_Wdt));
    u16*   g_Wnt_p; hipGetSymbolAddress((void**)&g_Wnt_p, HIP_SYMBOL(g_Wnt));
    u16*   g_W2t_p; hipGetSymbolAddress((void**)&g_W2t_p, HIP_SYMBOL(g_W2t));

    // transpose-cast weights to bf16 [n][k]
    k_tc<<<dim3(8, 8), dim3(256), 0, stream>>>(Whd, g_Wdt_p, 256, 256);
    k_tc<<<dim3(8, 8), dim3(256), 0, stream>>>(Wn,  g_Wnt_p, 256, 256);
    k_tc<<<dim3(VPAD / 32, 8), dim3(256), 0, stream>>>(W2, g_W2t_p, 256, Vv);

    // LSTM front-end, latency-optimized: 512/512/256 blocks
    k_x<<<dim3(Bv, 4), dim3(256), 0, stream>>>(y, ctd, ctg, ctg2, emb, Wx);

    k_gates<<<dim3(Bv, 4), dim3(256), 0, stream>>>(h_prev, Wi, Wh, bi, bh, bx);

    k_cellsd<<<dim3(Bv, 2), dim3(256), 0, stream>>>(c_prev, Wsd, Wsf, o_h, o_c);

    k_scores<<<dim3(7, Bv), dim3(256), 0, stream>>>(
        enc, TKv, g_Wdt_p, g_sdp_p, g_sdp_p + 32768, bd, cov, wcdw, vd, g_e_p);

    k_scores<<<dim3(1, Bv), dim3(256), 0, stream>>>(
        encn, NKv, g_Wnt_p, g_sfp_p, g_sfp_p + 32768, bfv,
        nullptr, nullptr, vf, g_en_p);

    // doc attention back-end, latency-optimized
    k_doc<<<dim3(Bv), dim3(256), 0, stream>>>(mask, cov, o_a, o_cov);

    k_cd<<<dim3(Bv, 2), dim3(256), 0, stream>>>(enc);

    k_flow<<<dim3(Bv), dim3(256), 0, stream>>>(n2t, o_fl);

    k_node1<<<dim3(Bv), dim3(256), 0, stream>>>(
        encn, maskn, flow, graph, n2t, Wpg, bpg,
        o_cd, o_cg, o_cg2, o_ant, o_pg);

    k_o1<<<dim3(Bv, 4), dim3(256), 0, stream>>>(W1, b1);

    k_logits<<<dim3(VPAD / 128), dim3(256), 0, stream>>>(b2);

    // vocab softmax, latency-optimized: B x 16 chunk blocks
    k_vpart<<<dim3(Bv, NSv), dim3(256), 0, stream>>>();

    k_vwrite<<<dim3(Bv, NSv), dim3(256), 0, stream>>>(o_final);

    k_scatter<<<dim3(Bv), dim3(256), 0, stream>>>(o_final, vocd);
}

// Round 4
// 529.588 us; speedup vs baseline: 1.8539x; 1.0263x over previous
//
#include <hip/hip_runtime.h>
#include <stdint.h>

// ---------------------------------------------------------------------------
// LSTM pointer-generator decoder step, B=128 TK=400 NK=50 H=E=256 V=50000.
// Round 10: fix k_scores' serialized B loads (91 us, MfmaUtil 3%, VGPR=116
// forced the compiler to recycle B-frag registers -> one L2 round trip per
// N-tile). Retile: wave = 4 M-tiles x 4 N-tiles (64-col N-chunk per wave),
// 8 hoistable loads per k-step, acc stays 64 VGPR, B traffic/wave 4x lower.
// Epilogue: per-wave partial col-sums + LDS cross-wave reduce (1 KB).
// Same recipe for k_logits: wave = 2M x 4N, 64-col blocks, grid 784.
// Everything else unchanged from R9.
// ---------------------------------------------------------------------------

typedef unsigned short u16;
typedef unsigned int   u32;

#define Bv  128
#define TKv 400
#define NKv 50
#define Hv  256
#define Vv  50000
#define VPAD 50176   // 50000 padded to multiple of 128
#define NSv 16
#define CHUNKv 3136  // VPAD / NSv

typedef __attribute__((ext_vector_type(8))) short bf16x8;
typedef __attribute__((ext_vector_type(4))) float f32x4;

// ---- module-global workspace (no d_ws dependency) -------------------------
__device__ float g_x[32768];      // x = cat @ Wx + bx
__device__ float g_xp[4 * 32768]; // x K-partials
__device__ float g_gates[131072]; // LSTM gates [B,4H]
__device__ float g_h[32768];      // h_new
__device__ float g_c[32768];      // c_new
__device__ float g_sdp[2 * 32768];// s_hat@Wsd partials (no bias)
__device__ float g_sfp[2 * 32768];// s_hat@Wsf partials (no bias)
__device__ float g_e[51200];      // doc scores
__device__ float g_en[6400];      // node scores
__device__ float g_a[51200];      // doc attention a
__device__ float g_cd[32768];     // c_d
__device__ float g_cdp[2 * 32768];// c_d t-split partials
__device__ float g_cg[32768];     // c_g
__device__ float g_cg2[32768];    // c_g2
__device__ float g_pg[128];       // p_gen
__device__ float g_o1[32768];     // out1
__device__ float g_vred[Bv * NSv * 2];     // per-chunk (max, sum) pairs
__device__ float g_logits[6400000];        // f32 logits (25.6 MB)
__device__ u16   g_Wdt[256 * 256];         // Whd^T bf16 [n][k]
__device__ u16   g_Wnt[256 * 256];         // Wn^T  bf16 [n][k]
__device__ u16   g_W2t[(size_t)VPAD * 256];// W2^T  bf16 [v][k] (25.7 MB)

__device__ __forceinline__ float sigm(float x) { return 1.f / (1.f + expf(-x)); }

__device__ __forceinline__ u16 f2bf(float f) {
    u32 u = __float_as_uint(f);
    return (u16)((u + 0x7fffu + ((u >> 16) & 1u)) >> 16);  // RNE
}

__device__ __forceinline__ bf16x8 cvt8(const float* __restrict__ p) {
    const float4 a = *(const float4*)p;
    const float4 b = *(const float4*)(p + 4);
    bf16x8 r;
    r[0] = (short)f2bf(a.x); r[1] = (short)f2bf(a.y);
    r[2] = (short)f2bf(a.z); r[3] = (short)f2bf(a.w);
    r[4] = (short)f2bf(b.x); r[5] = (short)f2bf(b.y);
    r[6] = (short)f2bf(b.z); r[7] = (short)f2bf(b.w);
    return r;
}

// tanh via exp; clamp so exp never overflows (tanh saturated anyway)
__device__ __forceinline__ float fast_tanh(float x) {
    x = fminf(fmaxf(x, -15.f), 15.f);
    float e = __expf(2.f * x);
    return (e - 1.f) / (e + 1.f);
}

// online (max,sum) merge: (m1,s1) <- (m1,s1) U (m2,s2)
__device__ __forceinline__ void ms_merge(float& m1, float& s1, float m2, float s2) {
    float M = fmaxf(m1, m2);
    s1 = s1 * expf(m1 - M) + s2 * expf(m2 - M);
    m1 = M;
}

// ---------------------------------------------------------------------------
// K0: transpose-cast  src[K][N] f32  ->  dst[n][k] bf16.
// grid = (Npad/32, K/32), block 256 (32x8). Reads n>=N give 0 (pad rows).
// ---------------------------------------------------------------------------
__global__ __launch_bounds__(256) void k_tc(
    const float* __restrict__ src, u16* __restrict__ dst, int K, int N)
{
    __shared__ float tile[32][33];
    const int n0 = blockIdx.x * 32, k0 = blockIdx.y * 32;
    const int tx = threadIdx.x & 31, ty = threadIdx.x >> 5;
    #pragma unroll
    for (int i = 0; i < 32; i += 8) {
        int k = k0 + ty + i, n = n0 + tx;
        tile[ty + i][tx] = (n < N) ? src[(size_t)k * N + n] : 0.f;
    }
    __syncthreads();
    #pragma unroll
    for (int i = 0; i < 32; i += 8) {
        int n = n0 + ty + i, k = k0 + tx;
        dst[(size_t)n * K + k] = f2bf(tile[tx][ty + i]);
    }
}

// ---------------------------------------------------------------------------
// K1a: x K-partials. grid (B, 4): block (b, ks) stages cat-chunk ks in LDS,
// computes partial x over its 256-row slice of Wx. 512 blocks = 2 waves/SIMD.
// ---------------------------------------------------------------------------
__global__ __launch_bounds__(256) void k_x(
    const int* __restrict__ y,
    const float* __restrict__ ctd, const float* __restrict__ ctg,
    const float* __restrict__ ctg2, const float* __restrict__ emb,
    const float* __restrict__ Wx)
{
    const int b = blockIdx.x, ks = blockIdx.y, j = threadIdx.x;
    __shared__ float cs[256];
    float v;
    if      (ks == 0) v = ctd [b * 256 + j];
    else if (ks == 1) v = ctg [b * 256 + j];
    else if (ks == 2) v = ctg2[b * 256 + j];
    else              v = emb[(size_t)y[b] * 256 + j];
    cs[j] = v;
    __syncthreads();

    float acc = 0.f;
    const float* w = Wx + (size_t)(ks * 256) * 256 + j;
    #pragma unroll 8
    for (int k = 0; k < 256; k++) acc += cs[k] * w[(size_t)k * 256];
    g_xp[ks * 32768 + b * 256 + j] = acc;
}

// ---------------------------------------------------------------------------
// K1b: gates = x@Wi + h@Wh + bi + bh. grid (B, 4 col-chunks), fully
// output-parallel (no atomics). Sums the 4 x-partials + bx while staging
// (col-chunk 0 also publishes g_x for k_node1's p_gen).
// ---------------------------------------------------------------------------
__global__ __launch_bounds__(256) void k_gates(
    const float* __restrict__ h_prev,
    const float* __restrict__ Wi, const float* __restrict__ Wh,
    const float* __restrict__ bi, const float* __restrict__ bh,
    const float* __restrict__ bx)
{
    const int b = blockIdx.x, cc = blockIdx.y, j = threadIdx.x;
    __shared__ float xs[256], hs[256];

    float xv = bx[j] + g_xp[b * 256 + j] + g_xp[32768 + b * 256 + j]
             + g_xp[65536 + b * 256 + j] + g_xp[98304 + b * 256 + j];
    xs[j] = xv;
    if (cc == 0) g_x[b * 256 + j] = xv;
    hs[j] = h_prev[b * 256 + j];
    __syncthreads();

    const int col = cc * 256 + j;
    float acc = bi[col] + bh[col];
    const float* wi = Wi + col;
    const float* wh = Wh + col;
    #pragma unroll 8
    for (int k = 0; k < 256; k++)
        acc += xs[k] * wi[(size_t)k * 1024] + hs[k] * wh[(size_t)k * 1024];
    g_gates[b * 1024 + col] = acc;
}

// ---------------------------------------------------------------------------
// K1c: LSTM elementwise + sd/sf K-partials. grid (B, 2): both K-halves
// redundantly compute the cheap cell update; ks==0 publishes h/c. Each block
// stages its half of s_hat=[h|c] and emits sd/sf partials (bias deferred to
// the k_scores epilogue).
// ---------------------------------------------------------------------------
__global__ __launch_bounds__(256) void k_cellsd(
    const float* __restrict__ c_prev,
    const float* __restrict__ Wsd, const float* __restrict__ Wsf,
    float* __restrict__ out_h, float* __restrict__ out_c)
{
    const int b = blockIdx.x, ks = blockIdx.y, j = threadIdx.x;
    __shared__ float sh[256];

    const float* gb = g_gates + b * 1024;
    float gi_ = gb[j], gf_ = gb[256 + j], gg_ = gb[512 + j], go_ = gb[768 + j];
    float cp = c_prev[b * 256 + j];
    float cn = sigm(gf_) * cp + sigm(gi_) * tanhf(gg_);
    float hn = sigm(go_) * tanhf(cn);
    if (ks == 0) {
        g_h[b * 256 + j] = hn;  g_c[b * 256 + j] = cn;
        out_h[b * 256 + j] = hn; out_c[b * 256 + j] = cn;
    }
    sh[j] = (ks == 0) ? hn : cn;   // s_hat rows [0,256) = h, [256,512) = c
    __syncthreads();

    float asd = 0.f, asf = 0.f;
    const float* wd = Wsd + (size_t)(ks * 256) * 256 + j;
    const float* wf = Wsf + (size_t)(ks * 256) * 256 + j;
    #pragma unroll 8
    for (int k = 0; k < 256; k++) {
        float sv = sh[k];
        asd += sv * wd[(size_t)k * 256];
        asf += sv * wf[(size_t)k * 256];
    }
    g_sdp[ks * 32768 + b * 256 + j] = asd;
    g_sfp[ks * 32768 + b * 256 + j] = asf;
}

// ---------------------------------------------------------------------------
// K2/K4 (MFMA): e[b,t] = vv . tanh( src[b,t,:]@W + add0+add1+abias + cov*wcw )
// Wt is the bf16 transposed weight [n][k]. grid (ceil(R/64), B), block 256.
// R10 retile: wave w owns the 64-col N-chunk [w*64, w*64+64); each wave does
// 4 M-tiles (all 64 block rows) x 4 N-tiles. Per k-step: 4 A + 4 B frag
// loads, all independent -> pipelined (vs 16 serialized B round trips).
// Epilogue: per-wave col-chunk partial sums, LDS cross-wave reduce.
// ---------------------------------------------------------------------------
__global__ __launch_bounds__(256) void k_scores(
    const float* __restrict__ src, int R,
    const u16* __restrict__ Wt,
    const float* __restrict__ addv0,  // s_hat@W partial (K lower half)
    const float* __restrict__ addv1,  // s_hat@W partial (K upper half)
    const float* __restrict__ abias,  // attention bias vector (bd / bf)
    const float* __restrict__ cov,    // nullptr for node attention
    const float* __restrict__ wcw,    // nullptr for node attention
    const float* __restrict__ vv,
    float* __restrict__ eout)
{
    const int b = blockIdx.y, t0 = blockIdx.x * 64;
    const int tid = threadIdx.x;
    const int lane = tid & 63, wave = tid >> 6;   // wave = 64-col N-chunk
    const int nlow = lane & 15, quad = lane >> 4;

    const u16* brow = Wt + (size_t)(wave * 64 + nlow) * 256 + quad * 8;

    bool tval[4]; const float* arow[4];
    #pragma unroll
    for (int mi = 0; mi < 4; mi++) {
        int trow = t0 + mi * 16 + nlow;
        tval[mi] = trow < R;
        arow[mi] = src + ((size_t)b * R + trow) * 256 + quad * 8;
    }

    const f32x4 zf = {0.f, 0.f, 0.f, 0.f};
    f32x4 acc[4][4];
    #pragma unroll
    for (int mi = 0; mi < 4; mi++)
        #pragma unroll
        for (int ni = 0; ni < 4; ni++) acc[mi][ni] = zf;

    for (int k0 = 0; k0 < 256; k0 += 32) {
        bf16x8 af[4], bf[4];
        #pragma unroll
        for (int mi = 0; mi < 4; mi++) {
            af[mi] = (bf16x8){0, 0, 0, 0, 0, 0, 0, 0};
            if (tval[mi]) af[mi] = cvt8(arow[mi] + k0);
        }
        #pragma unroll
        for (int ni = 0; ni < 4; ni++)
            bf[ni] = *(const bf16x8*)(brow + ni * 4096 + k0);
        #pragma unroll
        for (int mi = 0; mi < 4; mi++)
            #pragma unroll
            for (int ni = 0; ni < 4; ni++)
                acc[mi][ni] = __builtin_amdgcn_mfma_f32_16x16x32_bf16(
                    af[mi], bf[ni], acc[mi][ni], 0, 0, 0);
    }

    // epilogue: C row = mi*16 + quad*4 + r, col = wave*64 + ni*16 + nlow
    __shared__ float part[4][64];
    #pragma unroll
    for (int mi = 0; mi < 4; mi++) {
        float covt[4];
        #pragma unroll
        for (int r = 0; r < 4; r++) {
            int t = t0 + mi * 16 + quad * 4 + r;
            covt[r] = (cov && t < R) ? cov[b * R + t] : 0.f;
        }
        float s4[4] = {0.f, 0.f, 0.f, 0.f};
        #pragma unroll
        for (int ni = 0; ni < 4; ni++) {
            int col = wave * 64 + ni * 16 + nlow;
            float vvc = vv[col];
            float adc = addv0[b * 256 + col] + addv1[b * 256 + col] + abias[col];
            float wcc = wcw ? wcw[col] : 0.f;
            #pragma unroll
            for (int r = 0; r < 4; r++)
                s4[r] += vvc * fast_tanh(acc[mi][ni][r] + adc + covt[r] * wcc);
        }
        #pragma unroll
        for (int r = 0; r < 4; r++) {
            float s = s4[r];
            s += __shfl_xor(s, 1, 64);
            s += __shfl_xor(s, 2, 64);
            s += __shfl_xor(s, 4, 64);
            s += __shfl_xor(s, 8, 64);
            if (nlow == 0) part[wave][mi * 16 + quad * 4 + r] = s;
        }
    }
    __syncthreads();
    if (tid < 64) {
        int t = t0 + tid;
        if (t < R)
            eout[b * R + t] =
                part[0][tid] + part[1][tid] + part[2][tid] + part[3][tid];
    }
}

// ---------------------------------------------------------------------------
// K3: doc softmax (+mask renorm) only: a, coverage_next. Fully t-parallel.
// ---------------------------------------------------------------------------
__global__ __launch_bounds__(256) void k_doc(
    const float* __restrict__ mask,
    const float* __restrict__ cov,
    float* __restrict__ out_a, float* __restrict__ out_cov)
{
    const int b = blockIdx.x, tid = threadIdx.x;
    __shared__ float red[256];

    float e0 = g_e[b * TKv + tid];
    float e1 = (tid + 256 < TKv) ? g_e[b * TKv + tid + 256] : -1e30f;

    float m = fmaxf(e0, e1);
    red[tid] = m; __syncthreads();
    for (int s = 128; s > 0; s >>= 1) { if (tid < s) red[tid] = fmaxf(red[tid], red[tid + s]); __syncthreads(); }
    m = red[0]; __syncthreads();

    float p0 = expf(e0 - m) * mask[b * TKv + tid];
    float p1 = (tid + 256 < TKv) ? expf(e1 - m) * mask[b * TKv + tid + 256] : 0.f;
    red[tid] = p0 + p1; __syncthreads();
    for (int s = 128; s > 0; s >>= 1) { if (tid < s) red[tid] += red[tid + s]; __syncthreads(); }
    float inv = 1.f / red[0];

    float a0 = p0 * inv;
    g_a[b * TKv + tid] = a0;
    out_a[b * TKv + tid] = a0;
    out_cov[b * TKv + tid] = cov[b * TKv + tid] + a0;
    if (tid + 256 < TKv) {
        float a1 = p1 * inv;
        g_a[b * TKv + tid + 256] = a1;
        out_a[b * TKv + tid + 256] = a1;
        out_cov[b * TKv + tid + 256] = cov[b * TKv + tid + 256] + a1;
    }
}

// ---------------------------------------------------------------------------
// K3b: c_d t-split partials. grid (B, 2): block (b,ks) stages its 200-elem
// a-chunk in LDS, each thread does 200 serial MACs over enc (unroll 8).
// ---------------------------------------------------------------------------
__global__ __launch_bounds__(256) void k_cd(const float* __restrict__ enc)
{
    const int b = blockIdx.x, ks = blockIdx.y, tid = threadIdx.x;
    __shared__ float as_[200];
    if (tid < 200) as_[tid] = g_a[b * TKv + ks * 200 + tid];
    __syncthreads();

    const float* eb = enc + ((size_t)b * TKv + ks * 200) * 256 + tid;
    float acc = 0.f;
    #pragma unroll 8
    for (int t = 0; t < 200; t++) acc += as_[t] * eb[(size_t)t * 256];
    g_cdp[ks * 32768 + b * 256 + tid] = acc;
}

// ---------------------------------------------------------------------------
// K3c: flow_next. grid (B): 50 nodes x 4 threads (t-quarters of 100),
// shuffle-max across the 4, block-sum over 50, normalized write.
// ---------------------------------------------------------------------------
__global__ __launch_bounds__(256) void k_flow(
    const float* __restrict__ n2t, float* __restrict__ out_flow)
{
    const int b = blockIdx.x, tid = threadIdx.x;
    __shared__ float as_[TKv];
    __shared__ float fl[NKv];
    __shared__ float red[256];

    for (int t = tid; t < TKv; t += 256) as_[t] = g_a[b * TKv + t];
    __syncthreads();

    const int nn = tid >> 2, sub = tid & 3;
    float mx = 0.f;
    if (nn < NKv) {
        const float* nb = n2t + ((size_t)b * NKv + nn) * TKv + sub * 100;
        const float* ab = as_ + sub * 100;
        #pragma unroll 4
        for (int t = 0; t < 100; t++) mx = fmaxf(mx, ab[t] * nb[t]);
    }
    mx = fmaxf(mx, __shfl_xor(mx, 1, 64));
    mx = fmaxf(mx, __shfl_xor(mx, 2, 64));
    if (sub == 0 && nn < NKv) fl[nn] = mx;
    __syncthreads();

    float fv = (tid < NKv) ? fl[tid] : 0.f;
    red[tid] = fv; __syncthreads();
    for (int s = 128; s > 0; s >>= 1) { if (tid < s) red[tid] += red[tid + s]; __syncthreads(); }
    float fs = red[0];
    if (tid < NKv) out_flow[b * NKv + tid] = fl[tid] / fs;
}

// ---------------------------------------------------------------------------
// K5: node softmax chain (an, c_g, an2, c_g2, a_n2t), cd-partial sum, p_gen.
// All 50-length loops fully unrolled so loads pipeline; cg+cg2 share one
// enb pass. out1 moved to k_o1.
// ---------------------------------------------------------------------------
__global__ __launch_bounds__(256) void k_node1(
    const float* __restrict__ encn,
    const float* __restrict__ maskn,
    const float* __restrict__ flow,
    const float* __restrict__ graph,
    const float* __restrict__ n2t,
    const float* __restrict__ Wpg, const float* __restrict__ bpg,
    float* __restrict__ out_cd, float* __restrict__ out_cg,
    float* __restrict__ out_cg2, float* __restrict__ out_ant,
    float* __restrict__ out_pgen)
{
    const int b = blockIdx.x, tid = threadIdx.x;
    __shared__ float ans[NKv], an2s[NKv], red[256];

    // c_d = sum of t-split partials
    const float cd = g_cdp[b * 256 + tid] + g_cdp[32768 + b * 256 + tid];
    g_cd[b * 256 + tid] = cd;
    out_cd[b * 256 + tid] = cd;

    // node softmax -> flow-weighted renorm
    float v = (tid < NKv) ? g_en[b * NKv + tid] : -1e30f;
    red[tid] = v; __syncthreads();
    for (int s = 128; s > 0; s >>= 1) { if (tid < s) red[tid] = fmaxf(red[tid], red[tid + s]); __syncthreads(); }
    float m = red[0]; __syncthreads();

    float p = (tid < NKv) ? expf(v - m) * maskn[b * NKv + tid] : 0.f;
    red[tid] = p; __syncthreads();
    for (int s = 128; s > 0; s >>= 1) { if (tid < s) red[tid] += red[tid + s]; __syncthreads(); }
    float S = red[0]; __syncthreads();
    p = (tid < NKv) ? (p / S) * flow[b * NKv + tid] : 0.f;
    red[tid] = p; __syncthreads();
    for (int s = 128; s > 0; s >>= 1) { if (tid < s) red[tid] += red[tid + s]; __syncthreads(); }
    float S2 = red[0]; __syncthreads();
    if (tid < NKv) ans[tid] = p / S2;
    __syncthreads();

    // an2 = (ans @ graph) * mask, renormalized
    float q = 0.f;
    if (tid < NKv) {
        const float* gb = graph + (size_t)b * NKv * NKv + tid;
        #pragma unroll
        for (int n = 0; n < NKv; n++) q += ans[n] * gb[n * NKv];
        q *= maskn[b * NKv + tid];
    }
    red[tid] = q; __syncthreads();
    for (int s = 128; s > 0; s >>= 1) { if (tid < s) red[tid] += red[tid + s]; __syncthreads(); }
    float S3 = red[0]; __syncthreads();
    if (tid < NKv) an2s[tid] = q / S3;
    __syncthreads();

    // c_g and c_g2 in one pass over encn
    float cg = 0.f, cg2 = 0.f;
    {
        const float* enb = encn + (size_t)b * NKv * 256 + tid;
        #pragma unroll
        for (int n = 0; n < NKv; n++) {
            float e = enb[n * 256];
            cg  += ans[n]  * e;
            cg2 += an2s[n] * e;
        }
    }
    g_cg[b * 256 + tid] = cg;   out_cg[b * 256 + tid] = cg;
    g_cg2[b * 256 + tid] = cg2; out_cg2[b * 256 + tid] = cg2;

    // a_n2t with normalization
    float at0 = 0.f, at1 = 0.f;
    {
        const float* nb = n2t + (size_t)b * NKv * TKv;
        #pragma unroll
        for (int n = 0; n < NKv; n++) {
            float an = ans[n];
            at0 += an * nb[n * TKv + tid];
            if (tid + 256 < TKv) at1 += an * nb[n * TKv + tid + 256];
        }
    }
    float loc = at0 + ((tid + 256 < TKv) ? at1 : 0.f);
    red[tid] = loc; __syncthreads();
    for (int s = 128; s > 0; s >>= 1) { if (tid < s) red[tid] += red[tid + s]; __syncthreads(); }
    float S4 = red[0]; __syncthreads();
    out_ant[b * TKv + tid] = at0 / S4;
    if (tid + 256 < TKv) out_ant[b * TKv + tid + 256] = at1 / S4;

    // p_gen
    float hvv = g_h[b * 256 + tid], cvv = g_c[b * 256 + tid];
    float xvv = g_x[b * 256 + tid];
    float part = cd  * Wpg[tid]        + cg  * Wpg[256 + tid]
               + cg2 * Wpg[512 + tid]  + hvv * Wpg[768 + tid]
               + cvv * Wpg[1024 + tid] + xvv * Wpg[1280 + tid];
    red[tid] = part; __syncthreads();
    for (int s = 128; s > 0; s >>= 1) { if (tid < s) red[tid] += red[tid + s]; __syncthreads(); }
    if (tid == 0) {
        float pg = sigm(red[0] + bpg[0]);
        g_pg[b] = pg; out_pgen[b] = pg;
    }
}

// ---------------------------------------------------------------------------
// K6: out1 = [h|cd|cg|cg2] @ W1 + b1. grid (B, 4 col-chunks of 64).
// Thread (kq, lane): kq = tid>>6 K-quarter, lane picks output col; 256
// serial MACs each (unroll 8), LDS cross-kq reduce.
// ---------------------------------------------------------------------------
__global__ __launch_bounds__(256) void k_o1(
    const float* __restrict__ W1, const float* __restrict__ b1)
{
    const int b = blockIdx.x, cc = blockIdx.y, tid = threadIdx.x;
    __shared__ float cat[1024];
    __shared__ float red[256];

    cat[tid]       = g_h  [b * 256 + tid];
    cat[256 + tid] = g_cd [b * 256 + tid];
    cat[512 + tid] = g_cg [b * 256 + tid];
    cat[768 + tid] = g_cg2[b * 256 + tid];
    __syncthreads();

    const int lane = tid & 63, kq = tid >> 6;
    const int col = cc * 64 + lane;
    const float* w  = W1 + (size_t)(kq * 256) * 256 + col;
    const float* cs = cat + kq * 256;
    float acc = 0.f;
    #pragma unroll 8
    for (int k = 0; k < 256; k++) acc += cs[k] * w[(size_t)k * 256];
    red[tid] = acc; __syncthreads();

    if (tid < 64) {
        float o = b1[cc * 64 + tid]
                + red[tid] + red[64 + tid] + red[128 + tid] + red[192 + tid];
        g_o1[b * 256 + cc * 64 + tid] = o;
    }
}

// ---------------------------------------------------------------------------
// K7 (MFMA): logits = out1[128,256] @ W2[256,50000] + b2 -> g_logits (f32).
// R10 retile: 64-col blocks (grid VPAD/64 = 784); wave w owns rows
// [w*32, w*32+32) as 2 M-tiles x 4 N-tiles. Per k-step: 2 A + 4 B loads,
// acc = 32 VGPRs -> fully pipelined.
// ---------------------------------------------------------------------------
__global__ __launch_bounds__(256) void k_logits(const float* __restrict__ b2)
{
    const int v0 = blockIdx.x * 64;
    const int tid = threadIdx.x;
    const int lane = tid & 63, wave = tid >> 6;
    const int nlow = lane & 15, quad = lane >> 4;

    const float* a0p = g_o1 + (wave * 32 + nlow) * 256 + quad * 8;
    const float* a1p = a0p + 16 * 256;
    const u16* bbase = g_W2t + (size_t)(v0 + nlow) * 256 + quad * 8;

    const f32x4 zf = {0.f, 0.f, 0.f, 0.f};
    f32x4 acc0[4], acc1[4];
    #pragma unroll
    for (int i = 0; i < 4; i++) { acc0[i] = zf; acc1[i] = zf; }

    for (int k0 = 0; k0 < 256; k0 += 32) {
        bf16x8 a0 = cvt8(a0p + k0);
        bf16x8 a1 = cvt8(a1p + k0);
        #pragma unroll
        for (int nt = 0; nt < 4; nt++) {
            bf16x8 bf = *(const bf16x8*)(bbase + (size_t)nt * 4096 + k0);
            acc0[nt] = __builtin_amdgcn_mfma_f32_16x16x32_bf16(a0, bf, acc0[nt], 0, 0, 0);
            acc1[nt] = __builtin_amdgcn_mfma_f32_16x16x32_bf16(a1, bf, acc1[nt], 0, 0, 0);
        }
    }

    #pragma unroll
    for (int nt = 0; nt < 4; nt++) {
        int v = v0 + nt * 16 + nlow;
        if (v < Vv) {
            float bb = b2[v];
            #pragma unroll
            for (int r = 0; r < 4; r++) {
                int row0 = wave * 32 + quad * 4 + r;
                g_logits[(size_t)row0 * Vv + v]        = acc0[nt][r] + bb;
                g_logits[(size_t)(row0 + 16) * Vv + v] = acc1[nt][r] + bb;
            }
        }
    }
}

// ---------------------------------------------------------------------------
// K8a: per-chunk online (max, sum) partials. grid (B, NS), float4 loads.
// Chunk ks covers [ks*3136, min(+3136, 50000)) — always float4-exact.
// ---------------------------------------------------------------------------
__global__ __launch_bounds__(256) void k_vpart()
{
    const int b = blockIdx.x, ks = blockIdx.y, tid = threadIdx.x;
    __shared__ float rm[256], rs[256];

    const int base = ks * CHUNKv;
    const int end  = min(base + CHUNKv, Vv);
    const int n4   = (end - base) >> 2;
    const float4* L4 = (const float4*)(g_logits + (size_t)b * Vv + base);

    float m = -1e30f, s = 0.f;
    for (int i = tid; i < n4; i += 256) {
        float4 x = L4[i];
        float mx = fmaxf(fmaxf(x.x, x.y), fmaxf(x.z, x.w));
        if (mx > m) { s *= expf(m - mx); m = mx; }
        s += expf(x.x - m) + expf(x.y - m) + expf(x.z - m) + expf(x.w - m);
    }
    rm[tid] = m; rs[tid] = s; __syncthreads();
    for (int off = 128; off > 0; off >>= 1) {
        if (tid < off) {
            float m1 = rm[tid], s1 = rs[tid];
            ms_merge(m1, s1, rm[tid + off], rs[tid + off]);
            rm[tid] = m1; rs[tid] = s1;
        }
        __syncthreads();
    }
    if (tid == 0) {
        g_vred[(b * NSv + ks) * 2]     = rm[0];
        g_vred[(b * NSv + ks) * 2 + 1] = rs[0];
    }
}

// ---------------------------------------------------------------------------
// K8b: merge the NS pairs (broadcast, L2-hot), write exp(x-M)*pg/S for the
// chunk with float4 stores. grid (B, NS).
// ---------------------------------------------------------------------------
__global__ __launch_bounds__(256) void k_vwrite(float* __restrict__ outF)
{
    const int b = blockIdx.x, ks = blockIdx.y, tid = threadIdx.x;

    float M = -1e30f, S = 0.f;
    #pragma unroll
    for (int i = 0; i < NSv; i++) {
        float mi = g_vred[(b * NSv + i) * 2];
        float si = g_vred[(b * NSv + i) * 2 + 1];
        ms_merge(M, S, mi, si);
    }
    const float inv = g_pg[b] / S;

    const int base = ks * CHUNKv;
    const int end  = min(base + CHUNKv, Vv);
    const int n4   = (end - base) >> 2;
    const float4* L4 = (const float4*)(g_logits + (size_t)b * Vv + base);
    float4* O4 = (float4*)(outF + (size_t)b * Vv + base);

    for (int i = tid; i < n4; i += 256) {
        float4 x = L4[i];
        float4 r;
        r.x = expf(x.x - M) * inv;
        r.y = expf(x.y - M) * inv;
        r.z = expf(x.z - M) * inv;
        r.w = expf(x.w - M) * inv;
        O4[i] = r;
    }
}

// ---------------------------------------------------------------------------
// K8c: row-local pointer scatter (1-pg)*a[b,t] at voc_d[b,t]. Runs after
// k_vwrite (stream order guarantees the base probs are in place).
// ---------------------------------------------------------------------------
__global__ __launch_bounds__(256) void k_scatter(
    float* __restrict__ outF, const int* __restrict__ vocd)
{
    const int b = blockIdx.x, tid = threadIdx.x;
    float* Ob = outF + (size_t)b * Vv;
    const float omp = 1.f - g_pg[b];
    for (int t = tid; t < TKv; t += 256)
        atomicAdd(Ob + vocd[b * TKv + t], omp * g_a[b * TKv + t]);
}

// ---------------------------------------------------------------------------

extern "C" void kernel_launch(void* const* d_in, const int* in_sizes, int n_in,
                              void* d_out, int out_size, void* d_ws, size_t ws_size,
                              hipStream_t stream)
{
    (void)in_sizes; (void)n_in; (void)out_size; (void)d_ws; (void)ws_size;

    const int*   y      = (const int*)d_in[0];
    const float* h_prev = (const float*)d_in[1];
    const float* c_prev = (const float*)d_in[2];
    const float* enc    = (const float*)d_in[3];
    const float* encn   = (const float*)d_in[4];
    const float* mask   = (const float*)d_in[5];
    const float* maskn  = (const float*)d_in[6];
    const float* ctd    = (const float*)d_in[7];
    const float* ctg    = (const float*)d_in[8];
    const float* ctg2   = (const float*)d_in[9];
    const float* cov    = (const float*)d_in[10];
    const float* flow   = (const float*)d_in[11];
    const float* n2t    = (const float*)d_in[12];
    const float* graph  = (const float*)d_in[13];
    const int*   vocd   = (const int*)d_in[14];
    // d_in[15] = step (unused)
    const float* emb    = (const float*)d_in[16];
    const float* Wx     = (const float*)d_in[17];
    const float* bx     = (const float*)d_in[18];
    const float* Wi     = (const float*)d_in[19];
    const float* Wh     = (const float*)d_in[20];
    const float* bi     = (const float*)d_in[21];
    const float* bh     = (const float*)d_in[22];
    const float* Whd    = (const float*)d_in[23];
    const float* Wsd    = (const float*)d_in[24];
    const float* wcdw   = (const float*)d_in[25];
    const float* vd     = (const float*)d_in[26];
    const float* bd     = (const float*)d_in[27];
    const float* Wn     = (const float*)d_in[28];
    const float* Wsf    = (const float*)d_in[29];
    const float* vf     = (const float*)d_in[30];
    const float* bfv    = (const float*)d_in[31];
    const float* Wpg    = (const float*)d_in[32];
    const float* bpg    = (const float*)d_in[33];
    const float* W1     = (const float*)d_in[34];
    const float* b1     = (const float*)d_in[35];
    const float* W2     = (const float*)d_in[36];
    const float* b2     = (const float*)d_in[37];

    float* o = (float*)d_out;                 // FLOAT32 output
    float* o_final = o;                       // 6,400,000
    float* o_h     = o + 6400000;
    float* o_c     = o + 6432768;
    float* o_cd    = o + 6465536;
    float* o_cg    = o + 6498304;
    float* o_cg2   = o + 6531072;
    float* o_a     = o + 6563840;
    float* o_ant   = o + 6615040;
    float* o_pg    = o + 6666240;
    float* o_cov   = o + 6666368;
    float* o_fl    = o + 6717568;

    float* g_e_p;   hipGetSymbolAddress((void**)&g_e_p,   HIP_SYMBOL(g_e));
    float* g_en_p;  hipGetSymbolAddress((void**)&g_en_p,  HIP_SYMBOL(g_en));
    float* g_sdp_p; hipGetSymbolAddress((void**)&g_sdp_p, HIP_SYMBOL(g_sdp));
    float* g_sfp_p; hipGetSymbolAddress((void**)&g_sfp_p, HIP_SYMBOL(g_sfp));
    u16*   g_Wdt_p; hipGetSymbolAddress((void**)&g_Wdt_p, HIP_SYMBOL(g_Wdt));
    u16*   g_Wnt_p; hipGetSymbolAddress((void**)&g_Wnt_p, HIP_SYMBOL(g_Wnt));
    u16*   g_W2t_p; hipGetSymbolAddress((void**)&g_W2t_p, HIP_SYMBOL(g_W2t));

    // transpose-cast weights to bf16 [n][k]
    k_tc<<<dim3(8, 8), dim3(256), 0, stream>>>(Whd, g_Wdt_p, 256, 256);
    k_tc<<<dim3(8, 8), dim3(256), 0, stream>>>(Wn,  g_Wnt_p, 256, 256);
    k_tc<<<dim3(VPAD / 32, 8), dim3(256), 0, stream>>>(W2, g_W2t_p, 256, Vv);

    // LSTM front-end, latency-optimized: 512/512/256 blocks
    k_x<<<dim3(Bv, 4), dim3(256), 0, stream>>>(y, ctd, ctg, ctg2, emb, Wx);

    k_gates<<<dim3(Bv, 4), dim3(256), 0, stream>>>(h_prev, Wi, Wh, bi, bh, bx);

    k_cellsd<<<dim3(Bv, 2), dim3(256), 0, stream>>>(c_prev, Wsd, Wsf, o_h, o_c);

    k_scores<<<dim3(7, Bv), dim3(256), 0, stream>>>(
        enc, TKv, g_Wdt_p, g_sdp_p, g_sdp_p + 32768, bd, cov, wcdw, vd, g_e_p);

    k_scores<<<dim3(1, Bv), dim3(256), 0, stream>>>(
        encn, NKv, g_Wnt_p, g_sfp_p, g_sfp_p + 32768, bfv,
        nullptr, nullptr, vf, g_en_p);

    // doc attention back-end, latency-optimized
    k_doc<<<dim3(Bv), dim3(256), 0, stream>>>(mask, cov, o_a, o_cov);

    k_cd<<<dim3(Bv, 2), dim3(256), 0, stream>>>(enc);

    k_flow<<<dim3(Bv), dim3(256), 0, stream>>>(n2t, o_fl);

    k_node1<<<dim3(Bv), dim3(256), 0, stream>>>(
        encn, maskn, flow, graph, n2t, Wpg, bpg,
        o_cd, o_cg, o_cg2, o_ant, o_pg);

    k_o1<<<dim3(Bv, 4), dim3(256), 0, stream>>>(W1, b1);

    k_logits<<<dim3(VPAD / 64), dim3(256), 0, stream>>>(b2);

    // vocab softmax, latency-optimized: B x 16 chunk blocks
    k_vpart<<<dim3(Bv, NSv), dim3(256), 0, stream>>>();

    k_vwrite<<<dim3(Bv, NSv), dim3(256), 0, stream>>>(o_final);

    k_scatter<<<dim3(Bv), dim3(256), 0, stream>>>(o_final, vocd);
}

// Round 5
// 506.324 us; speedup vs baseline: 1.9391x; 1.0459x over previous
//
#include <hip/hip_runtime.h>
#include <stdint.h>

// ---------------------------------------------------------------------------
// LSTM pointer-generator decoder step, B=128 TK=400 NK=50 H=E=256 V=50000.
// Round 11: k_scores was still register-recycling (VGPR=84 < the ~100 needed
// to hoist 8 loads; VALUBusy 18.6% = in-loop f32->bf16 cvt). Fixes:
// (1) k_cvt pre-converts enc/encn to bf16 once (A-frag = one 16B load,
//     no cvt in the hot loop), (2) wave tile 2Mx4N (acc 32 VGPR, all frags
//     hoistable + prefetch headroom), (3) 32-row blocks -> grid (13,128),
//     6.5 waves/SIMD. k_cd split (B,2)->(B,8) for the same TLP reason;
//     k_node1 sums 8 cd partials. Everything else unchanged from R10.
// ---------------------------------------------------------------------------

typedef unsigned short u16;
typedef unsigned int   u32;

#define Bv  128
#define TKv 400
#define NKv 50
#define Hv  256
#define Vv  50000
#define VPAD 50176   // 50000 padded to multiple of 128
#define NSv 16
#define CHUNKv 3136  // VPAD / NSv

typedef __attribute__((ext_vector_type(8))) short bf16x8;
typedef __attribute__((ext_vector_type(4))) float f32x4;

// ---- module-global workspace (no d_ws dependency) -------------------------
__device__ float g_x[32768];      // x = cat @ Wx + bx
__device__ float g_xp[4 * 32768]; // x K-partials
__device__ float g_gates[131072]; // LSTM gates [B,4H]
__device__ float g_h[32768];      // h_new
__device__ float g_c[32768];      // c_new
__device__ float g_sdp[2 * 32768];// s_hat@Wsd partials (no bias)
__device__ float g_sfp[2 * 32768];// s_hat@Wsf partials (no bias)
__device__ float g_e[51200];      // doc scores
__device__ float g_en[6400];      // node scores
__device__ float g_a[51200];      // doc attention a
__device__ float g_cd[32768];     // c_d
__device__ float g_cdp[8 * 32768];// c_d t-split partials (8 chunks of 50)
__device__ float g_cg[32768];     // c_g
__device__ float g_cg2[32768];    // c_g2
__device__ float g_pg[128];       // p_gen
__device__ float g_o1[32768];     // out1
__device__ float g_vred[Bv * NSv * 2];     // per-chunk (max, sum) pairs
__device__ float g_logits[6400000];        // f32 logits (25.6 MB)
__device__ u16   g_Wdt[256 * 256];         // Whd^T bf16 [n][k]
__device__ u16   g_Wnt[256 * 256];         // Wn^T  bf16 [n][k]
__device__ u16   g_W2t[(size_t)VPAD * 256];// W2^T  bf16 [v][k] (25.7 MB)
__device__ u16   g_encb[(size_t)Bv * TKv * 256]; // enc bf16 (26.2 MB)
__device__ u16   g_encnb[(size_t)Bv * NKv * 256];// encn bf16 (3.3 MB)

__device__ __forceinline__ float sigm(float x) { return 1.f / (1.f + expf(-x)); }

__device__ __forceinline__ u16 f2bf(float f) {
    u32 u = __float_as_uint(f);
    return (u16)((u + 0x7fffu + ((u >> 16) & 1u)) >> 16);  // RNE
}

__device__ __forceinline__ bf16x8 cvt8(const float* __restrict__ p) {
    const float4 a = *(const float4*)p;
    const float4 b = *(const float4*)(p + 4);
    bf16x8 r;
    r[0] = (short)f2bf(a.x); r[1] = (short)f2bf(a.y);
    r[2] = (short)f2bf(a.z); r[3] = (short)f2bf(a.w);
    r[4] = (short)f2bf(b.x); r[5] = (short)f2bf(b.y);
    r[6] = (short)f2bf(b.z); r[7] = (short)f2bf(b.w);
    return r;
}

// tanh via exp; clamp so exp never overflows (tanh saturated anyway)
__device__ __forceinline__ float fast_tanh(float x) {
    x = fminf(fmaxf(x, -15.f), 15.f);
    float e = __expf(2.f * x);
    return (e - 1.f) / (e + 1.f);
}

// online (max,sum) merge: (m1,s1) <- (m1,s1) U (m2,s2)
__device__ __forceinline__ void ms_merge(float& m1, float& s1, float m2, float s2) {
    float M = fmaxf(m1, m2);
    s1 = s1 * expf(m1 - M) + s2 * expf(m2 - M);
    m1 = M;
}

// ---------------------------------------------------------------------------
// K-1: streaming f32 -> bf16 (RNE, identical bits to the old in-loop cvt8).
// n8 = element count / 8; grid-stride over bf16x8 groups.
// ---------------------------------------------------------------------------
__global__ __launch_bounds__(256) void k_cvt(
    const float* __restrict__ src, u16* __restrict__ dst, int n8)
{
    int i = blockIdx.x * 256 + threadIdx.x;
    const int stride = gridDim.x * 256;
    for (; i < n8; i += stride)
        *(bf16x8*)(dst + (size_t)i * 8) = cvt8(src + (size_t)i * 8);
}

// ---------------------------------------------------------------------------
// K0: transpose-cast  src[K][N] f32  ->  dst[n][k] bf16.
// grid = (Npad/32, K/32), block 256 (32x8). Reads n>=N give 0 (pad rows).
// ---------------------------------------------------------------------------
__global__ __launch_bounds__(256) void k_tc(
    const float* __restrict__ src, u16* __restrict__ dst, int K, int N)
{
    __shared__ float tile[32][33];
    const int n0 = blockIdx.x * 32, k0 = blockIdx.y * 32;
    const int tx = threadIdx.x & 31, ty = threadIdx.x >> 5;
    #pragma unroll
    for (int i = 0; i < 32; i += 8) {
        int k = k0 + ty + i, n = n0 + tx;
        tile[ty + i][tx] = (n < N) ? src[(size_t)k * N + n] : 0.f;
    }
    __syncthreads();
    #pragma unroll
    for (int i = 0; i < 32; i += 8) {
        int n = n0 + ty + i, k = k0 + tx;
        dst[(size_t)n * K + k] = f2bf(tile[tx][ty + i]);
    }
}

// ---------------------------------------------------------------------------
// K1a: x K-partials. grid (B, 4): block (b, ks) stages cat-chunk ks in LDS,
// computes partial x over its 256-row slice of Wx. 512 blocks = 2 waves/SIMD.
// ---------------------------------------------------------------------------
__global__ __launch_bounds__(256) void k_x(
    const int* __restrict__ y,
    const float* __restrict__ ctd, const float* __restrict__ ctg,
    const float* __restrict__ ctg2, const float* __restrict__ emb,
    const float* __restrict__ Wx)
{
    const int b = blockIdx.x, ks = blockIdx.y, j = threadIdx.x;
    __shared__ float cs[256];
    float v;
    if      (ks == 0) v = ctd [b * 256 + j];
    else if (ks == 1) v = ctg [b * 256 + j];
    else if (ks == 2) v = ctg2[b * 256 + j];
    else              v = emb[(size_t)y[b] * 256 + j];
    cs[j] = v;
    __syncthreads();

    float acc = 0.f;
    const float* w = Wx + (size_t)(ks * 256) * 256 + j;
    #pragma unroll 8
    for (int k = 0; k < 256; k++) acc += cs[k] * w[(size_t)k * 256];
    g_xp[ks * 32768 + b * 256 + j] = acc;
}

// ---------------------------------------------------------------------------
// K1b: gates = x@Wi + h@Wh + bi + bh. grid (B, 4 col-chunks), fully
// output-parallel (no atomics). Sums the 4 x-partials + bx while staging
// (col-chunk 0 also publishes g_x for k_node1's p_gen).
// ---------------------------------------------------------------------------
__global__ __launch_bounds__(256) void k_gates(
    const float* __restrict__ h_prev,
    const float* __restrict__ Wi, const float* __restrict__ Wh,
    const float* __restrict__ bi, const float* __restrict__ bh,
    const float* __restrict__ bx)
{
    const int b = blockIdx.x, cc = blockIdx.y, j = threadIdx.x;
    __shared__ float xs[256], hs[256];

    float xv = bx[j] + g_xp[b * 256 + j] + g_xp[32768 + b * 256 + j]
             + g_xp[65536 + b * 256 + j] + g_xp[98304 + b * 256 + j];
    xs[j] = xv;
    if (cc == 0) g_x[b * 256 + j] = xv;
    hs[j] = h_prev[b * 256 + j];
    __syncthreads();

    const int col = cc * 256 + j;
    float acc = bi[col] + bh[col];
    const float* wi = Wi + col;
    const float* wh = Wh + col;
    #pragma unroll 8
    for (int k = 0; k < 256; k++)
        acc += xs[k] * wi[(size_t)k * 1024] + hs[k] * wh[(size_t)k * 1024];
    g_gates[b * 1024 + col] = acc;
}

// ---------------------------------------------------------------------------
// K1c: LSTM elementwise + sd/sf K-partials. grid (B, 2): both K-halves
// redundantly compute the cheap cell update; ks==0 publishes h/c. Each block
// stages its half of s_hat=[h|c] and emits sd/sf partials (bias deferred to
// the k_scores epilogue).
// ---------------------------------------------------------------------------
__global__ __launch_bounds__(256) void k_cellsd(
    const float* __restrict__ c_prev,
    const float* __restrict__ Wsd, const float* __restrict__ Wsf,
    float* __restrict__ out_h, float* __restrict__ out_c)
{
    const int b = blockIdx.x, ks = blockIdx.y, j = threadIdx.x;
    __shared__ float sh[256];

    const float* gb = g_gates + b * 1024;
    float gi_ = gb[j], gf_ = gb[256 + j], gg_ = gb[512 + j], go_ = gb[768 + j];
    float cp = c_prev[b * 256 + j];
    float cn = sigm(gf_) * cp + sigm(gi_) * tanhf(gg_);
    float hn = sigm(go_) * tanhf(cn);
    if (ks == 0) {
        g_h[b * 256 + j] = hn;  g_c[b * 256 + j] = cn;
        out_h[b * 256 + j] = hn; out_c[b * 256 + j] = cn;
    }
    sh[j] = (ks == 0) ? hn : cn;   // s_hat rows [0,256) = h, [256,512) = c
    __syncthreads();

    float asd = 0.f, asf = 0.f;
    const float* wd = Wsd + (size_t)(ks * 256) * 256 + j;
    const float* wf = Wsf + (size_t)(ks * 256) * 256 + j;
    #pragma unroll 8
    for (int k = 0; k < 256; k++) {
        float sv = sh[k];
        asd += sv * wd[(size_t)k * 256];
        asf += sv * wf[(size_t)k * 256];
    }
    g_sdp[ks * 32768 + b * 256 + j] = asd;
    g_sfp[ks * 32768 + b * 256 + j] = asf;
}

// ---------------------------------------------------------------------------
// K2/K4 (MFMA): e[b,t] = vv . tanh( src[b,t,:]@W + add0+add1+abias + cov*wcw )
// R11: A is PRE-CONVERTED bf16 (g_encb / g_encnb) — one 16B load per frag,
// no in-loop cvt. Block = 32 rows x 256 cols, grid (ceil(R/32), B).
// Wave w owns the 64-col N-chunk: 2 M-tiles x 4 N-tiles, acc 32 VGPR,
// 6 hoistable loads per k-step + prefetch headroom.
// ---------------------------------------------------------------------------
__global__ __launch_bounds__(256) void k_scores(
    const u16* __restrict__ srcb, int R,
    const u16* __restrict__ Wt,
    const float* __restrict__ addv0,  // s_hat@W partial (K lower half)
    const float* __restrict__ addv1,  // s_hat@W partial (K upper half)
    const float* __restrict__ abias,  // attention bias vector (bd / bf)
    const float* __restrict__ cov,    // nullptr for node attention
    const float* __restrict__ wcw,    // nullptr for node attention
    const float* __restrict__ vv,
    float* __restrict__ eout)
{
    const int b = blockIdx.y, t0 = blockIdx.x * 32;
    const int tid = threadIdx.x;
    const int lane = tid & 63, wave = tid >> 6;   // wave = 64-col N-chunk
    const int nlow = lane & 15, quad = lane >> 4;

    const u16* brow = Wt + (size_t)(wave * 64 + nlow) * 256 + quad * 8;

    bool tval[2]; const u16* arow[2];
    #pragma unroll
    for (int mi = 0; mi < 2; mi++) {
        int trow = t0 + mi * 16 + nlow;
        tval[mi] = trow < R;
        arow[mi] = srcb + ((size_t)b * R + trow) * 256 + quad * 8;
    }

    const f32x4 zf = {0.f, 0.f, 0.f, 0.f};
    f32x4 acc[2][4];
    #pragma unroll
    for (int mi = 0; mi < 2; mi++)
        #pragma unroll
        for (int ni = 0; ni < 4; ni++) acc[mi][ni] = zf;

    for (int k0 = 0; k0 < 256; k0 += 32) {
        bf16x8 af[2], bf[4];
        #pragma unroll
        for (int mi = 0; mi < 2; mi++) {
            af[mi] = (bf16x8){0, 0, 0, 0, 0, 0, 0, 0};
            if (tval[mi]) af[mi] = *(const bf16x8*)(arow[mi] + k0);
        }
        #pragma unroll
        for (int ni = 0; ni < 4; ni++)
            bf[ni] = *(const bf16x8*)(brow + ni * 4096 + k0);
        #pragma unroll
        for (int mi = 0; mi < 2; mi++)
            #pragma unroll
            for (int ni = 0; ni < 4; ni++)
                acc[mi][ni] = __builtin_amdgcn_mfma_f32_16x16x32_bf16(
                    af[mi], bf[ni], acc[mi][ni], 0, 0, 0);
    }

    // epilogue: C row = mi*16 + quad*4 + r, col = wave*64 + ni*16 + nlow
    __shared__ float part[4][32];
    #pragma unroll
    for (int mi = 0; mi < 2; mi++) {
        float covt[4];
        #pragma unroll
        for (int r = 0; r < 4; r++) {
            int t = t0 + mi * 16 + quad * 4 + r;
            covt[r] = (cov && t < R) ? cov[b * R + t] : 0.f;
        }
        float s4[4] = {0.f, 0.f, 0.f, 0.f};
        #pragma unroll
        for (int ni = 0; ni < 4; ni++) {
            int col = wave * 64 + ni * 16 + nlow;
            float vvc = vv[col];
            float adc = addv0[b * 256 + col] + addv1[b * 256 + col] + abias[col];
            float wcc = wcw ? wcw[col] : 0.f;
            #pragma unroll
            for (int r = 0; r < 4; r++)
                s4[r] += vvc * fast_tanh(acc[mi][ni][r] + adc + covt[r] * wcc);
        }
        #pragma unroll
        for (int r = 0; r < 4; r++) {
            float s = s4[r];
            s += __shfl_xor(s, 1, 64);
            s += __shfl_xor(s, 2, 64);
            s += __shfl_xor(s, 4, 64);
            s += __shfl_xor(s, 8, 64);
            if (nlow == 0) part[wave][mi * 16 + quad * 4 + r] = s;
        }
    }
    __syncthreads();
    if (tid < 32) {
        int t = t0 + tid;
        if (t < R)
            eout[b * R + t] =
                part[0][tid] + part[1][tid] + part[2][tid] + part[3][tid];
    }
}

// ---------------------------------------------------------------------------
// K3: doc softmax (+mask renorm) only: a, coverage_next. Fully t-parallel.
// ---------------------------------------------------------------------------
__global__ __launch_bounds__(256) void k_doc(
    const float* __restrict__ mask,
    const float* __restrict__ cov,
    float* __restrict__ out_a, float* __restrict__ out_cov)
{
    const int b = blockIdx.x, tid = threadIdx.x;
    __shared__ float red[256];

    float e0 = g_e[b * TKv + tid];
    float e1 = (tid + 256 < TKv) ? g_e[b * TKv + tid + 256] : -1e30f;

    float m = fmaxf(e0, e1);
    red[tid] = m; __syncthreads();
    for (int s = 128; s > 0; s >>= 1) { if (tid < s) red[tid] = fmaxf(red[tid], red[tid + s]); __syncthreads(); }
    m = red[0]; __syncthreads();

    float p0 = expf(e0 - m) * mask[b * TKv + tid];
    float p1 = (tid + 256 < TKv) ? expf(e1 - m) * mask[b * TKv + tid + 256] : 0.f;
    red[tid] = p0 + p1; __syncthreads();
    for (int s = 128; s > 0; s >>= 1) { if (tid < s) red[tid] += red[tid + s]; __syncthreads(); }
    float inv = 1.f / red[0];

    float a0 = p0 * inv;
    g_a[b * TKv + tid] = a0;
    out_a[b * TKv + tid] = a0;
    out_cov[b * TKv + tid] = cov[b * TKv + tid] + a0;
    if (tid + 256 < TKv) {
        float a1 = p1 * inv;
        g_a[b * TKv + tid + 256] = a1;
        out_a[b * TKv + tid + 256] = a1;
        out_cov[b * TKv + tid + 256] = cov[b * TKv + tid + 256] + a1;
    }
}

// ---------------------------------------------------------------------------
// K3b: c_d t-split partials. grid (B, 8): block (b,ks) stages its 50-elem
// a-chunk in LDS, each thread does 50 serial MACs over enc.
// 1024 blocks = 4 waves/SIMD.
// ---------------------------------------------------------------------------
__global__ __launch_bounds__(256) void k_cd(const float* __restrict__ enc)
{
    const int b = blockIdx.x, ks = blockIdx.y, tid = threadIdx.x;
    __shared__ float as_[50];
    if (tid < 50) as_[tid] = g_a[b * TKv + ks * 50 + tid];
    __syncthreads();

    const float* eb = enc + ((size_t)b * TKv + ks * 50) * 256 + tid;
    float acc = 0.f;
    #pragma unroll 10
    for (int t = 0; t < 50; t++) acc += as_[t] * eb[(size_t)t * 256];
    g_cdp[ks * 32768 + b * 256 + tid] = acc;
}

// ---------------------------------------------------------------------------
// K3c: flow_next. grid (B): 50 nodes x 4 threads (t-quarters of 100),
// shuffle-max across the 4, block-sum over 50, normalized write.
// ---------------------------------------------------------------------------
__global__ __launch_bounds__(256) void k_flow(
    const float* __restrict__ n2t, float* __restrict__ out_flow)
{
    const int b = blockIdx.x, tid = threadIdx.x;
    __shared__ float as_[TKv];
    __shared__ float fl[NKv];
    __shared__ float red[256];

    for (int t = tid; t < TKv; t += 256) as_[t] = g_a[b * TKv + t];
    __syncthreads();

    const int nn = tid >> 2, sub = tid & 3;
    float mx = 0.f;
    if (nn < NKv) {
        const float* nb = n2t + ((size_t)b * NKv + nn) * TKv + sub * 100;
        const float* ab = as_ + sub * 100;
        #pragma unroll 4
        for (int t = 0; t < 100; t++) mx = fmaxf(mx, ab[t] * nb[t]);
    }
    mx = fmaxf(mx, __shfl_xor(mx, 1, 64));
    mx = fmaxf(mx, __shfl_xor(mx, 2, 64));
    if (sub == 0 && nn < NKv) fl[nn] = mx;
    __syncthreads();

    float fv = (tid < NKv) ? fl[tid] : 0.f;
    red[tid] = fv; __syncthreads();
    for (int s = 128; s > 0; s >>= 1) { if (tid < s) red[tid] += red[tid + s]; __syncthreads(); }
    float fs = red[0];
    if (tid < NKv) out_flow[b * NKv + tid] = fl[tid] / fs;
}

// ---------------------------------------------------------------------------
// K5: node softmax chain (an, c_g, an2, c_g2, a_n2t), cd-partial sum, p_gen.
// All 50-length loops fully unrolled so loads pipeline; cg+cg2 share one
// enb pass. out1 moved to k_o1.
// ---------------------------------------------------------------------------
__global__ __launch_bounds__(256) void k_node1(
    const float* __restrict__ encn,
    const float* __restrict__ maskn,
    const float* __restrict__ flow,
    const float* __restrict__ graph,
    const float* __restrict__ n2t,
    const float* __restrict__ Wpg, const float* __restrict__ bpg,
    float* __restrict__ out_cd, float* __restrict__ out_cg,
    float* __restrict__ out_cg2, float* __restrict__ out_ant,
    float* __restrict__ out_pgen)
{
    const int b = blockIdx.x, tid = threadIdx.x;
    __shared__ float ans[NKv], an2s[NKv], red[256];

    // c_d = sum of 8 t-split partials
    float cd = 0.f;
    #pragma unroll
    for (int i = 0; i < 8; i++) cd += g_cdp[i * 32768 + b * 256 + tid];
    g_cd[b * 256 + tid] = cd;
    out_cd[b * 256 + tid] = cd;

    // node softmax -> flow-weighted renorm
    float v = (tid < NKv) ? g_en[b * NKv + tid] : -1e30f;
    red[tid] = v; __syncthreads();
    for (int s = 128; s > 0; s >>= 1) { if (tid < s) red[tid] = fmaxf(red[tid], red[tid + s]); __syncthreads(); }
    float m = red[0]; __syncthreads();

    float p = (tid < NKv) ? expf(v - m) * maskn[b * NKv + tid] : 0.f;
    red[tid] = p; __syncthreads();
    for (int s = 128; s > 0; s >>= 1) { if (tid < s) red[tid] += red[tid + s]; __syncthreads(); }
    float S = red[0]; __syncthreads();
    p = (tid < NKv) ? (p / S) * flow[b * NKv + tid] : 0.f;
    red[tid] = p; __syncthreads();
    for (int s = 128; s > 0; s >>= 1) { if (tid < s) red[tid] += red[tid + s]; __syncthreads(); }
    float S2 = red[0]; __syncthreads();
    if (tid < NKv) ans[tid] = p / S2;
    __syncthreads();

    // an2 = (ans @ graph) * mask, renormalized
    float q = 0.f;
    if (tid < NKv) {
        const float* gb = graph + (size_t)b * NKv * NKv + tid;
        #pragma unroll
        for (int n = 0; n < NKv; n++) q += ans[n] * gb[n * NKv];
        q *= maskn[b * NKv + tid];
    }
    red[tid] = q; __syncthreads();
    for (int s = 128; s > 0; s >>= 1) { if (tid < s) red[tid] += red[tid + s]; __syncthreads(); }
    float S3 = red[0]; __syncthreads();
    if (tid < NKv) an2s[tid] = q / S3;
    __syncthreads();

    // c_g and c_g2 in one pass over encn
    float cg = 0.f, cg2 = 0.f;
    {
        const float* enb = encn + (size_t)b * NKv * 256 + tid;
        #pragma unroll
        for (int n = 0; n < NKv; n++) {
            float e = enb[n * 256];
            cg  += ans[n]  * e;
            cg2 += an2s[n] * e;
        }
    }
    g_cg[b * 256 + tid] = cg;   out_cg[b * 256 + tid] = cg;
    g_cg2[b * 256 + tid] = cg2; out_cg2[b * 256 + tid] = cg2;

    // a_n2t with normalization
    float at0 = 0.f, at1 = 0.f;
    {
        const float* nb = n2t + (size_t)b * NKv * TKv;
        #pragma unroll
        for (int n = 0; n < NKv; n++) {
            float an = ans[n];
            at0 += an * nb[n * TKv + tid];
            if (tid + 256 < TKv) at1 += an * nb[n * TKv + tid + 256];
        }
    }
    float loc = at0 + ((tid + 256 < TKv) ? at1 : 0.f);
    red[tid] = loc; __syncthreads();
    for (int s = 128; s > 0; s >>= 1) { if (tid < s) red[tid] += red[tid + s]; __syncthreads(); }
    float S4 = red[0]; __syncthreads();
    out_ant[b * TKv + tid] = at0 / S4;
    if (tid + 256 < TKv) out_ant[b * TKv + tid + 256] = at1 / S4;

    // p_gen
    float hvv = g_h[b * 256 + tid], cvv = g_c[b * 256 + tid];
    float xvv = g_x[b * 256 + tid];
    float part = cd  * Wpg[tid]        + cg  * Wpg[256 + tid]
               + cg2 * Wpg[512 + tid]  + hvv * Wpg[768 + tid]
               + cvv * Wpg[1024 + tid] + xvv * Wpg[1280 + tid];
    red[tid] = part; __syncthreads();
    for (int s = 128; s > 0; s >>= 1) { if (tid < s) red[tid] += red[tid + s]; __syncthreads(); }
    if (tid == 0) {
        float pg = sigm(red[0] + bpg[0]);
        g_pg[b] = pg; out_pgen[b] = pg;
    }
}

// ---------------------------------------------------------------------------
// K6: out1 = [h|cd|cg|cg2] @ W1 + b1. grid (B, 4 col-chunks of 64).
// Thread (kq, lane): kq = tid>>6 K-quarter, lane picks output col; 256
// serial MACs each (unroll 8), LDS cross-kq reduce.
// ---------------------------------------------------------------------------
__global__ __launch_bounds__(256) void k_o1(
    const float* __restrict__ W1, const float* __restrict__ b1)
{
    const int b = blockIdx.x, cc = blockIdx.y, tid = threadIdx.x;
    __shared__ float cat[1024];
    __shared__ float red[256];

    cat[tid]       = g_h  [b * 256 + tid];
    cat[256 + tid] = g_cd [b * 256 + tid];
    cat[512 + tid] = g_cg [b * 256 + tid];
    cat[768 + tid] = g_cg2[b * 256 + tid];
    __syncthreads();

    const int lane = tid & 63, kq = tid >> 6;
    const int col = cc * 64 + lane;
    const float* w  = W1 + (size_t)(kq * 256) * 256 + col;
    const float* cs = cat + kq * 256;
    float acc = 0.f;
    #pragma unroll 8
    for (int k = 0; k < 256; k++) acc += cs[k] * w[(size_t)k * 256];
    red[tid] = acc; __syncthreads();

    if (tid < 64) {
        float o = b1[cc * 64 + tid]
                + red[tid] + red[64 + tid] + red[128 + tid] + red[192 + tid];
        g_o1[b * 256 + cc * 64 + tid] = o;
    }
}

// ---------------------------------------------------------------------------
// K7 (MFMA): logits = out1[128,256] @ W2[256,50000] + b2 -> g_logits (f32).
// 64-col blocks (grid VPAD/64 = 784); wave w owns rows [w*32, w*32+32) as
// 2 M-tiles x 4 N-tiles. Per k-step: 2 A + 4 B loads, acc = 32 VGPRs.
// ---------------------------------------------------------------------------
__global__ __launch_bounds__(256) void k_logits(const float* __restrict__ b2)
{
    const int v0 = blockIdx.x * 64;
    const int tid = threadIdx.x;
    const int lane = tid & 63, wave = tid >> 6;
    const int nlow = lane & 15, quad = lane >> 4;

    const float* a0p = g_o1 + (wave * 32 + nlow) * 256 + quad * 8;
    const float* a1p = a0p + 16 * 256;
    const u16* bbase = g_W2t + (size_t)(v0 + nlow) * 256 + quad * 8;

    const f32x4 zf = {0.f, 0.f, 0.f, 0.f};
    f32x4 acc0[4], acc1[4];
    #pragma unroll
    for (int i = 0; i < 4; i++) { acc0[i] = zf; acc1[i] = zf; }

    for (int k0 = 0; k0 < 256; k0 += 32) {
        bf16x8 a0 = cvt8(a0p + k0);
        bf16x8 a1 = cvt8(a1p + k0);
        #pragma unroll
        for (int nt = 0; nt < 4; nt++) {
            bf16x8 bf = *(const bf16x8*)(bbase + (size_t)nt * 4096 + k0);
            acc0[nt] = __builtin_amdgcn_mfma_f32_16x16x32_bf16(a0, bf, acc0[nt], 0, 0, 0);
            acc1[nt] = __builtin_amdgcn_mfma_f32_16x16x32_bf16(a1, bf, acc1[nt], 0, 0, 0);
        }
    }

    #pragma unroll
    for (int nt = 0; nt < 4; nt++) {
        int v = v0 + nt * 16 + nlow;
        if (v < Vv) {
            float bb = b2[v];
            #pragma unroll
            for (int r = 0; r < 4; r++) {
                int row0 = wave * 32 + quad * 4 + r;
                g_logits[(size_t)row0 * Vv + v]        = acc0[nt][r] + bb;
                g_logits[(size_t)(row0 + 16) * Vv + v] = acc1[nt][r] + bb;
            }
        }
    }
}

// ---------------------------------------------------------------------------
// K8a: per-chunk online (max, sum) partials. grid (B, NS), float4 loads.
// Chunk ks covers [ks*3136, min(+3136, 50000)) — always float4-exact.
// ---------------------------------------------------------------------------
__global__ __launch_bounds__(256) void k_vpart()
{
    const int b = blockIdx.x, ks = blockIdx.y, tid = threadIdx.x;
    __shared__ float rm[256], rs[256];

    const int base = ks * CHUNKv;
    const int end  = min(base + CHUNKv, Vv);
    const int n4   = (end - base) >> 2;
    const float4* L4 = (const float4*)(g_logits + (size_t)b * Vv + base);

    float m = -1e30f, s = 0.f;
    for (int i = tid; i < n4; i += 256) {
        float4 x = L4[i];
        float mx = fmaxf(fmaxf(x.x, x.y), fmaxf(x.z, x.w));
        if (mx > m) { s *= expf(m - mx); m = mx; }
        s += expf(x.x - m) + expf(x.y - m) + expf(x.z - m) + expf(x.w - m);
    }
    rm[tid] = m; rs[tid] = s; __syncthreads();
    for (int off = 128; off > 0; off >>= 1) {
        if (tid < off) {
            float m1 = rm[tid], s1 = rs[tid];
            ms_merge(m1, s1, rm[tid + off], rs[tid + off]);
            rm[tid] = m1; rs[tid] = s1;
        }
        __syncthreads();
    }
    if (tid == 0) {
        g_vred[(b * NSv + ks) * 2]     = rm[0];
        g_vred[(b * NSv + ks) * 2 + 1] = rs[0];
    }
}

// ---------------------------------------------------------------------------
// K8b: merge the NS pairs (broadcast, L2-hot), write exp(x-M)*pg/S for the
// chunk with float4 stores. grid (B, NS).
// ---------------------------------------------------------------------------
__global__ __launch_bounds__(256) void k_vwrite(float* __restrict__ outF)
{
    const int b = blockIdx.x, ks = blockIdx.y, tid = threadIdx.x;

    float M = -1e30f, S = 0.f;
    #pragma unroll
    for (int i = 0; i < NSv; i++) {
        float mi = g_vred[(b * NSv + i) * 2];
        float si = g_vred[(b * NSv + i) * 2 + 1];
        ms_merge(M, S, mi, si);
    }
    const float inv = g_pg[b] / S;

    const int base = ks * CHUNKv;
    const int end  = min(base + CHUNKv, Vv);
    const int n4   = (end - base) >> 2;
    const float4* L4 = (const float4*)(g_logits + (size_t)b * Vv + base);
    float4* O4 = (float4*)(outF + (size_t)b * Vv + base);

    for (int i = tid; i < n4; i += 256) {
        float4 x = L4[i];
        float4 r;
        r.x = expf(x.x - M) * inv;
        r.y = expf(x.y - M) * inv;
        r.z = expf(x.z - M) * inv;
        r.w = expf(x.w - M) * inv;
        O4[i] = r;
    }
}

// ---------------------------------------------------------------------------
// K8c: row-local pointer scatter (1-pg)*a[b,t] at voc_d[b,t]. Runs after
// k_vwrite (stream order guarantees the base probs are in place).
// ---------------------------------------------------------------------------
__global__ __launch_bounds__(256) void k_scatter(
    float* __restrict__ outF, const int* __restrict__ vocd)
{
    const int b = blockIdx.x, tid = threadIdx.x;
    float* Ob = outF + (size_t)b * Vv;
    const float omp = 1.f - g_pg[b];
    for (int t = tid; t < TKv; t += 256)
        atomicAdd(Ob + vocd[b * TKv + t], omp * g_a[b * TKv + t]);
}

// ---------------------------------------------------------------------------

extern "C" void kernel_launch(void* const* d_in, const int* in_sizes, int n_in,
                              void* d_out, int out_size, void* d_ws, size_t ws_size,
                              hipStream_t stream)
{
    (void)in_sizes; (void)n_in; (void)out_size; (void)d_ws; (void)ws_size;

    const int*   y      = (const int*)d_in[0];
    const float* h_prev = (const float*)d_in[1];
    const float* c_prev = (const float*)d_in[2];
    const float* enc    = (const float*)d_in[3];
    const float* encn   = (const float*)d_in[4];
    const float* mask   = (const float*)d_in[5];
    const float* maskn  = (const float*)d_in[6];
    const float* ctd    = (const float*)d_in[7];
    const float* ctg    = (const float*)d_in[8];
    const float* ctg2   = (const float*)d_in[9];
    const float* cov    = (const float*)d_in[10];
    const float* flow   = (const float*)d_in[11];
    const float* n2t    = (const float*)d_in[12];
    const float* graph  = (const float*)d_in[13];
    const int*   vocd   = (const int*)d_in[14];
    // d_in[15] = step (unused)
    const float* emb    = (const float*)d_in[16];
    const float* Wx     = (const float*)d_in[17];
    const float* bx     = (const float*)d_in[18];
    const float* Wi     = (const float*)d_in[19];
    const float* Wh     = (const float*)d_in[20];
    const float* bi     = (const float*)d_in[21];
    const float* bh     = (const float*)d_in[22];
    const float* Whd    = (const float*)d_in[23];
    const float* Wsd    = (const float*)d_in[24];
    const float* wcdw   = (const float*)d_in[25];
    const float* vd     = (const float*)d_in[26];
    const float* bd     = (const float*)d_in[27];
    const float* Wn     = (const float*)d_in[28];
    const float* Wsf    = (const float*)d_in[29];
    const float* vf     = (const float*)d_in[30];
    const float* bfv    = (const float*)d_in[31];
    const float* Wpg    = (const float*)d_in[32];
    const float* bpg    = (const float*)d_in[33];
    const float* W1     = (const float*)d_in[34];
    const float* b1     = (const float*)d_in[35];
    const float* W2     = (const float*)d_in[36];
    const float* b2     = (const float*)d_in[37];

    float* o = (float*)d_out;                 // FLOAT32 output
    float* o_final = o;                       // 6,400,000
    float* o_h     = o + 6400000;
    float* o_c     = o + 6432768;
    float* o_cd    = o + 6465536;
    float* o_cg    = o + 6498304;
    float* o_cg2   = o + 6531072;
    float* o_a     = o + 6563840;
    float* o_ant   = o + 6615040;
    float* o_pg    = o + 6666240;
    float* o_cov   = o + 6666368;
    float* o_fl    = o + 6717568;

    float* g_e_p;   hipGetSymbolAddress((void**)&g_e_p,   HIP_SYMBOL(g_e));
    float* g_en_p;  hipGetSymbolAddress((void**)&g_en_p,  HIP_SYMBOL(g_en));
    float* g_sdp_p; hipGetSymbolAddress((void**)&g_sdp_p, HIP_SYMBOL(g_sdp));
    float* g_sfp_p; hipGetSymbolAddress((void**)&g_sfp_p, HIP_SYMBOL(g_sfp));
    u16*   g_Wdt_p; hipGetSymbolAddress((void**)&g_Wdt_p, HIP_SYMBOL(g_Wdt));
    u16*   g_Wnt_p; hipGetSymbolAddress((void**)&g_Wnt_p, HIP_SYMBOL(g_Wnt));
    u16*   g_W2t_p; hipGetSymbolAddress((void**)&g_W2t_p, HIP_SYMBOL(g_W2t));
    u16*   g_encb_p;  hipGetSymbolAddress((void**)&g_encb_p,  HIP_SYMBOL(g_encb));
    u16*   g_encnb_p; hipGetSymbolAddress((void**)&g_encnb_p, HIP_SYMBOL(g_encnb));

    // transpose-cast weights to bf16 [n][k]
    k_tc<<<dim3(8, 8), dim3(256), 0, stream>>>(Whd, g_Wdt_p, 256, 256);
    k_tc<<<dim3(8, 8), dim3(256), 0, stream>>>(Wn,  g_Wnt_p, 256, 256);
    k_tc<<<dim3(VPAD / 32, 8), dim3(256), 0, stream>>>(W2, g_W2t_p, 256, Vv);

    // pre-convert enc/encn to bf16 (A operands for k_scores)
    k_cvt<<<dim3(2048), dim3(256), 0, stream>>>(enc,  g_encb_p,  Bv * TKv * 256 / 8);
    k_cvt<<<dim3(800),  dim3(256), 0, stream>>>(encn, g_encnb_p, Bv * NKv * 256 / 8);

    // LSTM front-end, latency-optimized: 512/512/256 blocks
    k_x<<<dim3(Bv, 4), dim3(256), 0, stream>>>(y, ctd, ctg, ctg2, emb, Wx);

    k_gates<<<dim3(Bv, 4), dim3(256), 0, stream>>>(h_prev, Wi, Wh, bi, bh, bx);

    k_cellsd<<<dim3(Bv, 2), dim3(256), 0, stream>>>(c_prev, Wsd, Wsf, o_h, o_c);

    k_scores<<<dim3(13, Bv), dim3(256), 0, stream>>>(
        g_encb_p, TKv, g_Wdt_p, g_sdp_p, g_sdp_p + 32768, bd, cov, wcdw, vd, g_e_p);

    k_scores<<<dim3(2, Bv), dim3(256), 0, stream>>>(
        g_encnb_p, NKv, g_Wnt_p, g_sfp_p, g_sfp_p + 32768, bfv,
        nullptr, nullptr, vf, g_en_p);

    // doc attention back-end, latency-optimized
    k_doc<<<dim3(Bv), dim3(256), 0, stream>>>(mask, cov, o_a, o_cov);

    k_cd<<<dim3(Bv, 8), dim3(256), 0, stream>>>(enc);

    k_flow<<<dim3(Bv), dim3(256), 0, stream>>>(n2t, o_fl);

    k_node1<<<dim3(Bv), dim3(256), 0, stream>>>(
        encn, maskn, flow, graph, n2t, Wpg, bpg,
        o_cd, o_cg, o_cg2, o_ant, o_pg);

    k_o1<<<dim3(Bv, 4), dim3(256), 0, stream>>>(W1, b1);

    k_logits<<<dim3(VPAD / 64), dim3(256), 0, stream>>>(b2);

    // vocab softmax, latency-optimized: B x 16 chunk blocks
    k_vpart<<<dim3(Bv, NSv), dim3(256), 0, stream>>>();

    k_vwrite<<<dim3(Bv, NSv), dim3(256), 0, stream>>>(o_final);

    k_scatter<<<dim3(Bv), dim3(256), 0, stream>>>(o_final, vocd);
}

// Round 6
// 481.642 us; speedup vs baseline: 2.0385x; 1.0512x over previous
//
#include <hip/hip_runtime.h>
#include <stdint.h>

// ---------------------------------------------------------------------------
// LSTM pointer-generator decoder step, B=128 TK=400 NK=50 H=E=256 V=50000.
// Round 12: k_scores was STILL register-recycling (VGPR=52 < ~70 needed;
// 64 MFMA/wave in a 45K-cycle kernel). Canonical fix: B-operand (Wt 64-col
// chunk, 32 KB) staged in LDS once per block (padded [64][264] -> 2-way
// conflicts only = free), A-frags double-buffered from global. M flattened
// to B*R (contiguous rows): doc 51200=400x128, node 6400=50x128, no tail.
// Each block writes an e-PARTIAL per 64-col chunk; k_doc/k_node1 sum 4.
// k_o1 also emits bf16 out1 so k_logits drops its in-loop cvt8.
// Everything else unchanged from R11.
// ---------------------------------------------------------------------------

typedef unsigned short u16;
typedef unsigned int   u32;

#define Bv  128
#define TKv 400
#define NKv 50
#define Hv  256
#define Vv  50000
#define VPAD 50176   // 50000 padded to multiple of 128
#define NSv 16
#define CHUNKv 3136  // VPAD / NSv
#define MDOC (Bv * TKv)   // 51200
#define MNODE (Bv * NKv)  // 6400

typedef __attribute__((ext_vector_type(8))) short bf16x8;
typedef __attribute__((ext_vector_type(4))) float f32x4;

// ---- module-global workspace (no d_ws dependency) -------------------------
__device__ float g_x[32768];      // x = cat @ Wx + bx
__device__ float g_xp[4 * 32768]; // x K-partials
__device__ float g_gates[131072]; // LSTM gates [B,4H]
__device__ float g_h[32768];      // h_new
__device__ float g_c[32768];      // c_new
__device__ float g_sdp[2 * 32768];// s_hat@Wsd partials (no bias)
__device__ float g_sfp[2 * 32768];// s_hat@Wsf partials (no bias)
__device__ float g_ep[4 * MDOC];  // doc score partials (4 col-chunks)
__device__ float g_enp[4 * MNODE];// node score partials
__device__ float g_a[51200];      // doc attention a
__device__ float g_cd[32768];     // c_d
__device__ float g_cdp[8 * 32768];// c_d t-split partials (8 chunks of 50)
__device__ float g_cg[32768];     // c_g
__device__ float g_cg2[32768];    // c_g2
__device__ float g_pg[128];       // p_gen
__device__ float g_o1[32768];     // out1 (f32)
__device__ __attribute__((aligned(16))) u16 g_o1b[32768]; // out1 bf16
__device__ float g_vred[Bv * NSv * 2];     // per-chunk (max, sum) pairs
__device__ float g_logits[6400000];        // f32 logits (25.6 MB)
__device__ u16   g_Wdt[256 * 256];         // Whd^T bf16 [n][k]
__device__ u16   g_Wnt[256 * 256];         // Wn^T  bf16 [n][k]
__device__ u16   g_W2t[(size_t)VPAD * 256];// W2^T  bf16 [v][k] (25.7 MB)
__device__ u16   g_encb[(size_t)Bv * TKv * 256]; // enc bf16 (26.2 MB)
__device__ u16   g_encnb[(size_t)Bv * NKv * 256];// encn bf16 (3.3 MB)

__device__ __forceinline__ float sigm(float x) { return 1.f / (1.f + expf(-x)); }

__device__ __forceinline__ u16 f2bf(float f) {
    u32 u = __float_as_uint(f);
    return (u16)((u + 0x7fffu + ((u >> 16) & 1u)) >> 16);  // RNE
}

__device__ __forceinline__ bf16x8 cvt8(const float* __restrict__ p) {
    const float4 a = *(const float4*)p;
    const float4 b = *(const float4*)(p + 4);
    bf16x8 r;
    r[0] = (short)f2bf(a.x); r[1] = (short)f2bf(a.y);
    r[2] = (short)f2bf(a.z); r[3] = (short)f2bf(a.w);
    r[4] = (short)f2bf(b.x); r[5] = (short)f2bf(b.y);
    r[6] = (short)f2bf(b.z); r[7] = (short)f2bf(b.w);
    return r;
}

// tanh via exp; clamp so exp never overflows (tanh saturated anyway)
__device__ __forceinline__ float fast_tanh(float x) {
    x = fminf(fmaxf(x, -15.f), 15.f);
    float e = __expf(2.f * x);
    return (e - 1.f) / (e + 1.f);
}

// online (max,sum) merge: (m1,s1) <- (m1,s1) U (m2,s2)
__device__ __forceinline__ void ms_merge(float& m1, float& s1, float m2, float s2) {
    float M = fmaxf(m1, m2);
    s1 = s1 * expf(m1 - M) + s2 * expf(m2 - M);
    m1 = M;
}

// ---------------------------------------------------------------------------
// K-1: streaming f32 -> bf16 (RNE). n8 = element count / 8.
// ---------------------------------------------------------------------------
__global__ __launch_bounds__(256) void k_cvt(
    const float* __restrict__ src, u16* __restrict__ dst, int n8)
{
    int i = blockIdx.x * 256 + threadIdx.x;
    const int stride = gridDim.x * 256;
    for (; i < n8; i += stride)
        *(bf16x8*)(dst + (size_t)i * 8) = cvt8(src + (size_t)i * 8);
}

// ---------------------------------------------------------------------------
// K0: transpose-cast  src[K][N] f32  ->  dst[n][k] bf16.
// grid = (Npad/32, K/32), block 256 (32x8). Reads n>=N give 0 (pad rows).
// ---------------------------------------------------------------------------
__global__ __launch_bounds__(256) void k_tc(
    const float* __restrict__ src, u16* __restrict__ dst, int K, int N)
{
    __shared__ float tile[32][33];
    const int n0 = blockIdx.x * 32, k0 = blockIdx.y * 32;
    const int tx = threadIdx.x & 31, ty = threadIdx.x >> 5;
    #pragma unroll
    for (int i = 0; i < 32; i += 8) {
        int k = k0 + ty + i, n = n0 + tx;
        tile[ty + i][tx] = (n < N) ? src[(size_t)k * N + n] : 0.f;
    }
    __syncthreads();
    #pragma unroll
    for (int i = 0; i < 32; i += 8) {
        int n = n0 + ty + i, k = k0 + tx;
        dst[(size_t)n * K + k] = f2bf(tile[tx][ty + i]);
    }
}

// ---------------------------------------------------------------------------
// K1a: x K-partials. grid (B, 4).
// ---------------------------------------------------------------------------
__global__ __launch_bounds__(256) void k_x(
    const int* __restrict__ y,
    const float* __restrict__ ctd, const float* __restrict__ ctg,
    const float* __restrict__ ctg2, const float* __restrict__ emb,
    const float* __restrict__ Wx)
{
    const int b = blockIdx.x, ks = blockIdx.y, j = threadIdx.x;
    __shared__ float cs[256];
    float v;
    if      (ks == 0) v = ctd [b * 256 + j];
    else if (ks == 1) v = ctg [b * 256 + j];
    else if (ks == 2) v = ctg2[b * 256 + j];
    else              v = emb[(size_t)y[b] * 256 + j];
    cs[j] = v;
    __syncthreads();

    float acc = 0.f;
    const float* w = Wx + (size_t)(ks * 256) * 256 + j;
    #pragma unroll 8
    for (int k = 0; k < 256; k++) acc += cs[k] * w[(size_t)k * 256];
    g_xp[ks * 32768 + b * 256 + j] = acc;
}

// ---------------------------------------------------------------------------
// K1b: gates = x@Wi + h@Wh + bi + bh. grid (B, 4 col-chunks).
// ---------------------------------------------------------------------------
__global__ __launch_bounds__(256) void k_gates(
    const float* __restrict__ h_prev,
    const float* __restrict__ Wi, const float* __restrict__ Wh,
    const float* __restrict__ bi, const float* __restrict__ bh,
    const float* __restrict__ bx)
{
    const int b = blockIdx.x, cc = blockIdx.y, j = threadIdx.x;
    __shared__ float xs[256], hs[256];

    float xv = bx[j] + g_xp[b * 256 + j] + g_xp[32768 + b * 256 + j]
             + g_xp[65536 + b * 256 + j] + g_xp[98304 + b * 256 + j];
    xs[j] = xv;
    if (cc == 0) g_x[b * 256 + j] = xv;
    hs[j] = h_prev[b * 256 + j];
    __syncthreads();

    const int col = cc * 256 + j;
    float acc = bi[col] + bh[col];
    const float* wi = Wi + col;
    const float* wh = Wh + col;
    #pragma unroll 8
    for (int k = 0; k < 256; k++)
        acc += xs[k] * wi[(size_t)k * 1024] + hs[k] * wh[(size_t)k * 1024];
    g_gates[b * 1024 + col] = acc;
}

// ---------------------------------------------------------------------------
// K1c: LSTM elementwise + sd/sf K-partials. grid (B, 2).
// ---------------------------------------------------------------------------
__global__ __launch_bounds__(256) void k_cellsd(
    const float* __restrict__ c_prev,
    const float* __restrict__ Wsd, const float* __restrict__ Wsf,
    float* __restrict__ out_h, float* __restrict__ out_c)
{
    const int b = blockIdx.x, ks = blockIdx.y, j = threadIdx.x;
    __shared__ float sh[256];

    const float* gb = g_gates + b * 1024;
    float gi_ = gb[j], gf_ = gb[256 + j], gg_ = gb[512 + j], go_ = gb[768 + j];
    float cp = c_prev[b * 256 + j];
    float cn = sigm(gf_) * cp + sigm(gi_) * tanhf(gg_);
    float hn = sigm(go_) * tanhf(cn);
    if (ks == 0) {
        g_h[b * 256 + j] = hn;  g_c[b * 256 + j] = cn;
        out_h[b * 256 + j] = hn; out_c[b * 256 + j] = cn;
    }
    sh[j] = (ks == 0) ? hn : cn;   // s_hat rows [0,256) = h, [256,512) = c
    __syncthreads();

    float asd = 0.f, asf = 0.f;
    const float* wd = Wsd + (size_t)(ks * 256) * 256 + j;
    const float* wf = Wsf + (size_t)(ks * 256) * 256 + j;
    #pragma unroll 8
    for (int k = 0; k < 256; k++) {
        float sv = sh[k];
        asd += sv * wd[(size_t)k * 256];
        asf += sv * wf[(size_t)k * 256];
    }
    g_sdp[ks * 32768 + b * 256 + j] = asd;
    g_sfp[ks * 32768 + b * 256 + j] = asf;
}

// ---------------------------------------------------------------------------
// K2/K4 (MFMA, R12): e-PARTIAL[b,t] for one 64-col chunk.
// M flattened (row = b*R + t). Block = 128 rows x 64 cols; B-chunk in LDS
// (padded [64][264] -> 2-way bank conflicts only). Wave w = rows
// [w*32,w*32+32): 2 M-tiles x 4 N-tiles, A double-buffered from global.
// Writes eout[chunk*Mtot + row]; consumer sums the 4 chunk partials.
// ---------------------------------------------------------------------------
template<int R>
__global__ __launch_bounds__(256) void k_scores(
    const u16* __restrict__ srcb,     // bf16 A, Mtot x 256
    const u16* __restrict__ Wt,       // bf16 W^T [256][256]
    const float* __restrict__ addv0,  // s_hat@W partial (K lower half) [B][256]
    const float* __restrict__ addv1,  // s_hat@W partial (K upper half)
    const float* __restrict__ abias,  // bias vector (bd / bf) [256]
    const float* __restrict__ cov,    // flat [Mtot] or nullptr
    const float* __restrict__ wcw,    // [256] or nullptr
    const float* __restrict__ vv,     // [256]
    float* __restrict__ eout, int Mtot)
{
    const int tid = threadIdx.x;
    const int lane = tid & 63, w = tid >> 6;
    const int nlow = lane & 15, quad = lane >> 4;
    const int c0 = blockIdx.y * 64;

    __shared__ u16 Bs[64][264];
    {
        const u16* wsrc = Wt + (size_t)c0 * 256;
        #pragma unroll
        for (int j = 0; j < 8; j++) {
            int chunk = tid + j * 256;
            int row = chunk >> 5, c16 = chunk & 31;
            *(bf16x8*)(&Bs[row][c16 * 8]) =
                *(const bf16x8*)(wsrc + row * 256 + c16 * 8);
        }
    }
    __syncthreads();

    const int rowbase = blockIdx.x * 128 + w * 32;
    const u16* a0 = srcb + (size_t)(rowbase + nlow) * 256 + quad * 8;
    const u16* a1 = a0 + 16 * 256;

    const f32x4 zf = {0.f, 0.f, 0.f, 0.f};
    f32x4 acc[2][4];
    #pragma unroll
    for (int mi = 0; mi < 2; mi++)
        #pragma unroll
        for (int ni = 0; ni < 4; ni++) acc[mi][ni] = zf;

    bf16x8 af0 = *(const bf16x8*)(a0);
    bf16x8 af1 = *(const bf16x8*)(a1);
    for (int k0 = 0; k0 < 256; k0 += 32) {
        const int kn = (k0 + 32) & 255;   // wrap: last iter re-reads k=0 (discarded)
        bf16x8 nf0 = *(const bf16x8*)(a0 + kn);
        bf16x8 nf1 = *(const bf16x8*)(a1 + kn);
        bf16x8 bf[4];
        #pragma unroll
        for (int ni = 0; ni < 4; ni++)
            bf[ni] = *(const bf16x8*)(&Bs[ni * 16 + nlow][k0 + quad * 8]);
        #pragma unroll
        for (int ni = 0; ni < 4; ni++) {
            acc[0][ni] = __builtin_amdgcn_mfma_f32_16x16x32_bf16(af0, bf[ni], acc[0][ni], 0, 0, 0);
            acc[1][ni] = __builtin_amdgcn_mfma_f32_16x16x32_bf16(af1, bf[ni], acc[1][ni], 0, 0, 0);
        }
        af0 = nf0; af1 = nf1;
    }

    // epilogue: row = rowbase + mi*16 + quad*4 + r, col = c0 + ni*16 + nlow
    #pragma unroll
    for (int mi = 0; mi < 2; mi++) {
        float covt[4]; int bidx[4];
        #pragma unroll
        for (int r = 0; r < 4; r++) {
            int row = rowbase + mi * 16 + quad * 4 + r;
            covt[r] = cov ? cov[row] : 0.f;
            bidx[r] = row / R;             // compile-time R -> magic-mul
        }
        float s4[4] = {0.f, 0.f, 0.f, 0.f};
        #pragma unroll
        for (int ni = 0; ni < 4; ni++) {
            int col = c0 + ni * 16 + nlow;
            float vvc = vv[col];
            float ab  = abias[col];
            float wcc = wcw ? wcw[col] : 0.f;
            #pragma unroll
            for (int r = 0; r < 4; r++) {
                float adc = addv0[bidx[r] * 256 + col] + addv1[bidx[r] * 256 + col] + ab;
                s4[r] += vvc * fast_tanh(acc[mi][ni][r] + adc + covt[r] * wcc);
            }
        }
        #pragma unroll
        for (int r = 0; r < 4; r++) {
            float s = s4[r];
            s += __shfl_xor(s, 1, 64);
            s += __shfl_xor(s, 2, 64);
            s += __shfl_xor(s, 4, 64);
            s += __shfl_xor(s, 8, 64);
            int row = rowbase + mi * 16 + quad * 4 + r;
            if (nlow == 0)
                eout[(size_t)blockIdx.y * Mtot + row] = s;
        }
    }
}

// ---------------------------------------------------------------------------
// K3: doc softmax (+mask renorm): sums the 4 e-partials, a, coverage_next.
// ---------------------------------------------------------------------------
__global__ __launch_bounds__(256) void k_doc(
    const float* __restrict__ mask,
    const float* __restrict__ cov,
    float* __restrict__ out_a, float* __restrict__ out_cov)
{
    const int b = blockIdx.x, tid = threadIdx.x;
    __shared__ float red[256];

    float e0 = 0.f, e1s = 0.f;
    #pragma unroll
    for (int ch = 0; ch < 4; ch++) {
        e0 += g_ep[ch * MDOC + b * TKv + tid];
        if (tid + 256 < TKv) e1s += g_ep[ch * MDOC + b * TKv + tid + 256];
    }
    float e1 = (tid + 256 < TKv) ? e1s : -1e30f;

    float m = fmaxf(e0, e1);
    red[tid] = m; __syncthreads();
    for (int s = 128; s > 0; s >>= 1) { if (tid < s) red[tid] = fmaxf(red[tid], red[tid + s]); __syncthreads(); }
    m = red[0]; __syncthreads();

    float p0 = expf(e0 - m) * mask[b * TKv + tid];
    float p1 = (tid + 256 < TKv) ? expf(e1 - m) * mask[b * TKv + tid + 256] : 0.f;
    red[tid] = p0 + p1; __syncthreads();
    for (int s = 128; s > 0; s >>= 1) { if (tid < s) red[tid] += red[tid + s]; __syncthreads(); }
    float inv = 1.f / red[0];

    float a0 = p0 * inv;
    g_a[b * TKv + tid] = a0;
    out_a[b * TKv + tid] = a0;
    out_cov[b * TKv + tid] = cov[b * TKv + tid] + a0;
    if (tid + 256 < TKv) {
        float a1 = p1 * inv;
        g_a[b * TKv + tid + 256] = a1;
        out_a[b * TKv + tid + 256] = a1;
        out_cov[b * TKv + tid + 256] = cov[b * TKv + tid + 256] + a1;
    }
}

// ---------------------------------------------------------------------------
// K3b: c_d t-split partials. grid (B, 8).
// ---------------------------------------------------------------------------
__global__ __launch_bounds__(256) void k_cd(const float* __restrict__ enc)
{
    const int b = blockIdx.x, ks = blockIdx.y, tid = threadIdx.x;
    __shared__ float as_[50];
    if (tid < 50) as_[tid] = g_a[b * TKv + ks * 50 + tid];
    __syncthreads();

    const float* eb = enc + ((size_t)b * TKv + ks * 50) * 256 + tid;
    float acc = 0.f;
    #pragma unroll 10
    for (int t = 0; t < 50; t++) acc += as_[t] * eb[(size_t)t * 256];
    g_cdp[ks * 32768 + b * 256 + tid] = acc;
}

// ---------------------------------------------------------------------------
// K3c: flow_next. grid (B).
// ---------------------------------------------------------------------------
__global__ __launch_bounds__(256) void k_flow(
    const float* __restrict__ n2t, float* __restrict__ out_flow)
{
    const int b = blockIdx.x, tid = threadIdx.x;
    __shared__ float as_[TKv];
    __shared__ float fl[NKv];
    __shared__ float red[256];

    for (int t = tid; t < TKv; t += 256) as_[t] = g_a[b * TKv + t];
    __syncthreads();

    const int nn = tid >> 2, sub = tid & 3;
    float mx = 0.f;
    if (nn < NKv) {
        const float* nb = n2t + ((size_t)b * NKv + nn) * TKv + sub * 100;
        const float* ab = as_ + sub * 100;
        #pragma unroll 4
        for (int t = 0; t < 100; t++) mx = fmaxf(mx, ab[t] * nb[t]);
    }
    mx = fmaxf(mx, __shfl_xor(mx, 1, 64));
    mx = fmaxf(mx, __shfl_xor(mx, 2, 64));
    if (sub == 0 && nn < NKv) fl[nn] = mx;
    __syncthreads();

    float fv = (tid < NKv) ? fl[tid] : 0.f;
    red[tid] = fv; __syncthreads();
    for (int s = 128; s > 0; s >>= 1) { if (tid < s) red[tid] += red[tid + s]; __syncthreads(); }
    float fs = red[0];
    if (tid < NKv) out_flow[b * NKv + tid] = fl[tid] / fs;
}

// ---------------------------------------------------------------------------
// K5: node softmax chain (sums 4 en-partials), cd-partial sum, p_gen.
// ---------------------------------------------------------------------------
__global__ __launch_bounds__(256) void k_node1(
    const float* __restrict__ encn,
    const float* __restrict__ maskn,
    const float* __restrict__ flow,
    const float* __restrict__ graph,
    const float* __restrict__ n2t,
    const float* __restrict__ Wpg, const float* __restrict__ bpg,
    float* __restrict__ out_cd, float* __restrict__ out_cg,
    float* __restrict__ out_cg2, float* __restrict__ out_ant,
    float* __restrict__ out_pgen)
{
    const int b = blockIdx.x, tid = threadIdx.x;
    __shared__ float ans[NKv], an2s[NKv], red[256];

    // c_d = sum of 8 t-split partials
    float cd = 0.f;
    #pragma unroll
    for (int i = 0; i < 8; i++) cd += g_cdp[i * 32768 + b * 256 + tid];
    g_cd[b * 256 + tid] = cd;
    out_cd[b * 256 + tid] = cd;

    // node softmax -> flow-weighted renorm
    float v = -1e30f;
    if (tid < NKv) {
        v = 0.f;
        #pragma unroll
        for (int ch = 0; ch < 4; ch++) v += g_enp[ch * MNODE + b * NKv + tid];
    }
    red[tid] = v; __syncthreads();
    for (int s = 128; s > 0; s >>= 1) { if (tid < s) red[tid] = fmaxf(red[tid], red[tid + s]); __syncthreads(); }
    float m = red[0]; __syncthreads();

    float p = (tid < NKv) ? expf(v - m) * maskn[b * NKv + tid] : 0.f;
    red[tid] = p; __syncthreads();
    for (int s = 128; s > 0; s >>= 1) { if (tid < s) red[tid] += red[tid + s]; __syncthreads(); }
    float S = red[0]; __syncthreads();
    p = (tid < NKv) ? (p / S) * flow[b * NKv + tid] : 0.f;
    red[tid] = p; __syncthreads();
    for (int s = 128; s > 0; s >>= 1) { if (tid < s) red[tid] += red[tid + s]; __syncthreads(); }
    float S2 = red[0]; __syncthreads();
    if (tid < NKv) ans[tid] = p / S2;
    __syncthreads();

    // an2 = (ans @ graph) * mask, renormalized
    float q = 0.f;
    if (tid < NKv) {
        const float* gb = graph + (size_t)b * NKv * NKv + tid;
        #pragma unroll
        for (int n = 0; n < NKv; n++) q += ans[n] * gb[n * NKv];
        q *= maskn[b * NKv + tid];
    }
    red[tid] = q; __syncthreads();
    for (int s = 128; s > 0; s >>= 1) { if (tid < s) red[tid] += red[tid + s]; __syncthreads(); }
    float S3 = red[0]; __syncthreads();
    if (tid < NKv) an2s[tid] = q / S3;
    __syncthreads();

    // c_g and c_g2 in one pass over encn
    float cg = 0.f, cg2 = 0.f;
    {
        const float* enb = encn + (size_t)b * NKv * 256 + tid;
        #pragma unroll
        for (int n = 0; n < NKv; n++) {
            float e = enb[n * 256];
            cg  += ans[n]  * e;
            cg2 += an2s[n] * e;
        }
    }
    g_cg[b * 256 + tid] = cg;   out_cg[b * 256 + tid] = cg;
    g_cg2[b * 256 + tid] = cg2; out_cg2[b * 256 + tid] = cg2;

    // a_n2t with normalization
    float at0 = 0.f, at1 = 0.f;
    {
        const float* nb = n2t + (size_t)b * NKv * TKv;
        #pragma unroll
        for (int n = 0; n < NKv; n++) {
            float an = ans[n];
            at0 += an * nb[n * TKv + tid];
            if (tid + 256 < TKv) at1 += an * nb[n * TKv + tid + 256];
        }
    }
    float loc = at0 + ((tid + 256 < TKv) ? at1 : 0.f);
    red[tid] = loc; __syncthreads();
    for (int s = 128; s > 0; s >>= 1) { if (tid < s) red[tid] += red[tid + s]; __syncthreads(); }
    float S4 = red[0]; __syncthreads();
    out_ant[b * TKv + tid] = at0 / S4;
    if (tid + 256 < TKv) out_ant[b * TKv + tid + 256] = at1 / S4;

    // p_gen
    float hvv = g_h[b * 256 + tid], cvv = g_c[b * 256 + tid];
    float xvv = g_x[b * 256 + tid];
    float part = cd  * Wpg[tid]        + cg  * Wpg[256 + tid]
               + cg2 * Wpg[512 + tid]  + hvv * Wpg[768 + tid]
               + cvv * Wpg[1024 + tid] + xvv * Wpg[1280 + tid];
    red[tid] = part; __syncthreads();
    for (int s = 128; s > 0; s >>= 1) { if (tid < s) red[tid] += red[tid + s]; __syncthreads(); }
    if (tid == 0) {
        float pg = sigm(red[0] + bpg[0]);
        g_pg[b] = pg; out_pgen[b] = pg;
    }
}

// ---------------------------------------------------------------------------
// K6: out1 = [h|cd|cg|cg2] @ W1 + b1. grid (B, 4 col-chunks of 64).
// Also emits bf16 out1 for k_logits.
// ---------------------------------------------------------------------------
__global__ __launch_bounds__(256) void k_o1(
    const float* __restrict__ W1, const float* __restrict__ b1)
{
    const int b = blockIdx.x, cc = blockIdx.y, tid = threadIdx.x;
    __shared__ float cat[1024];
    __shared__ float red[256];

    cat[tid]       = g_h  [b * 256 + tid];
    cat[256 + tid] = g_cd [b * 256 + tid];
    cat[512 + tid] = g_cg [b * 256 + tid];
    cat[768 + tid] = g_cg2[b * 256 + tid];
    __syncthreads();

    const int lane = tid & 63, kq = tid >> 6;
    const int col = cc * 64 + lane;
    const float* w  = W1 + (size_t)(kq * 256) * 256 + col;
    const float* cs = cat + kq * 256;
    float acc = 0.f;
    #pragma unroll 8
    for (int k = 0; k < 256; k++) acc += cs[k] * w[(size_t)k * 256];
    red[tid] = acc; __syncthreads();

    if (tid < 64) {
        float o = b1[cc * 64 + tid]
                + red[tid] + red[64 + tid] + red[128 + tid] + red[192 + tid];
        g_o1[b * 256 + cc * 64 + tid] = o;
        g_o1b[b * 256 + cc * 64 + tid] = f2bf(o);
    }
}

// ---------------------------------------------------------------------------
// K7 (MFMA): logits = out1[128,256] @ W2[256,50000] + b2 -> g_logits (f32).
// A is pre-converted bf16 (g_o1b) — no in-loop cvt. 64-col blocks, wave w =
// rows [w*32,w*32+32) as 2 M-tiles x 4 N-tiles.
// ---------------------------------------------------------------------------
__global__ __launch_bounds__(256) void k_logits(const float* __restrict__ b2)
{
    const int v0 = blockIdx.x * 64;
    const int tid = threadIdx.x;
    const int lane = tid & 63, wave = tid >> 6;
    const int nlow = lane & 15, quad = lane >> 4;

    const u16* a0p = g_o1b + (wave * 32 + nlow) * 256 + quad * 8;
    const u16* a1p = a0p + 16 * 256;
    const u16* bbase = g_W2t + (size_t)(v0 + nlow) * 256 + quad * 8;

    const f32x4 zf = {0.f, 0.f, 0.f, 0.f};
    f32x4 acc0[4], acc1[4];
    #pragma unroll
    for (int i = 0; i < 4; i++) { acc0[i] = zf; acc1[i] = zf; }

    for (int k0 = 0; k0 < 256; k0 += 32) {
        bf16x8 a0 = *(const bf16x8*)(a0p + k0);
        bf16x8 a1 = *(const bf16x8*)(a1p + k0);
        #pragma unroll
        for (int nt = 0; nt < 4; nt++) {
            bf16x8 bf = *(const bf16x8*)(bbase + (size_t)nt * 4096 + k0);
            acc0[nt] = __builtin_amdgcn_mfma_f32_16x16x32_bf16(a0, bf, acc0[nt], 0, 0, 0);
            acc1[nt] = __builtin_amdgcn_mfma_f32_16x16x32_bf16(a1, bf, acc1[nt], 0, 0, 0);
        }
    }

    #pragma unroll
    for (int nt = 0; nt < 4; nt++) {
        int v = v0 + nt * 16 + nlow;
        if (v < Vv) {
            float bb = b2[v];
            #pragma unroll
            for (int r = 0; r < 4; r++) {
                int row0 = wave * 32 + quad * 4 + r;
                g_logits[(size_t)row0 * Vv + v]        = acc0[nt][r] + bb;
                g_logits[(size_t)(row0 + 16) * Vv + v] = acc1[nt][r] + bb;
            }
        }
    }
}

// ---------------------------------------------------------------------------
// K8a: per-chunk online (max, sum) partials. grid (B, NS), float4 loads.
// ---------------------------------------------------------------------------
__global__ __launch_bounds__(256) void k_vpart()
{
    const int b = blockIdx.x, ks = blockIdx.y, tid = threadIdx.x;
    __shared__ float rm[256], rs[256];

    const int base = ks * CHUNKv;
    const int end  = min(base + CHUNKv, Vv);
    const int n4   = (end - base) >> 2;
    const float4* L4 = (const float4*)(g_logits + (size_t)b * Vv + base);

    float m = -1e30f, s = 0.f;
    for (int i = tid; i < n4; i += 256) {
        float4 x = L4[i];
        float mx = fmaxf(fmaxf(x.x, x.y), fmaxf(x.z, x.w));
        if (mx > m) { s *= expf(m - mx); m = mx; }
        s += expf(x.x - m) + expf(x.y - m) + expf(x.z - m) + expf(x.w - m);
    }
    rm[tid] = m; rs[tid] = s; __syncthreads();
    for (int off = 128; off > 0; off >>= 1) {
        if (tid < off) {
            float m1 = rm[tid], s1 = rs[tid];
            ms_merge(m1, s1, rm[tid + off], rs[tid + off]);
            rm[tid] = m1; rs[tid] = s1;
        }
        __syncthreads();
    }
    if (tid == 0) {
        g_vred[(b * NSv + ks) * 2]     = rm[0];
        g_vred[(b * NSv + ks) * 2 + 1] = rs[0];
    }
}

// ---------------------------------------------------------------------------
// K8b: merge the NS pairs, write exp(x-M)*pg/S with float4 stores.
// ---------------------------------------------------------------------------
__global__ __launch_bounds__(256) void k_vwrite(float* __restrict__ outF)
{
    const int b = blockIdx.x, ks = blockIdx.y, tid = threadIdx.x;

    float M = -1e30f, S = 0.f;
    #pragma unroll
    for (int i = 0; i < NSv; i++) {
        float mi = g_vred[(b * NSv + i) * 2];
        float si = g_vred[(b * NSv + i) * 2 + 1];
        ms_merge(M, S, mi, si);
    }
    const float inv = g_pg[b] / S;

    const int base = ks * CHUNKv;
    const int end  = min(base + CHUNKv, Vv);
    const int n4   = (end - base) >> 2;
    const float4* L4 = (const float4*)(g_logits + (size_t)b * Vv + base);
    float4* O4 = (float4*)(outF + (size_t)b * Vv + base);

    for (int i = tid; i < n4; i += 256) {
        float4 x = L4[i];
        float4 r;
        r.x = expf(x.x - M) * inv;
        r.y = expf(x.y - M) * inv;
        r.z = expf(x.z - M) * inv;
        r.w = expf(x.w - M) * inv;
        O4[i] = r;
    }
}

// ---------------------------------------------------------------------------
// K8c: row-local pointer scatter (1-pg)*a[b,t] at voc_d[b,t].
// ---------------------------------------------------------------------------
__global__ __launch_bounds__(256) void k_scatter(
    float* __restrict__ outF, const int* __restrict__ vocd)
{
    const int b = blockIdx.x, tid = threadIdx.x;
    float* Ob = outF + (size_t)b * Vv;
    const float omp = 1.f - g_pg[b];
    for (int t = tid; t < TKv; t += 256)
        atomicAdd(Ob + vocd[b * TKv + t], omp * g_a[b * TKv + t]);
}

// ---------------------------------------------------------------------------

extern "C" void kernel_launch(void* const* d_in, const int* in_sizes, int n_in,
                              void* d_out, int out_size, void* d_ws, size_t ws_size,
                              hipStream_t stream)
{
    (void)in_sizes; (void)n_in; (void)out_size; (void)d_ws; (void)ws_size;

    const int*   y      = (const int*)d_in[0];
    const float* h_prev = (const float*)d_in[1];
    const float* c_prev = (const float*)d_in[2];
    const float* enc    = (const float*)d_in[3];
    const float* encn   = (const float*)d_in[4];
    const float* mask   = (const float*)d_in[5];
    const float* maskn  = (const float*)d_in[6];
    const float* ctd    = (const float*)d_in[7];
    const float* ctg    = (const float*)d_in[8];
    const float* ctg2   = (const float*)d_in[9];
    const float* cov    = (const float*)d_in[10];
    const float* flow   = (const float*)d_in[11];
    const float* n2t    = (const float*)d_in[12];
    const float* graph  = (const float*)d_in[13];
    const int*   vocd   = (const int*)d_in[14];
    // d_in[15] = step (unused)
    const float* emb    = (const float*)d_in[16];
    const float* Wx     = (const float*)d_in[17];
    const float* bx     = (const float*)d_in[18];
    const float* Wi     = (const float*)d_in[19];
    const float* Wh     = (const float*)d_in[20];
    const float* bi     = (const float*)d_in[21];
    const float* bh     = (const float*)d_in[22];
    const float* Whd    = (const float*)d_in[23];
    const float* Wsd    = (const float*)d_in[24];
    const float* wcdw   = (const float*)d_in[25];
    const float* vd     = (const float*)d_in[26];
    const float* bd     = (const float*)d_in[27];
    const float* Wn     = (const float*)d_in[28];
    const float* Wsf    = (const float*)d_in[29];
    const float* vf     = (const float*)d_in[30];
    const float* bfv    = (const float*)d_in[31];
    const float* Wpg    = (const float*)d_in[32];
    const float* bpg    = (const float*)d_in[33];
    const float* W1     = (const float*)d_in[34];
    const float* b1     = (const float*)d_in[35];
    const float* W2     = (const float*)d_in[36];
    const float* b2     = (const float*)d_in[37];

    float* o = (float*)d_out;                 // FLOAT32 output
    float* o_final = o;                       // 6,400,000
    float* o_h     = o + 6400000;
    float* o_c     = o + 6432768;
    float* o_cd    = o + 6465536;
    float* o_cg    = o + 6498304;
    float* o_cg2   = o + 6531072;
    float* o_a     = o + 6563840;
    float* o_ant   = o + 6615040;
    float* o_pg    = o + 6666240;
    float* o_cov   = o + 6666368;
    float* o_fl    = o + 6717568;

    float* g_ep_p;  hipGetSymbolAddress((void**)&g_ep_p,  HIP_SYMBOL(g_ep));
    float* g_enp_p; hipGetSymbolAddress((void**)&g_enp_p, HIP_SYMBOL(g_enp));
    float* g_sdp_p; hipGetSymbolAddress((void**)&g_sdp_p, HIP_SYMBOL(g_sdp));
    float* g_sfp_p; hipGetSymbolAddress((void**)&g_sfp_p, HIP_SYMBOL(g_sfp));
    u16*   g_Wdt_p; hipGetSymbolAddress((void**)&g_Wdt_p, HIP_SYMBOL(g_Wdt));
    u16*   g_Wnt_p; hipGetSymbolAddress((void**)&g_Wnt_p, HIP_SYMBOL(g_Wnt));
    u16*   g_W2t_p; hipGetSymbolAddress((void**)&g_W2t_p, HIP_SYMBOL(g_W2t));
    u16*   g_encb_p;  hipGetSymbolAddress((void**)&g_encb_p,  HIP_SYMBOL(g_encb));
    u16*   g_encnb_p; hipGetSymbolAddress((void**)&g_encnb_p, HIP_SYMBOL(g_encnb));

    // transpose-cast weights to bf16 [n][k]
    k_tc<<<dim3(8, 8), dim3(256), 0, stream>>>(Whd, g_Wdt_p, 256, 256);
    k_tc<<<dim3(8, 8), dim3(256), 0, stream>>>(Wn,  g_Wnt_p, 256, 256);
    k_tc<<<dim3(VPAD / 32, 8), dim3(256), 0, stream>>>(W2, g_W2t_p, 256, Vv);

    // pre-convert enc/encn to bf16 (A operands for k_scores)
    k_cvt<<<dim3(2048), dim3(256), 0, stream>>>(enc,  g_encb_p,  Bv * TKv * 256 / 8);
    k_cvt<<<dim3(800),  dim3(256), 0, stream>>>(encn, g_encnb_p, Bv * NKv * 256 / 8);

    // LSTM front-end, latency-optimized
    k_x<<<dim3(Bv, 4), dim3(256), 0, stream>>>(y, ctd, ctg, ctg2, emb, Wx);

    k_gates<<<dim3(Bv, 4), dim3(256), 0, stream>>>(h_prev, Wi, Wh, bi, bh, bx);

    k_cellsd<<<dim3(Bv, 2), dim3(256), 0, stream>>>(c_prev, Wsd, Wsf, o_h, o_c);

    // attention scores: LDS-staged B, flattened M, e-partials per col-chunk
    k_scores<TKv><<<dim3(MDOC / 128, 4), dim3(256), 0, stream>>>(
        g_encb_p, g_Wdt_p, g_sdp_p, g_sdp_p + 32768, bd, cov, wcdw, vd,
        g_ep_p, MDOC);

    k_scores<NKv><<<dim3(MNODE / 128, 4), dim3(256), 0, stream>>>(
        g_encnb_p, g_Wnt_p, g_sfp_p, g_sfp_p + 32768, bfv,
        nullptr, nullptr, vf, g_enp_p, MNODE);

    // doc attention back-end
    k_doc<<<dim3(Bv), dim3(256), 0, stream>>>(mask, cov, o_a, o_cov);

    k_cd<<<dim3(Bv, 8), dim3(256), 0, stream>>>(enc);

    k_flow<<<dim3(Bv), dim3(256), 0, stream>>>(n2t, o_fl);

    k_node1<<<dim3(Bv), dim3(256), 0, stream>>>(
        encn, maskn, flow, graph, n2t, Wpg, bpg,
        o_cd, o_cg, o_cg2, o_ant, o_pg);

    k_o1<<<dim3(Bv, 4), dim3(256), 0, stream>>>(W1, b1);

    k_logits<<<dim3(VPAD / 64), dim3(256), 0, stream>>>(b2);

    // vocab softmax
    k_vpart<<<dim3(Bv, NSv), dim3(256), 0, stream>>>();

    k_vwrite<<<dim3(Bv, NSv), dim3(256), 0, stream>>>(o_final);

    k_scatter<<<dim3(Bv), dim3(256), 0, stream>>>(o_final, vocd);
}

// Round 7
// 466.759 us; speedup vs baseline: 2.1035x; 1.0319x over previous
//
#include <hip/hip_runtime.h>
#include <stdint.h>

// ---------------------------------------------------------------------------
// LSTM pointer-generator decoder step, B=128 TK=400 NK=50 H=E=256 V=50000.
// Round 13: top-5 is now only the harness's 268MB workspace fill (83% HBM,
// unavoidable). Attack the sub-40us long tail's worst offenders (all the
// 128-block 0.5-wave/SIMD class): (1) k_flow -> k_fmax (B*NK=6400 blocks,
// fused max(a*n2t) + rowsum(n2t)) + k_flow2 (1-wave normalize); (2) a_n2t
// moved out of k_node1 into fully-parallel k_ant, normalizer S4 computed
// from rowsums (Fubini, same value); (3) k_vpart deleted -- k_logits'
// epilogue emits per-(row,block) (max,sumexp) partials from registers via
// 16-lane shuffles, k_vmerge (grid B) folds 784 pairs. Everything else
// unchanged from R12.
// ---------------------------------------------------------------------------

typedef unsigned short u16;
typedef unsigned int   u32;

#define Bv  128
#define TKv 400
#define NKv 50
#define Hv  256
#define Vv  50000
#define VPAD 50176   // 50000 padded to multiple of 128
#define NSv 16
#define CHUNKv 3136  // VPAD / NSv
#define MDOC (Bv * TKv)   // 51200
#define MNODE (Bv * NKv)  // 6400
#define NBLK (VPAD / 64)  // 784 logits col-blocks

typedef __attribute__((ext_vector_type(8))) short bf16x8;
typedef __attribute__((ext_vector_type(4))) float f32x4;

// ---- module-global workspace (no d_ws dependency) -------------------------
__device__ float g_x[32768];      // x = cat @ Wx + bx
__device__ float g_xp[4 * 32768]; // x K-partials
__device__ float g_gates[131072]; // LSTM gates [B,4H]
__device__ float g_h[32768];      // h_new
__device__ float g_c[32768];      // c_new
__device__ float g_sdp[2 * 32768];// s_hat@Wsd partials (no bias)
__device__ float g_sfp[2 * 32768];// s_hat@Wsf partials (no bias)
__device__ float g_ep[4 * MDOC];  // doc score partials (4 col-chunks)
__device__ float g_enp[4 * MNODE];// node score partials
__device__ float g_a[51200];      // doc attention a
__device__ float g_cd[32768];     // c_d
__device__ float g_cdp[8 * 32768];// c_d t-split partials (8 chunks of 50)
__device__ float g_cg[32768];     // c_g
__device__ float g_cg2[32768];    // c_g2
__device__ float g_pg[128];       // p_gen
__device__ float g_ans[MNODE];    // node attention an
__device__ float g_inv4[128];     // 1/S4 for a_n2t
__device__ float g_fl[MNODE];     // unnormalized flow
__device__ float g_nrs[MNODE];    // n2t row sums
__device__ float g_o1[32768];     // out1 (f32)
__device__ __attribute__((aligned(16))) u16 g_o1b[32768]; // out1 bf16
__device__ float g_vpp[(size_t)2 * Bv * NBLK]; // per-(row,blk) (max,sum)
__device__ float g_vred[Bv * 2];           // per-row merged (max, sum)
__device__ float g_logits[6400000];        // f32 logits (25.6 MB)
__device__ u16   g_Wdt[256 * 256];         // Whd^T bf16 [n][k]
__device__ u16   g_Wnt[256 * 256];         // Wn^T  bf16 [n][k]
__device__ u16   g_W2t[(size_t)VPAD * 256];// W2^T  bf16 [v][k] (25.7 MB)
__device__ u16   g_encb[(size_t)Bv * TKv * 256]; // enc bf16 (26.2 MB)
__device__ u16   g_encnb[(size_t)Bv * NKv * 256];// encn bf16 (3.3 MB)

__device__ __forceinline__ float sigm(float x) { return 1.f / (1.f + expf(-x)); }

__device__ __forceinline__ u16 f2bf(float f) {
    u32 u = __float_as_uint(f);
    return (u16)((u + 0x7fffu + ((u >> 16) & 1u)) >> 16);  // RNE
}

__device__ __forceinline__ bf16x8 cvt8(const float* __restrict__ p) {
    const float4 a = *(const float4*)p;
    const float4 b = *(const float4*)(p + 4);
    bf16x8 r;
    r[0] = (short)f2bf(a.x); r[1] = (short)f2bf(a.y);
    r[2] = (short)f2bf(a.z); r[3] = (short)f2bf(a.w);
    r[4] = (short)f2bf(b.x); r[5] = (short)f2bf(b.y);
    r[6] = (short)f2bf(b.z); r[7] = (short)f2bf(b.w);
    return r;
}

// tanh via exp; clamp so exp never overflows (tanh saturated anyway)
__device__ __forceinline__ float fast_tanh(float x) {
    x = fminf(fmaxf(x, -15.f), 15.f);
    float e = __expf(2.f * x);
    return (e - 1.f) / (e + 1.f);
}

// online (max,sum) merge: (m1,s1) <- (m1,s1) U (m2,s2)
__device__ __forceinline__ void ms_merge(float& m1, float& s1, float m2, float s2) {
    float M = fmaxf(m1, m2);
    s1 = s1 * expf(m1 - M) + s2 * expf(m2 - M);
    m1 = M;
}

// ---------------------------------------------------------------------------
// K-1: streaming f32 -> bf16 (RNE). n8 = element count / 8.
// ---------------------------------------------------------------------------
__global__ __launch_bounds__(256) void k_cvt(
    const float* __restrict__ src, u16* __restrict__ dst, int n8)
{
    int i = blockIdx.x * 256 + threadIdx.x;
    const int stride = gridDim.x * 256;
    for (; i < n8; i += stride)
        *(bf16x8*)(dst + (size_t)i * 8) = cvt8(src + (size_t)i * 8);
}

// ---------------------------------------------------------------------------
// K0: transpose-cast  src[K][N] f32  ->  dst[n][k] bf16.
// ---------------------------------------------------------------------------
__global__ __launch_bounds__(256) void k_tc(
    const float* __restrict__ src, u16* __restrict__ dst, int K, int N)
{
    __shared__ float tile[32][33];
    const int n0 = blockIdx.x * 32, k0 = blockIdx.y * 32;
    const int tx = threadIdx.x & 31, ty = threadIdx.x >> 5;
    #pragma unroll
    for (int i = 0; i < 32; i += 8) {
        int k = k0 + ty + i, n = n0 + tx;
        tile[ty + i][tx] = (n < N) ? src[(size_t)k * N + n] : 0.f;
    }
    __syncthreads();
    #pragma unroll
    for (int i = 0; i < 32; i += 8) {
        int n = n0 + ty + i, k = k0 + tx;
        dst[(size_t)n * K + k] = f2bf(tile[tx][ty + i]);
    }
}

// ---------------------------------------------------------------------------
// K1a: x K-partials. grid (B, 4).
// ---------------------------------------------------------------------------
__global__ __launch_bounds__(256) void k_x(
    const int* __restrict__ y,
    const float* __restrict__ ctd, const float* __restrict__ ctg,
    const float* __restrict__ ctg2, const float* __restrict__ emb,
    const float* __restrict__ Wx)
{
    const int b = blockIdx.x, ks = blockIdx.y, j = threadIdx.x;
    __shared__ float cs[256];
    float v;
    if      (ks == 0) v = ctd [b * 256 + j];
    else if (ks == 1) v = ctg [b * 256 + j];
    else if (ks == 2) v = ctg2[b * 256 + j];
    else              v = emb[(size_t)y[b] * 256 + j];
    cs[j] = v;
    __syncthreads();

    float acc = 0.f;
    const float* w = Wx + (size_t)(ks * 256) * 256 + j;
    #pragma unroll 8
    for (int k = 0; k < 256; k++) acc += cs[k] * w[(size_t)k * 256];
    g_xp[ks * 32768 + b * 256 + j] = acc;
}

// ---------------------------------------------------------------------------
// K1b: gates = x@Wi + h@Wh + bi + bh. grid (B, 4 col-chunks).
// ---------------------------------------------------------------------------
__global__ __launch_bounds__(256) void k_gates(
    const float* __restrict__ h_prev,
    const float* __restrict__ Wi, const float* __restrict__ Wh,
    const float* __restrict__ bi, const float* __restrict__ bh,
    const float* __restrict__ bx)
{
    const int b = blockIdx.x, cc = blockIdx.y, j = threadIdx.x;
    __shared__ float xs[256], hs[256];

    float xv = bx[j] + g_xp[b * 256 + j] + g_xp[32768 + b * 256 + j]
             + g_xp[65536 + b * 256 + j] + g_xp[98304 + b * 256 + j];
    xs[j] = xv;
    if (cc == 0) g_x[b * 256 + j] = xv;
    hs[j] = h_prev[b * 256 + j];
    __syncthreads();

    const int col = cc * 256 + j;
    float acc = bi[col] + bh[col];
    const float* wi = Wi + col;
    const float* wh = Wh + col;
    #pragma unroll 8
    for (int k = 0; k < 256; k++)
        acc += xs[k] * wi[(size_t)k * 1024] + hs[k] * wh[(size_t)k * 1024];
    g_gates[b * 1024 + col] = acc;
}

// ---------------------------------------------------------------------------
// K1c: LSTM elementwise + sd/sf K-partials. grid (B, 2).
// ---------------------------------------------------------------------------
__global__ __launch_bounds__(256) void k_cellsd(
    const float* __restrict__ c_prev,
    const float* __restrict__ Wsd, const float* __restrict__ Wsf,
    float* __restrict__ out_h, float* __restrict__ out_c)
{
    const int b = blockIdx.x, ks = blockIdx.y, j = threadIdx.x;
    __shared__ float sh[256];

    const float* gb = g_gates + b * 1024;
    float gi_ = gb[j], gf_ = gb[256 + j], gg_ = gb[512 + j], go_ = gb[768 + j];
    float cp = c_prev[b * 256 + j];
    float cn = sigm(gf_) * cp + sigm(gi_) * tanhf(gg_);
    float hn = sigm(go_) * tanhf(cn);
    if (ks == 0) {
        g_h[b * 256 + j] = hn;  g_c[b * 256 + j] = cn;
        out_h[b * 256 + j] = hn; out_c[b * 256 + j] = cn;
    }
    sh[j] = (ks == 0) ? hn : cn;   // s_hat rows [0,256) = h, [256,512) = c
    __syncthreads();

    float asd = 0.f, asf = 0.f;
    const float* wd = Wsd + (size_t)(ks * 256) * 256 + j;
    const float* wf = Wsf + (size_t)(ks * 256) * 256 + j;
    #pragma unroll 8
    for (int k = 0; k < 256; k++) {
        float sv = sh[k];
        asd += sv * wd[(size_t)k * 256];
        asf += sv * wf[(size_t)k * 256];
    }
    g_sdp[ks * 32768 + b * 256 + j] = asd;
    g_sfp[ks * 32768 + b * 256 + j] = asf;
}

// ---------------------------------------------------------------------------
// K2/K4 (MFMA): e-PARTIAL for one 64-col chunk. LDS-staged B, flattened M.
// ---------------------------------------------------------------------------
template<int R>
__global__ __launch_bounds__(256) void k_scores(
    const u16* __restrict__ srcb,     // bf16 A, Mtot x 256
    const u16* __restrict__ Wt,       // bf16 W^T [256][256]
    const float* __restrict__ addv0,  // s_hat@W partial (K lower half) [B][256]
    const float* __restrict__ addv1,  // s_hat@W partial (K upper half)
    const float* __restrict__ abias,  // bias vector (bd / bf) [256]
    const float* __restrict__ cov,    // flat [Mtot] or nullptr
    const float* __restrict__ wcw,    // [256] or nullptr
    const float* __restrict__ vv,     // [256]
    float* __restrict__ eout, int Mtot)
{
    const int tid = threadIdx.x;
    const int lane = tid & 63, w = tid >> 6;
    const int nlow = lane & 15, quad = lane >> 4;
    const int c0 = blockIdx.y * 64;

    __shared__ u16 Bs[64][264];
    {
        const u16* wsrc = Wt + (size_t)c0 * 256;
        #pragma unroll
        for (int j = 0; j < 8; j++) {
            int chunk = tid + j * 256;
            int row = chunk >> 5, c16 = chunk & 31;
            *(bf16x8*)(&Bs[row][c16 * 8]) =
                *(const bf16x8*)(wsrc + row * 256 + c16 * 8);
        }
    }
    __syncthreads();

    const int rowbase = blockIdx.x * 128 + w * 32;
    const u16* a0 = srcb + (size_t)(rowbase + nlow) * 256 + quad * 8;
    const u16* a1 = a0 + 16 * 256;

    const f32x4 zf = {0.f, 0.f, 0.f, 0.f};
    f32x4 acc[2][4];
    #pragma unroll
    for (int mi = 0; mi < 2; mi++)
        #pragma unroll
        for (int ni = 0; ni < 4; ni++) acc[mi][ni] = zf;

    bf16x8 af0 = *(const bf16x8*)(a0);
    bf16x8 af1 = *(const bf16x8*)(a1);
    for (int k0 = 0; k0 < 256; k0 += 32) {
        const int kn = (k0 + 32) & 255;   // wrap: last iter re-reads k=0 (discarded)
        bf16x8 nf0 = *(const bf16x8*)(a0 + kn);
        bf16x8 nf1 = *(const bf16x8*)(a1 + kn);
        bf16x8 bf[4];
        #pragma unroll
        for (int ni = 0; ni < 4; ni++)
            bf[ni] = *(const bf16x8*)(&Bs[ni * 16 + nlow][k0 + quad * 8]);
        #pragma unroll
        for (int ni = 0; ni < 4; ni++) {
            acc[0][ni] = __builtin_amdgcn_mfma_f32_16x16x32_bf16(af0, bf[ni], acc[0][ni], 0, 0, 0);
            acc[1][ni] = __builtin_amdgcn_mfma_f32_16x16x32_bf16(af1, bf[ni], acc[1][ni], 0, 0, 0);
        }
        af0 = nf0; af1 = nf1;
    }

    // epilogue: row = rowbase + mi*16 + quad*4 + r, col = c0 + ni*16 + nlow
    #pragma unroll
    for (int mi = 0; mi < 2; mi++) {
        float covt[4]; int bidx[4];
        #pragma unroll
        for (int r = 0; r < 4; r++) {
            int row = rowbase + mi * 16 + quad * 4 + r;
            covt[r] = cov ? cov[row] : 0.f;
            bidx[r] = row / R;             // compile-time R -> magic-mul
        }
        float s4[4] = {0.f, 0.f, 0.f, 0.f};
        #pragma unroll
        for (int ni = 0; ni < 4; ni++) {
            int col = c0 + ni * 16 + nlow;
            float vvc = vv[col];
            float ab  = abias[col];
            float wcc = wcw ? wcw[col] : 0.f;
            #pragma unroll
            for (int r = 0; r < 4; r++) {
                float adc = addv0[bidx[r] * 256 + col] + addv1[bidx[r] * 256 + col] + ab;
                s4[r] += vvc * fast_tanh(acc[mi][ni][r] + adc + covt[r] * wcc);
            }
        }
        #pragma unroll
        for (int r = 0; r < 4; r++) {
            float s = s4[r];
            s += __shfl_xor(s, 1, 64);
            s += __shfl_xor(s, 2, 64);
            s += __shfl_xor(s, 4, 64);
            s += __shfl_xor(s, 8, 64);
            int row = rowbase + mi * 16 + quad * 4 + r;
            if (nlow == 0)
                eout[(size_t)blockIdx.y * Mtot + row] = s;
        }
    }
}

// ---------------------------------------------------------------------------
// K3: doc softmax (+mask renorm): sums the 4 e-partials, a, coverage_next.
// ---------------------------------------------------------------------------
__global__ __launch_bounds__(256) void k_doc(
    const float* __restrict__ mask,
    const float* __restrict__ cov,
    float* __restrict__ out_a, float* __restrict__ out_cov)
{
    const int b = blockIdx.x, tid = threadIdx.x;
    __shared__ float red[256];

    float e0 = 0.f, e1s = 0.f;
    #pragma unroll
    for (int ch = 0; ch < 4; ch++) {
        e0 += g_ep[ch * MDOC + b * TKv + tid];
        if (tid + 256 < TKv) e1s += g_ep[ch * MDOC + b * TKv + tid + 256];
    }
    float e1 = (tid + 256 < TKv) ? e1s : -1e30f;

    float m = fmaxf(e0, e1);
    red[tid] = m; __syncthreads();
    for (int s = 128; s > 0; s >>= 1) { if (tid < s) red[tid] = fmaxf(red[tid], red[tid + s]); __syncthreads(); }
    m = red[0]; __syncthreads();

    float p0 = expf(e0 - m) * mask[b * TKv + tid];
    float p1 = (tid + 256 < TKv) ? expf(e1 - m) * mask[b * TKv + tid + 256] : 0.f;
    red[tid] = p0 + p1; __syncthreads();
    for (int s = 128; s > 0; s >>= 1) { if (tid < s) red[tid] += red[tid + s]; __syncthreads(); }
    float inv = 1.f / red[0];

    float a0 = p0 * inv;
    g_a[b * TKv + tid] = a0;
    out_a[b * TKv + tid] = a0;
    out_cov[b * TKv + tid] = cov[b * TKv + tid] + a0;
    if (tid + 256 < TKv) {
        float a1 = p1 * inv;
        g_a[b * TKv + tid + 256] = a1;
        out_a[b * TKv + tid + 256] = a1;
        out_cov[b * TKv + tid + 256] = cov[b * TKv + tid + 256] + a1;
    }
}

// ---------------------------------------------------------------------------
// K3b: c_d t-split partials. grid (B, 8).
// ---------------------------------------------------------------------------
__global__ __launch_bounds__(256) void k_cd(const float* __restrict__ enc)
{
    const int b = blockIdx.x, ks = blockIdx.y, tid = threadIdx.x;
    __shared__ float as_[50];
    if (tid < 50) as_[tid] = g_a[b * TKv + ks * 50 + tid];
    __syncthreads();

    const float* eb = enc + ((size_t)b * TKv + ks * 50) * 256 + tid;
    float acc = 0.f;
    #pragma unroll 10
    for (int t = 0; t < 50; t++) acc += as_[t] * eb[(size_t)t * 256];
    g_cdp[ks * 32768 + b * 256 + tid] = acc;
}

// ---------------------------------------------------------------------------
// K3c: per-(b,n): fl = max_t(a[t]*n2t[b,n,t]) AND rowsum rs = sum_t n2t.
// grid (B*NK) = 6400 blocks, one n2t row each — full-occupancy reduce.
// ---------------------------------------------------------------------------
__global__ __launch_bounds__(256) void k_fmax(const float* __restrict__ n2t)
{
    const int bn = blockIdx.x;
    const int b = bn / NKv;
    const int tid = threadIdx.x;
    __shared__ float rmx[256], rsm[256];

    const float* nb = n2t + (size_t)bn * TKv;
    const float* ab = g_a + b * TKv;

    float x0 = nb[tid], a0 = ab[tid];
    float mx = a0 * x0, sm = x0;
    if (tid + 256 < TKv) {
        float x1 = nb[tid + 256], a1 = ab[tid + 256];
        mx = fmaxf(mx, a1 * x1);
        sm += x1;
    }
    mx = fmaxf(mx, 0.f);   // match prior 0-init (a,n2t >= 0)
    rmx[tid] = mx; rsm[tid] = sm; __syncthreads();
    for (int s = 128; s > 0; s >>= 1) {
        if (tid < s) {
            rmx[tid] = fmaxf(rmx[tid], rmx[tid + s]);
            rsm[tid] += rsm[tid + s];
        }
        __syncthreads();
    }
    if (tid == 0) { g_fl[bn] = rmx[0]; g_nrs[bn] = rsm[0]; }
}

// ---------------------------------------------------------------------------
// K3d: normalize flow. grid (B), 1 wave.
// ---------------------------------------------------------------------------
__global__ __launch_bounds__(64) void k_flow2(float* __restrict__ out_flow)
{
    const int b = blockIdx.x, tid = threadIdx.x;
    float v = (tid < NKv) ? g_fl[b * NKv + tid] : 0.f;
    float s = v;
    s += __shfl_xor(s, 1, 64);
    s += __shfl_xor(s, 2, 64);
    s += __shfl_xor(s, 4, 64);
    s += __shfl_xor(s, 8, 64);
    s += __shfl_xor(s, 16, 64);
    s += __shfl_xor(s, 32, 64);
    if (tid < NKv) out_flow[b * NKv + tid] = v / s;
}

// ---------------------------------------------------------------------------
// K5: node softmax chain (sums 4 en-partials), an2, cg/cg2, S4, p_gen.
// a_n2t moved to k_ant (normalizer S4 = sum_n an*rowsum via Fubini).
// ---------------------------------------------------------------------------
__global__ __launch_bounds__(256) void k_node1(
    const float* __restrict__ encn,
    const float* __restrict__ maskn,
    const float* __restrict__ flow,
    const float* __restrict__ graph,
    const float* __restrict__ Wpg, const float* __restrict__ bpg,
    float* __restrict__ out_cd, float* __restrict__ out_cg,
    float* __restrict__ out_cg2, float* __restrict__ out_pgen)
{
    const int b = blockIdx.x, tid = threadIdx.x;
    __shared__ float ans[NKv], an2s[NKv], red[256];

    // c_d = sum of 8 t-split partials
    float cd = 0.f;
    #pragma unroll
    for (int i = 0; i < 8; i++) cd += g_cdp[i * 32768 + b * 256 + tid];
    g_cd[b * 256 + tid] = cd;
    out_cd[b * 256 + tid] = cd;

    // node softmax -> flow-weighted renorm
    float v = -1e30f;
    if (tid < NKv) {
        v = 0.f;
        #pragma unroll
        for (int ch = 0; ch < 4; ch++) v += g_enp[ch * MNODE + b * NKv + tid];
    }
    red[tid] = v; __syncthreads();
    for (int s = 128; s > 0; s >>= 1) { if (tid < s) red[tid] = fmaxf(red[tid], red[tid + s]); __syncthreads(); }
    float m = red[0]; __syncthreads();

    float p = (tid < NKv) ? expf(v - m) * maskn[b * NKv + tid] : 0.f;
    red[tid] = p; __syncthreads();
    for (int s = 128; s > 0; s >>= 1) { if (tid < s) red[tid] += red[tid + s]; __syncthreads(); }
    float S = red[0]; __syncthreads();
    p = (tid < NKv) ? (p / S) * flow[b * NKv + tid] : 0.f;
    red[tid] = p; __syncthreads();
    for (int s = 128; s > 0; s >>= 1) { if (tid < s) red[tid] += red[tid + s]; __syncthreads(); }
    float S2 = red[0]; __syncthreads();
    if (tid < NKv) {
        ans[tid] = p / S2;
        g_ans[b * NKv + tid] = ans[tid];
    }
    __syncthreads();

    // S4 = sum_n an[n] * rowsum_n (for a_n2t normalization)
    float s4p = (tid < NKv) ? ans[tid] * g_nrs[b * NKv + tid] : 0.f;
    red[tid] = s4p; __syncthreads();
    for (int s = 128; s > 0; s >>= 1) { if (tid < s) red[tid] += red[tid + s]; __syncthreads(); }
    if (tid == 0) g_inv4[b] = 1.f / red[0];
    __syncthreads();

    // an2 = (ans @ graph) * mask, renormalized
    float q = 0.f;
    if (tid < NKv) {
        const float* gb = graph + (size_t)b * NKv * NKv + tid;
        #pragma unroll
        for (int n = 0; n < NKv; n++) q += ans[n] * gb[n * NKv];
        q *= maskn[b * NKv + tid];
    }
    red[tid] = q; __syncthreads();
    for (int s = 128; s > 0; s >>= 1) { if (tid < s) red[tid] += red[tid + s]; __syncthreads(); }
    float S3 = red[0]; __syncthreads();
    if (tid < NKv) an2s[tid] = q / S3;
    __syncthreads();

    // c_g and c_g2 in one pass over encn
    float cg = 0.f, cg2 = 0.f;
    {
        const float* enb = encn + (size_t)b * NKv * 256 + tid;
        #pragma unroll
        for (int n = 0; n < NKv; n++) {
            float e = enb[n * 256];
            cg  += ans[n]  * e;
            cg2 += an2s[n] * e;
        }
    }
    g_cg[b * 256 + tid] = cg;   out_cg[b * 256 + tid] = cg;
    g_cg2[b * 256 + tid] = cg2; out_cg2[b * 256 + tid] = cg2;

    // p_gen
    float hvv = g_h[b * 256 + tid], cvv = g_c[b * 256 + tid];
    float xvv = g_x[b * 256 + tid];
    float part = cd  * Wpg[tid]        + cg  * Wpg[256 + tid]
               + cg2 * Wpg[512 + tid]  + hvv * Wpg[768 + tid]
               + cvv * Wpg[1024 + tid] + xvv * Wpg[1280 + tid];
    red[tid] = part; __syncthreads();
    for (int s = 128; s > 0; s >>= 1) { if (tid < s) red[tid] += red[tid + s]; __syncthreads(); }
    if (tid == 0) {
        float pg = sigm(red[0] + bpg[0]);
        g_pg[b] = pg; out_pgen[b] = pg;
    }
}

// ---------------------------------------------------------------------------
// K5b: a_n2t scatter, fully t-parallel (S4 precomputed). grid (B, 2).
// ---------------------------------------------------------------------------
__global__ __launch_bounds__(256) void k_ant(
    const float* __restrict__ n2t, float* __restrict__ out_ant)
{
    const int b = blockIdx.x, ks = blockIdx.y, tid = threadIdx.x;
    __shared__ float ans[NKv];
    if (tid < NKv) ans[tid] = g_ans[b * NKv + tid];
    __syncthreads();

    if (tid < 200) {
        const int t = ks * 200 + tid;
        const float* nb = n2t + (size_t)b * NKv * TKv + t;
        float at = 0.f;
        #pragma unroll
        for (int n = 0; n < NKv; n++) at += ans[n] * nb[n * TKv];
        out_ant[b * TKv + t] = at * g_inv4[b];
    }
}

// ---------------------------------------------------------------------------
// K6: out1 = [h|cd|cg|cg2] @ W1 + b1. grid (B, 4 col-chunks of 64).
// ---------------------------------------------------------------------------
__global__ __launch_bounds__(256) void k_o1(
    const float* __restrict__ W1, const float* __restrict__ b1)
{
    const int b = blockIdx.x, cc = blockIdx.y, tid = threadIdx.x;
    __shared__ float cat[1024];
    __shared__ float red[256];

    cat[tid]       = g_h  [b * 256 + tid];
    cat[256 + tid] = g_cd [b * 256 + tid];
    cat[512 + tid] = g_cg [b * 256 + tid];
    cat[768 + tid] = g_cg2[b * 256 + tid];
    __syncthreads();

    const int lane = tid & 63, kq = tid >> 6;
    const int col = cc * 64 + lane;
    const float* w  = W1 + (size_t)(kq * 256) * 256 + col;
    const float* cs = cat + kq * 256;
    float acc = 0.f;
    #pragma unroll 8
    for (int k = 0; k < 256; k++) acc += cs[k] * w[(size_t)k * 256];
    red[tid] = acc; __syncthreads();

    if (tid < 64) {
        float o = b1[cc * 64 + tid]
                + red[tid] + red[64 + tid] + red[128 + tid] + red[192 + tid];
        g_o1[b * 256 + cc * 64 + tid] = o;
        g_o1b[b * 256 + cc * 64 + tid] = f2bf(o);
    }
}

// ---------------------------------------------------------------------------
// K7 (MFMA): logits chunk + fused per-row (max, sumexp) partial.
// 64-col blocks (grid NBLK=784); wave w = rows [w*32,w*32+32) as 2Mx4N.
// Epilogue: per-row max/sum over this block's 64 cols via 16-lane shuffles,
// one (m,s) pair per (row, block) -> g_vpp. Invalid cols -> x=-1e30.
// ---------------------------------------------------------------------------
__global__ __launch_bounds__(256) void k_logits(const float* __restrict__ b2)
{
    const int v0 = blockIdx.x * 64;
    const int tid = threadIdx.x;
    const int lane = tid & 63, wave = tid >> 6;
    const int nlow = lane & 15, quad = lane >> 4;

    const u16* a0p = g_o1b + (wave * 32 + nlow) * 256 + quad * 8;
    const u16* a1p = a0p + 16 * 256;
    const u16* bbase = g_W2t + (size_t)(v0 + nlow) * 256 + quad * 8;

    const f32x4 zf = {0.f, 0.f, 0.f, 0.f};
    f32x4 acc0[4], acc1[4];
    #pragma unroll
    for (int i = 0; i < 4; i++) { acc0[i] = zf; acc1[i] = zf; }

    for (int k0 = 0; k0 < 256; k0 += 32) {
        bf16x8 a0 = *(const bf16x8*)(a0p + k0);
        bf16x8 a1 = *(const bf16x8*)(a1p + k0);
        #pragma unroll
        for (int nt = 0; nt < 4; nt++) {
            bf16x8 bf = *(const bf16x8*)(bbase + (size_t)nt * 4096 + k0);
            acc0[nt] = __builtin_amdgcn_mfma_f32_16x16x32_bf16(a0, bf, acc0[nt], 0, 0, 0);
            acc1[nt] = __builtin_amdgcn_mfma_f32_16x16x32_bf16(a1, bf, acc1[nt], 0, 0, 0);
        }
    }

    float bbv[4]; bool val[4];
    #pragma unroll
    for (int nt = 0; nt < 4; nt++) {
        int v = v0 + nt * 16 + nlow;
        val[nt] = v < Vv;
        bbv[nt] = val[nt] ? b2[v] : 0.f;
    }

    #pragma unroll
    for (int mi = 0; mi < 2; mi++) {
        #pragma unroll
        for (int r = 0; r < 4; r++) {
            const int row = wave * 32 + mi * 16 + quad * 4 + r;
            float x[4];
            #pragma unroll
            for (int nt = 0; nt < 4; nt++) {
                float xv = (mi ? acc1[nt][r] : acc0[nt][r]) + bbv[nt];
                if (val[nt]) g_logits[(size_t)row * Vv + v0 + nt * 16 + nlow] = xv;
                x[nt] = val[nt] ? xv : -1e30f;
            }
            float m = fmaxf(fmaxf(x[0], x[1]), fmaxf(x[2], x[3]));
            m = fmaxf(m, __shfl_xor(m, 1, 64));
            m = fmaxf(m, __shfl_xor(m, 2, 64));
            m = fmaxf(m, __shfl_xor(m, 4, 64));
            m = fmaxf(m, __shfl_xor(m, 8, 64));
            float s = expf(x[0] - m) + expf(x[1] - m)
                    + expf(x[2] - m) + expf(x[3] - m);
            s += __shfl_xor(s, 1, 64);
            s += __shfl_xor(s, 2, 64);
            s += __shfl_xor(s, 4, 64);
            s += __shfl_xor(s, 8, 64);
            if (nlow == 0) {
                g_vpp[((size_t)row * NBLK + blockIdx.x) * 2]     = m;
                g_vpp[((size_t)row * NBLK + blockIdx.x) * 2 + 1] = s;
            }
        }
    }
}

// ---------------------------------------------------------------------------
// K8a: merge NBLK (max,sum) partials per row. grid (B).
// ---------------------------------------------------------------------------
__global__ __launch_bounds__(256) void k_vmerge()
{
    const int b = blockIdx.x, tid = threadIdx.x;
    __shared__ float rm[256], rs[256];

    float M = -1e30f, S = 0.f;
    for (int i = tid; i < NBLK; i += 256)
        ms_merge(M, S, g_vpp[((size_t)b * NBLK + i) * 2],
                       g_vpp[((size_t)b * NBLK + i) * 2 + 1]);
    rm[tid] = M; rs[tid] = S; __syncthreads();
    for (int off = 128; off > 0; off >>= 1) {
        if (tid < off) {
            float m1 = rm[tid], s1 = rs[tid];
            ms_merge(m1, s1, rm[tid + off], rs[tid + off]);
            rm[tid] = m1; rs[tid] = s1;
        }
        __syncthreads();
    }
    if (tid == 0) { g_vred[b * 2] = rm[0]; g_vred[b * 2 + 1] = rs[0]; }
}

// ---------------------------------------------------------------------------
// K8b: write exp(x-M)*pg/S with float4 stores. grid (B, NS).
// ---------------------------------------------------------------------------
__global__ __launch_bounds__(256) void k_vwrite(float* __restrict__ outF)
{
    const int b = blockIdx.x, ks = blockIdx.y, tid = threadIdx.x;

    const float M = g_vred[b * 2];
    const float inv = g_pg[b] / g_vred[b * 2 + 1];

    const int base = ks * CHUNKv;
    const int end  = min(base + CHUNKv, Vv);
    const int n4   = (end - base) >> 2;
    const float4* L4 = (const float4*)(g_logits + (size_t)b * Vv + base);
    float4* O4 = (float4*)(outF + (size_t)b * Vv + base);

    for (int i = tid; i < n4; i += 256) {
        float4 x = L4[i];
        float4 r;
        r.x = expf(x.x - M) * inv;
        r.y = expf(x.y - M) * inv;
        r.z = expf(x.z - M) * inv;
        r.w = expf(x.w - M) * inv;
        O4[i] = r;
    }
}

// ---------------------------------------------------------------------------
// K8c: row-local pointer scatter (1-pg)*a[b,t] at voc_d[b,t].
// ---------------------------------------------------------------------------
__global__ __launch_bounds__(256) void k_scatter(
    float* __restrict__ outF, const int* __restrict__ vocd)
{
    const int b = blockIdx.x, tid = threadIdx.x;
    float* Ob = outF + (size_t)b * Vv;
    const float omp = 1.f - g_pg[b];
    for (int t = tid; t < TKv; t += 256)
        atomicAdd(Ob + vocd[b * TKv + t], omp * g_a[b * TKv + t]);
}

// ---------------------------------------------------------------------------

extern "C" void kernel_launch(void* const* d_in, const int* in_sizes, int n_in,
                              void* d_out, int out_size, void* d_ws, size_t ws_size,
                              hipStream_t stream)
{
    (void)in_sizes; (void)n_in; (void)out_size; (void)d_ws; (void)ws_size;

    const int*   y      = (const int*)d_in[0];
    const float* h_prev = (const float*)d_in[1];
    const float* c_prev = (const float*)d_in[2];
    const float* enc    = (const float*)d_in[3];
    const float* encn   = (const float*)d_in[4];
    const float* mask   = (const float*)d_in[5];
    const float* maskn  = (const float*)d_in[6];
    const float* ctd    = (const float*)d_in[7];
    const float* ctg    = (const float*)d_in[8];
    const float* ctg2   = (const float*)d_in[9];
    const float* cov    = (const float*)d_in[10];
    const float* flow   = (const float*)d_in[11];
    const float* n2t    = (const float*)d_in[12];
    const float* graph  = (const float*)d_in[13];
    const int*   vocd   = (const int*)d_in[14];
    // d_in[15] = step (unused)
    const float* emb    = (const float*)d_in[16];
    const float* Wx     = (const float*)d_in[17];
    const float* bx     = (const float*)d_in[18];
    const float* Wi     = (const float*)d_in[19];
    const float* Wh     = (const float*)d_in[20];
    const float* bi     = (const float*)d_in[21];
    const float* bh     = (const float*)d_in[22];
    const float* Whd    = (const float*)d_in[23];
    const float* Wsd    = (const float*)d_in[24];
    const float* wcdw   = (const float*)d_in[25];
    const float* vd     = (const float*)d_in[26];
    const float* bd     = (const float*)d_in[27];
    const float* Wn     = (const float*)d_in[28];
    const float* Wsf    = (const float*)d_in[29];
    const float* vf     = (const float*)d_in[30];
    const float* bfv    = (const float*)d_in[31];
    const float* Wpg    = (const float*)d_in[32];
    const float* bpg    = (const float*)d_in[33];
    const float* W1     = (const float*)d_in[34];
    const float* b1     = (const float*)d_in[35];
    const float* W2     = (const float*)d_in[36];
    const float* b2     = (const float*)d_in[37];

    float* o = (float*)d_out;                 // FLOAT32 output
    float* o_final = o;                       // 6,400,000
    float* o_h     = o + 6400000;
    float* o_c     = o + 6432768;
    float* o_cd    = o + 6465536;
    float* o_cg    = o + 6498304;
    float* o_cg2   = o + 6531072;
    float* o_a     = o + 6563840;
    float* o_ant   = o + 6615040;
    float* o_pg    = o + 6666240;
    float* o_cov   = o + 6666368;
    float* o_fl    = o + 6717568;

    float* g_ep_p;  hipGetSymbolAddress((void**)&g_ep_p,  HIP_SYMBOL(g_ep));
    float* g_enp_p; hipGetSymbolAddress((void**)&g_enp_p, HIP_SYMBOL(g_enp));
    float* g_sdp_p; hipGetSymbolAddress((void**)&g_sdp_p, HIP_SYMBOL(g_sdp));
    float* g_sfp_p; hipGetSymbolAddress((void**)&g_sfp_p, HIP_SYMBOL(g_sfp));
    u16*   g_Wdt_p; hipGetSymbolAddress((void**)&g_Wdt_p, HIP_SYMBOL(g_Wdt));
    u16*   g_Wnt_p; hipGetSymbolAddress((void**)&g_Wnt_p, HIP_SYMBOL(g_Wnt));
    u16*   g_W2t_p; hipGetSymbolAddress((void**)&g_W2t_p, HIP_SYMBOL(g_W2t));
    u16*   g_encb_p;  hipGetSymbolAddress((void**)&g_encb_p,  HIP_SYMBOL(g_encb));
    u16*   g_encnb_p; hipGetSymbolAddress((void**)&g_encnb_p, HIP_SYMBOL(g_encnb));

    // transpose-cast weights to bf16 [n][k]
    k_tc<<<dim3(8, 8), dim3(256), 0, stream>>>(Whd, g_Wdt_p, 256, 256);
    k_tc<<<dim3(8, 8), dim3(256), 0, stream>>>(Wn,  g_Wnt_p, 256, 256);
    k_tc<<<dim3(VPAD / 32, 8), dim3(256), 0, stream>>>(W2, g_W2t_p, 256, Vv);

    // pre-convert enc/encn to bf16 (A operands for k_scores)
    k_cvt<<<dim3(2048), dim3(256), 0, stream>>>(enc,  g_encb_p,  Bv * TKv * 256 / 8);
    k_cvt<<<dim3(800),  dim3(256), 0, stream>>>(encn, g_encnb_p, Bv * NKv * 256 / 8);

    // LSTM front-end
    k_x<<<dim3(Bv, 4), dim3(256), 0, stream>>>(y, ctd, ctg, ctg2, emb, Wx);

    k_gates<<<dim3(Bv, 4), dim3(256), 0, stream>>>(h_prev, Wi, Wh, bi, bh, bx);

    k_cellsd<<<dim3(Bv, 2), dim3(256), 0, stream>>>(c_prev, Wsd, Wsf, o_h, o_c);

    // attention scores: LDS-staged B, flattened M, e-partials per col-chunk
    k_scores<TKv><<<dim3(MDOC / 128, 4), dim3(256), 0, stream>>>(
        g_encb_p, g_Wdt_p, g_sdp_p, g_sdp_p + 32768, bd, cov, wcdw, vd,
        g_ep_p, MDOC);

    k_scores<NKv><<<dim3(MNODE / 128, 4), dim3(256), 0, stream>>>(
        g_encnb_p, g_Wnt_p, g_sfp_p, g_sfp_p + 32768, bfv,
        nullptr, nullptr, vf, g_enp_p, MNODE);

    // doc attention back-end
    k_doc<<<dim3(Bv), dim3(256), 0, stream>>>(mask, cov, o_a, o_cov);

    k_fmax<<<dim3(Bv * NKv), dim3(256), 0, stream>>>(n2t);

    k_flow2<<<dim3(Bv), dim3(64), 0, stream>>>(o_fl);

    k_cd<<<dim3(Bv, 8), dim3(256), 0, stream>>>(enc);

    k_node1<<<dim3(Bv), dim3(256), 0, stream>>>(
        encn, maskn, flow, graph, Wpg, bpg,
        o_cd, o_cg, o_cg2, o_pg);

    k_ant<<<dim3(Bv, 2), dim3(256), 0, stream>>>(n2t, o_ant);

    k_o1<<<dim3(Bv, 4), dim3(256), 0, stream>>>(W1, b1);

    k_logits<<<dim3(NBLK), dim3(256), 0, stream>>>(b2);

    // vocab softmax
    k_vmerge<<<dim3(Bv), dim3(256), 0, stream>>>();

    k_vwrite<<<dim3(Bv, NSv), dim3(256), 0, stream>>>(o_final);

    k_scatter<<<dim3(Bv), dim3(256), 0, stream>>>(o_final, vocd);
}